// Round 1
// baseline (1006.045 us; speedup 1.0000x reference)
//
#include <hip/hip_runtime.h>
#include <math.h>

#define N_NODES 50000
#define N_EDGES 1600000
#define IN_CH 512
#define HID 64
#define OUTC 64
#define NEG_SLOPE 0.2f

// ---------------- degree + histogram ----------------
__global__ void k_init_deg(float* deg) {
    int i = blockIdx.x * blockDim.x + threadIdx.x;
    if (i < N_NODES) deg[i] = 1.0f;  // self-loop weight 1
}

__global__ void k_deg_hist(const int* __restrict__ dst, const float* __restrict__ ea,
                           float* deg, int* counts) {
    int e = blockIdx.x * blockDim.x + threadIdx.x;
    if (e >= N_EDGES) return;
    int d = dst[e];
    atomicAdd(&deg[d], ea[e]);
    atomicAdd(&counts[d], 1);
}

__global__ void k_dinv(float* deg) {
    int i = blockIdx.x * blockDim.x + threadIdx.x;
    if (i < N_NODES) deg[i] = rsqrtf(deg[i]);  // deg >= 1 always
}

// ---------------- exclusive scan (counts -> offsets) ----------------
__global__ void k_scan_reduce(const int* __restrict__ counts, int* bsum, int n) {
    __shared__ int lds[256];
    int i = blockIdx.x * 256 + threadIdx.x;
    lds[threadIdx.x] = (i < n) ? counts[i] : 0;
    __syncthreads();
    for (int s = 128; s > 0; s >>= 1) {
        if (threadIdx.x < s) lds[threadIdx.x] += lds[threadIdx.x + s];
        __syncthreads();
    }
    if (threadIdx.x == 0) bsum[blockIdx.x] = lds[0];
}

__global__ void k_scan_bsum(int* bsum, int nb) {
    __shared__ int lds[256];
    int t = threadIdx.x;
    int v = (t < nb) ? bsum[t] : 0;
    lds[t] = v;
    __syncthreads();
    for (int s = 1; s < 256; s <<= 1) {
        int add = (t >= s) ? lds[t - s] : 0;
        __syncthreads();
        lds[t] += add;
        __syncthreads();
    }
    if (t < nb) bsum[t] = lds[t] - v;  // exclusive
}

__global__ void k_scan_final(const int* __restrict__ counts, const int* __restrict__ bsum,
                             int* offsets, int n) {
    __shared__ int lds[256];
    int t = threadIdx.x;
    int i = blockIdx.x * 256 + t;
    int v = (i < n) ? counts[i] : 0;
    lds[t] = v;
    __syncthreads();
    for (int s = 1; s < 256; s <<= 1) {
        int add = (t >= s) ? lds[t - s] : 0;
        __syncthreads();
        lds[t] += add;
        __syncthreads();
    }
    int incl = lds[t];
    int base = bsum[blockIdx.x];
    if (i < n) offsets[i] = base + incl - v;
    if (i == n - 1) offsets[n] = base + incl;
}

// ---------------- CSR scatter (by dst), norm precomputed ----------------
__global__ void k_scatter(const int* __restrict__ src, const int* __restrict__ dst,
                          const float* __restrict__ ea, const float* __restrict__ dinv,
                          const int* __restrict__ offsets, int* cursor,
                          int* col, float* wedge) {
    int e = blockIdx.x * blockDim.x + threadIdx.x;
    if (e >= N_EDGES) return;
    int s = src[e], d = dst[e];
    int pos = offsets[d] + atomicAdd(&cursor[d], 1);
    col[pos] = s;
    wedge[pos] = dinv[s] * ea[e] * dinv[d];
}

// ---------------- GEMM1: p = x @ W_sg  (50000x512 @ 512x64) ----------------
#define RPW 8
__global__ __launch_bounds__(256) void k_gemm1(const float* __restrict__ x,
                                               const float* __restrict__ W,
                                               float* __restrict__ p) {
    int wid = blockIdx.x * 4 + (threadIdx.x >> 6);
    int lane = threadIdx.x & 63;
    if (wid >= N_NODES / RPW) return;  // 50000 % 8 == 0
    int r0 = wid * RPW;
    float acc[RPW];
#pragma unroll
    for (int j = 0; j < RPW; j++) acc[j] = 0.f;
    for (int k4 = 0; k4 < IN_CH / 4; k4++) {
        int k = k4 * 4;
        float w0 = W[(k + 0) * HID + lane];
        float w1 = W[(k + 1) * HID + lane];
        float w2 = W[(k + 2) * HID + lane];
        float w3 = W[(k + 3) * HID + lane];
#pragma unroll
        for (int j = 0; j < RPW; j++) {
            float4 xv = *(const float4*)(x + (size_t)(r0 + j) * IN_CH + k);
            acc[j] += xv.x * w0 + xv.y * w1 + xv.z * w2 + xv.w * w3;
        }
    }
#pragma unroll
    for (int j = 0; j < RPW; j++) p[(size_t)(r0 + j) * HID + lane] = acc[j];
}

// ---------------- one normalized-adjacency hop ----------------
__global__ __launch_bounds__(256) void k_hop(const float* __restrict__ hin,
                                             const int* __restrict__ offsets,
                                             const int* __restrict__ col,
                                             const float* __restrict__ wedge,
                                             const float* __restrict__ dinv,
                                             float* __restrict__ hout) {
    int v = blockIdx.x * 4 + (threadIdx.x >> 6);
    int lane = threadIdx.x & 63;
    if (v >= N_NODES) return;
    float dv = dinv[v];
    float acc = dv * dv * hin[(size_t)v * HID + lane];  // self-loop
    int beg = offsets[v], end = offsets[v + 1];
    for (int i = beg; i < end; i++) {
        int s = col[i];
        float w = wedge[i];
        acc += w * hin[(size_t)s * HID + lane];
    }
    hout[(size_t)v * HID + lane] = acc;
}

// ---------------- bias + SELU + GEMM2 + attention dots ----------------
__global__ __launch_bounds__(256) void k_act_gemm2(const float* __restrict__ h2,
                                                   const float* __restrict__ bsg,
                                                   const float* __restrict__ Wg,
                                                   const float* __restrict__ att_s,
                                                   const float* __restrict__ att_d,
                                                   float* __restrict__ g,
                                                   float* __restrict__ asrc,
                                                   float* __restrict__ adst) {
    __shared__ float hs[4][HID];
    int w = threadIdx.x >> 6;
    int v = blockIdx.x * 4 + w;
    int lane = threadIdx.x & 63;
    if (v >= N_NODES) return;  // 50000 % 4 == 0, never taken
    float hv = h2[(size_t)v * HID + lane] + bsg[lane];
    const float SC = 1.0507009873554805f, AL = 1.6732632423543772f;
    hv = (hv > 0.f) ? SC * hv : SC * AL * (__expf(hv) - 1.f);
    hs[w][lane] = hv;
    __syncthreads();
    float g0 = 0.f, g1 = 0.f;
#pragma unroll
    for (int k = 0; k < HID; k++) {
        float hk = hs[w][k];
        g0 += hk * Wg[k * 128 + lane];
        g1 += hk * Wg[k * 128 + 64 + lane];
    }
    g[(size_t)v * 128 + lane] = g0;
    g[(size_t)v * 128 + 64 + lane] = g1;
    float s0 = g0 * att_s[lane], s1 = g1 * att_s[64 + lane];
    float d0 = g0 * att_d[lane], d1 = g1 * att_d[64 + lane];
#pragma unroll
    for (int o = 32; o > 0; o >>= 1) {
        s0 += __shfl_xor(s0, o);
        s1 += __shfl_xor(s1, o);
        d0 += __shfl_xor(d0, o);
        d1 += __shfl_xor(d1, o);
    }
    if (lane == 0) {
        asrc[v * 2 + 0] = s0;
        asrc[v * 2 + 1] = s1;
        adst[v * 2 + 0] = d0;
        adst[v * 2 + 1] = d1;
    }
}

// ---------------- GAT aggregation: online softmax, one wave per node ----------------
__global__ __launch_bounds__(256) void k_gat(const float* __restrict__ g,
                                             const float* __restrict__ asrc,
                                             const float* __restrict__ adst,
                                             const int* __restrict__ offsets,
                                             const int* __restrict__ col,
                                             const float* __restrict__ bgat,
                                             float* __restrict__ out) {
    int v = blockIdx.x * 4 + (threadIdx.x >> 6);
    int lane = threadIdx.x & 63;
    if (v >= N_NODES) return;
    float ad0 = adst[v * 2], ad1 = adst[v * 2 + 1];
    // self-loop seeds the online softmax
    float as0 = asrc[v * 2], as1 = asrc[v * 2 + 1];
    float e0 = as0 + ad0; e0 = (e0 > 0.f) ? e0 : NEG_SLOPE * e0;
    float e1 = as1 + ad1; e1 = (e1 > 0.f) ? e1 : NEG_SLOPE * e1;
    float m0 = e0, m1 = e1;
    float den0 = 1.f, den1 = 1.f;
    float acc0 = g[(size_t)v * 128 + lane];
    float acc1 = g[(size_t)v * 128 + 64 + lane];
    int beg = offsets[v], end = offsets[v + 1];
    for (int i = beg; i < end; i++) {
        int s = col[i];
        float bs0 = asrc[s * 2], bs1 = asrc[s * 2 + 1];
        float t0 = bs0 + ad0; t0 = (t0 > 0.f) ? t0 : NEG_SLOPE * t0;
        float t1 = bs1 + ad1; t1 = (t1 > 0.f) ? t1 : NEG_SLOPE * t1;
        float g0 = g[(size_t)s * 128 + lane];
        float g1 = g[(size_t)s * 128 + 64 + lane];
        if (t0 > m0) {
            float sc = __expf(m0 - t0);
            acc0 = acc0 * sc + g0;
            den0 = den0 * sc + 1.f;
            m0 = t0;
        } else {
            float p = __expf(t0 - m0);
            acc0 += p * g0;
            den0 += p;
        }
        if (t1 > m1) {
            float sc = __expf(m1 - t1);
            acc1 = acc1 * sc + g1;
            den1 = den1 * sc + 1.f;
            m1 = t1;
        } else {
            float p = __expf(t1 - m1);
            acc1 += p * g1;
            den1 += p;
        }
    }
    out[(size_t)v * OUTC + lane] = 0.5f * (acc0 / den0 + acc1 / den1) + bgat[lane];
}

extern "C" void kernel_launch(void* const* d_in, const int* in_sizes, int n_in,
                              void* d_out, int out_size, void* d_ws, size_t ws_size,
                              hipStream_t stream) {
    const float* x     = (const float*)d_in[0];
    const int*   ei    = (const int*)d_in[1];
    const float* ea    = (const float*)d_in[2];
    const float* Wsg   = (const float*)d_in[3];
    const float* bsg   = (const float*)d_in[4];
    const float* Wg    = (const float*)d_in[5];
    const float* att_s = (const float*)d_in[6];
    const float* att_d = (const float*)d_in[7];
    const float* bgat  = (const float*)d_in[8];
    const int* src = ei;
    const int* dst = ei + N_EDGES;
    float* out = (float*)d_out;

    char* ws = (char*)d_ws;
    size_t off = 0;
    auto alloc = [&](size_t bytes) -> void* {
        void* p = ws + off;
        off = (off + bytes + 255) & ~(size_t)255;
        return p;
    };
    float* deg    = (float*)alloc((size_t)N_NODES * 4);        // becomes dinv
    int*   counts = (int*)alloc((size_t)N_NODES * 4);
    int*   offs   = (int*)alloc((size_t)(N_NODES + 1) * 4);
    int*   cursor = (int*)alloc((size_t)N_NODES * 4);
    int*   bsum   = (int*)alloc(256 * 4);
    int*   col    = (int*)alloc((size_t)N_EDGES * 4);
    float* wedge  = (float*)alloc((size_t)N_EDGES * 4);
    float* h0     = (float*)alloc((size_t)N_NODES * HID * 4);
    float* h1     = (float*)alloc((size_t)N_NODES * HID * 4);
    float* g      = (float*)alloc((size_t)N_NODES * 128 * 4);
    float* asrc   = (float*)alloc((size_t)N_NODES * 2 * 4);
    float* adst   = (float*)alloc((size_t)N_NODES * 2 * 4);
    (void)ws_size; (void)in_sizes; (void)n_in; (void)out_size;

    hipMemsetAsync(counts, 0, (size_t)N_NODES * 4, stream);
    hipMemsetAsync(cursor, 0, (size_t)N_NODES * 4, stream);

    k_init_deg<<<(N_NODES + 255) / 256, 256, 0, stream>>>(deg);
    k_deg_hist<<<(N_EDGES + 255) / 256, 256, 0, stream>>>(dst, ea, deg, counts);
    k_dinv<<<(N_NODES + 255) / 256, 256, 0, stream>>>(deg);

    int nb = (N_NODES + 255) / 256;  // 196
    k_scan_reduce<<<nb, 256, 0, stream>>>(counts, bsum, N_NODES);
    k_scan_bsum<<<1, 256, 0, stream>>>(bsum, nb);
    k_scan_final<<<nb, 256, 0, stream>>>(counts, bsum, offs, N_NODES);

    k_scatter<<<(N_EDGES + 255) / 256, 256, 0, stream>>>(src, dst, ea, deg, offs, cursor, col, wedge);

    k_gemm1<<<(N_NODES / RPW + 3) / 4, 256, 0, stream>>>(x, Wsg, h0);
    k_hop<<<N_NODES / 4, 256, 0, stream>>>(h0, offs, col, wedge, deg, h1);
    k_hop<<<N_NODES / 4, 256, 0, stream>>>(h1, offs, col, wedge, deg, h0);
    k_act_gemm2<<<N_NODES / 4, 256, 0, stream>>>(h0, bsg, Wg, att_s, att_d, g, asrc, adst);
    k_gat<<<N_NODES / 4, 256, 0, stream>>>(g, asrc, adst, offs, col, bgat, out);
}

// Round 2
// 969.168 us; speedup vs baseline: 1.0380x; 1.0380x over previous
//
#include <hip/hip_runtime.h>
#include <math.h>

#define N_NODES 50000
#define N_EDGES 1600000
#define IN_CH 512
#define HID 64
#define OUTC 64
#define NEG_SLOPE 0.2f

// ---------------- init: deg=1 (self-loop), counts=0, cursor=0 ----------------
__global__ void k_init(float* deg, int* counts, int* cursor) {
    int i = blockIdx.x * blockDim.x + threadIdx.x;
    if (i < N_NODES) { deg[i] = 1.0f; counts[i] = 0; cursor[i] = 0; }
}

__global__ void k_deg_hist(const int* __restrict__ dst, const float* __restrict__ ea,
                           float* deg, int* counts) {
    int e = blockIdx.x * blockDim.x + threadIdx.x;
    if (e >= N_EDGES) return;
    int d = dst[e];
    atomicAdd(&deg[d], ea[e]);
    atomicAdd(&counts[d], 1);
}

// ---------------- exclusive scan (counts -> offsets), fused dinv ----------------
__global__ void k_scan_reduce(const int* __restrict__ counts, int* bsum, int n) {
    __shared__ int lds[256];
    int i = blockIdx.x * 256 + threadIdx.x;
    lds[threadIdx.x] = (i < n) ? counts[i] : 0;
    __syncthreads();
    for (int s = 128; s > 0; s >>= 1) {
        if (threadIdx.x < s) lds[threadIdx.x] += lds[threadIdx.x + s];
        __syncthreads();
    }
    if (threadIdx.x == 0) bsum[blockIdx.x] = lds[0];
}

__global__ void k_scan_bsum(int* bsum, int nb) {
    __shared__ int lds[256];
    int t = threadIdx.x;
    int v = (t < nb) ? bsum[t] : 0;
    lds[t] = v;
    __syncthreads();
    for (int s = 1; s < 256; s <<= 1) {
        int add = (t >= s) ? lds[t - s] : 0;
        __syncthreads();
        lds[t] += add;
        __syncthreads();
    }
    if (t < nb) bsum[t] = lds[t] - v;  // exclusive
}

__global__ void k_scan_final(const int* __restrict__ counts, const int* __restrict__ bsum,
                             int* offsets, float* deg, int n) {
    __shared__ int lds[256];
    int t = threadIdx.x;
    int i = blockIdx.x * 256 + t;
    int v = (i < n) ? counts[i] : 0;
    lds[t] = v;
    __syncthreads();
    for (int s = 1; s < 256; s <<= 1) {
        int add = (t >= s) ? lds[t - s] : 0;
        __syncthreads();
        lds[t] += add;
        __syncthreads();
    }
    int incl = lds[t];
    int base = bsum[blockIdx.x];
    if (i < n) {
        offsets[i] = base + incl - v;
        deg[i] = rsqrtf(deg[i]);  // deg >= 1 always
    }
    if (i == n - 1) offsets[n] = base + incl;
}

// ---------------- CSR scatter (by dst): packed {src, norm-weight} ----------------
__global__ void k_scatter(const int* __restrict__ src, const int* __restrict__ dst,
                          const float* __restrict__ ea, const float* __restrict__ dinv,
                          const int* __restrict__ offsets, int* cursor,
                          int2* __restrict__ edges) {
    int e = blockIdx.x * blockDim.x + threadIdx.x;
    if (e >= N_EDGES) return;
    int s = src[e], d = dst[e];
    int pos = offsets[d] + atomicAdd(&cursor[d], 1);
    edges[pos] = make_int2(s, __float_as_int(dinv[s] * ea[e] * dinv[d]));
}

// ---------------- GEMM1: p = x @ W_sg  (50000x512 @ 512x64), LDS-tiled ----------------
#define G1_ROWS 32
#define G1_KC 64
__global__ __launch_bounds__(256) void k_gemm1(const float* __restrict__ x,
                                               const float* __restrict__ W,
                                               float* __restrict__ p) {
    __shared__ float xs[G1_ROWS][G1_KC];     // 8 KB, broadcast reads
    __shared__ float wsT[64][G1_KC + 1];     // 16.6 KB, pad=1 -> conflict-free
    int tid = threadIdx.x;
    int wave = tid >> 6, lane = tid & 63;
    int r0 = blockIdx.x * G1_ROWS;
    int rbase = wave * 8;
    float acc[8];
#pragma unroll
    for (int j = 0; j < 8; j++) acc[j] = 0.f;

    for (int k0 = 0; k0 < IN_CH; k0 += G1_KC) {
        // stage x tile: 32 rows x 64 cols, coalesced
#pragma unroll
        for (int it = 0; it < 2; it++) {
            int idx4 = tid + it * 256;
            int row = idx4 >> 4, c0 = (idx4 & 15) * 4;
            float4 xv = make_float4(0.f, 0.f, 0.f, 0.f);
            if (r0 + row < N_NODES)
                xv = *(const float4*)(x + (size_t)(r0 + row) * IN_CH + k0 + c0);
            *(float4*)&xs[row][c0] = xv;
        }
        // stage W chunk transposed: wsT[c][k] = W[k0+k][c]
#pragma unroll
        for (int it = 0; it < 4; it++) {
            int idx4 = tid + it * 256;
            int k = idx4 >> 4, c0 = (idx4 & 15) * 4;
            float4 wv = *(const float4*)(W + (size_t)(k0 + k) * HID + c0);
            wsT[c0 + 0][k] = wv.x;
            wsT[c0 + 1][k] = wv.y;
            wsT[c0 + 2][k] = wv.z;
            wsT[c0 + 3][k] = wv.w;
        }
        __syncthreads();
#pragma unroll
        for (int kg = 0; kg < G1_KC / 4; kg++) {
            int k = kg * 4;
            float w0 = wsT[lane][k + 0];
            float w1 = wsT[lane][k + 1];
            float w2 = wsT[lane][k + 2];
            float w3 = wsT[lane][k + 3];
#pragma unroll
            for (int j = 0; j < 8; j++) {
                float4 xv = *(const float4*)&xs[rbase + j][k];
                acc[j] += xv.x * w0 + xv.y * w1 + xv.z * w2 + xv.w * w3;
            }
        }
        __syncthreads();
    }
#pragma unroll
    for (int j = 0; j < 8; j++) {
        int r = r0 + rbase + j;
        if (r < N_NODES) p[(size_t)r * HID + lane] = acc[j];
    }
}

// ---------------- one normalized-adjacency hop ----------------
__global__ __launch_bounds__(256) void k_hop(const float* __restrict__ hin,
                                             const int* __restrict__ offsets,
                                             const int2* __restrict__ edges,
                                             const float* __restrict__ dinv,
                                             float* __restrict__ hout) {
    int v = blockIdx.x * 4 + (threadIdx.x >> 6);
    int lane = threadIdx.x & 63;
    if (v >= N_NODES) return;
    float dv = dinv[v];
    float acc = dv * dv * hin[(size_t)v * HID + lane];  // self-loop
    int beg = offsets[v], end = offsets[v + 1];
    for (int i = beg; i < end; i++) {
        int2 e = edges[i];
        acc += __int_as_float(e.y) * hin[(size_t)e.x * HID + lane];
    }
    hout[(size_t)v * HID + lane] = acc;
}

// ---------------- bias + SELU + GEMM2 (g interleaved float2) + att dots ----------------
__global__ __launch_bounds__(256) void k_act_gemm2(const float* __restrict__ h2,
                                                   const float* __restrict__ bsg,
                                                   const float* __restrict__ Wg,
                                                   const float* __restrict__ att_s,
                                                   const float* __restrict__ att_d,
                                                   float2* __restrict__ g2,
                                                   float4* __restrict__ asd) {
    __shared__ float hs[G1_ROWS][HID];   // 8 KB
    __shared__ float2 wg2[HID][64];      // 32 KB: (head0, head1) per [k][c]
    int tid = threadIdx.x;
    int wave = tid >> 6, lane = tid & 63;
    int r0 = blockIdx.x * G1_ROWS;
    int rbase = wave * 8;

    // stage Wg interleaved
    for (int idx = tid; idx < HID * 64; idx += 256) {
        int k = idx >> 6, c = idx & 63;
        wg2[k][c] = make_float2(Wg[(size_t)k * 128 + c], Wg[(size_t)k * 128 + 64 + c]);
    }
    // stage h rows with bias + SELU
    const float SC = 1.0507009873554805f, AL = 1.6732632423543772f;
#pragma unroll
    for (int it = 0; it < 2; it++) {
        int idx4 = tid + it * 256;
        int row = idx4 >> 4, c0 = (idx4 & 15) * 4;
        float4 hv = make_float4(0.f, 0.f, 0.f, 0.f);
        if (r0 + row < N_NODES)
            hv = *(const float4*)(h2 + (size_t)(r0 + row) * HID + c0);
        float b0 = bsg[c0], b1 = bsg[c0 + 1], b2 = bsg[c0 + 2], b3 = bsg[c0 + 3];
        float v0 = hv.x + b0, v1 = hv.y + b1, v2 = hv.z + b2, v3 = hv.w + b3;
        v0 = (v0 > 0.f) ? SC * v0 : SC * AL * (__expf(v0) - 1.f);
        v1 = (v1 > 0.f) ? SC * v1 : SC * AL * (__expf(v1) - 1.f);
        v2 = (v2 > 0.f) ? SC * v2 : SC * AL * (__expf(v2) - 1.f);
        v3 = (v3 > 0.f) ? SC * v3 : SC * AL * (__expf(v3) - 1.f);
        *(float4*)&hs[row][c0] = make_float4(v0, v1, v2, v3);
    }
    __syncthreads();

    float2 accg[8];
#pragma unroll
    for (int j = 0; j < 8; j++) accg[j] = make_float2(0.f, 0.f);
#pragma unroll
    for (int kg = 0; kg < HID / 4; kg++) {
        int k = kg * 4;
        float2 wv0 = wg2[k + 0][lane];
        float2 wv1 = wg2[k + 1][lane];
        float2 wv2 = wg2[k + 2][lane];
        float2 wv3 = wg2[k + 3][lane];
#pragma unroll
        for (int j = 0; j < 8; j++) {
            float4 hv = *(const float4*)&hs[rbase + j][k];
            accg[j].x += hv.x * wv0.x + hv.y * wv1.x + hv.z * wv2.x + hv.w * wv3.x;
            accg[j].y += hv.x * wv0.y + hv.y * wv1.y + hv.z * wv2.y + hv.w * wv3.y;
        }
    }
    float ats0 = att_s[lane], ats1 = att_s[64 + lane];
    float atd0 = att_d[lane], atd1 = att_d[64 + lane];
#pragma unroll
    for (int j = 0; j < 8; j++) {
        int v = r0 + rbase + j;
        if (v >= N_NODES) break;
        g2[(size_t)v * 64 + lane] = accg[j];
        float s0 = accg[j].x * ats0, s1 = accg[j].y * ats1;
        float d0 = accg[j].x * atd0, d1 = accg[j].y * atd1;
#pragma unroll
        for (int o = 32; o > 0; o >>= 1) {
            s0 += __shfl_xor(s0, o);
            s1 += __shfl_xor(s1, o);
            d0 += __shfl_xor(d0, o);
            d1 += __shfl_xor(d1, o);
        }
        if (lane == 0) asd[v] = make_float4(s0, s1, d0, d1);
    }
}

// ---------------- GAT aggregation: online softmax, one wave per node ----------------
__global__ __launch_bounds__(256) void k_gat(const float2* __restrict__ g2,
                                             const float4* __restrict__ asd,
                                             const int* __restrict__ offsets,
                                             const int2* __restrict__ edges,
                                             const float* __restrict__ bgat,
                                             float* __restrict__ out) {
    int v = blockIdx.x * 4 + (threadIdx.x >> 6);
    int lane = threadIdx.x & 63;
    if (v >= N_NODES) return;
    float4 av = asd[v];
    float ad0 = av.z, ad1 = av.w;
    // self-loop seeds the online softmax
    float e0 = av.x + ad0; e0 = (e0 > 0.f) ? e0 : NEG_SLOPE * e0;
    float e1 = av.y + ad1; e1 = (e1 > 0.f) ? e1 : NEG_SLOPE * e1;
    float m0 = e0, m1 = e1;
    float den0 = 1.f, den1 = 1.f;
    float2 gv = g2[(size_t)v * 64 + lane];
    float acc0 = gv.x, acc1 = gv.y;
    int beg = offsets[v], end = offsets[v + 1];
    for (int i = beg; i < end; i++) {
        int s = edges[i].x;
        float2 as2 = *(const float2*)&asd[s];
        float t0 = as2.x + ad0; t0 = (t0 > 0.f) ? t0 : NEG_SLOPE * t0;
        float t1 = as2.y + ad1; t1 = (t1 > 0.f) ? t1 : NEG_SLOPE * t1;
        float2 gs = g2[(size_t)s * 64 + lane];
        if (t0 > m0) {
            float sc = __expf(m0 - t0);
            acc0 = acc0 * sc + gs.x;
            den0 = den0 * sc + 1.f;
            m0 = t0;
        } else {
            float p = __expf(t0 - m0);
            acc0 += p * gs.x;
            den0 += p;
        }
        if (t1 > m1) {
            float sc = __expf(m1 - t1);
            acc1 = acc1 * sc + gs.y;
            den1 = den1 * sc + 1.f;
            m1 = t1;
        } else {
            float p = __expf(t1 - m1);
            acc1 += p * gs.y;
            den1 += p;
        }
    }
    out[(size_t)v * OUTC + lane] = 0.5f * (acc0 / den0 + acc1 / den1) + bgat[lane];
}

extern "C" void kernel_launch(void* const* d_in, const int* in_sizes, int n_in,
                              void* d_out, int out_size, void* d_ws, size_t ws_size,
                              hipStream_t stream) {
    const float* x     = (const float*)d_in[0];
    const int*   ei    = (const int*)d_in[1];
    const float* ea    = (const float*)d_in[2];
    const float* Wsg   = (const float*)d_in[3];
    const float* bsg   = (const float*)d_in[4];
    const float* Wg    = (const float*)d_in[5];
    const float* att_s = (const float*)d_in[6];
    const float* att_d = (const float*)d_in[7];
    const float* bgat  = (const float*)d_in[8];
    const int* src = ei;
    const int* dst = ei + N_EDGES;
    float* out = (float*)d_out;

    char* ws = (char*)d_ws;
    size_t off = 0;
    auto alloc = [&](size_t bytes) -> void* {
        void* p = ws + off;
        off = (off + bytes + 255) & ~(size_t)255;
        return p;
    };
    float*  deg    = (float*)alloc((size_t)N_NODES * 4);        // becomes dinv
    int*    counts = (int*)alloc((size_t)N_NODES * 4);
    int*    offs   = (int*)alloc((size_t)(N_NODES + 1) * 4);
    int*    cursor = (int*)alloc((size_t)N_NODES * 4);
    int*    bsum   = (int*)alloc(256 * 4);
    int2*   edges  = (int2*)alloc((size_t)N_EDGES * 8);
    float*  h0     = (float*)alloc((size_t)N_NODES * HID * 4);
    float*  h1     = (float*)alloc((size_t)N_NODES * HID * 4);
    float2* g2     = (float2*)alloc((size_t)N_NODES * 64 * 8);
    float4* asd    = (float4*)alloc((size_t)N_NODES * 16);
    (void)ws_size; (void)in_sizes; (void)n_in; (void)out_size;

    k_init<<<(N_NODES + 255) / 256, 256, 0, stream>>>(deg, counts, cursor);
    k_deg_hist<<<(N_EDGES + 255) / 256, 256, 0, stream>>>(dst, ea, deg, counts);

    int nb = (N_NODES + 255) / 256;  // 196
    k_scan_reduce<<<nb, 256, 0, stream>>>(counts, bsum, N_NODES);
    k_scan_bsum<<<1, 256, 0, stream>>>(bsum, nb);
    k_scan_final<<<nb, 256, 0, stream>>>(counts, bsum, offs, deg, N_NODES);

    k_scatter<<<(N_EDGES + 255) / 256, 256, 0, stream>>>(src, dst, ea, deg, offs, cursor, edges);

    int gblocks = (N_NODES + G1_ROWS - 1) / G1_ROWS;  // 1563
    k_gemm1<<<gblocks, 256, 0, stream>>>(x, Wsg, h0);
    k_hop<<<N_NODES / 4, 256, 0, stream>>>(h0, offs, edges, deg, h1);
    k_hop<<<N_NODES / 4, 256, 0, stream>>>(h1, offs, edges, deg, h0);
    k_act_gemm2<<<gblocks, 256, 0, stream>>>(h0, bsg, Wg, att_s, att_d, g2, asd);
    k_gat<<<N_NODES / 4, 256, 0, stream>>>(g2, asd, offs, edges, bgat, out);
}

// Round 3
// 847.647 us; speedup vs baseline: 1.1869x; 1.1434x over previous
//
#include <hip/hip_runtime.h>
#include <math.h>

#define N_NODES 50000
#define N_EDGES 1600000
#define IN_CH 512
#define HID 64
#define OUTC 64
#define NEG_SLOPE 0.2f
#define NBUCK 8
#define BUCK_DIV 6250   // 50000 / 8
#define NCNT (N_NODES * NBUCK)

// ---------------- init: deg=1 (self-loop), counts2=0, cursor2=0 ----------------
__global__ void k_init(float* deg, int* counts2, int* cursor2) {
    int i = blockIdx.x * blockDim.x + threadIdx.x;
    if (i < N_NODES) deg[i] = 1.0f;
    if (i < NCNT) { counts2[i] = 0; cursor2[i] = 0; }
}

__global__ void k_deg_hist(const int* __restrict__ src, const int* __restrict__ dst,
                           const float* __restrict__ ea,
                           float* deg, int* counts2) {
    int e = blockIdx.x * blockDim.x + threadIdx.x;
    if (e >= N_EDGES) return;
    int d = dst[e];
    int b = src[e] / BUCK_DIV;
    atomicAdd(&deg[d], ea[e]);
    atomicAdd(&counts2[d * NBUCK + b], 1);
}

__global__ void k_dinv(float* deg) {
    int i = blockIdx.x * blockDim.x + threadIdx.x;
    if (i < N_NODES) deg[i] = rsqrtf(deg[i]);  // deg >= 1 always
}

// ---------------- 3-level exclusive scan over counts2 (400000) ----------------
__global__ void k_scan_reduce(const int* __restrict__ counts, int* bsum, int n) {
    __shared__ int lds[256];
    int i = blockIdx.x * 256 + threadIdx.x;
    lds[threadIdx.x] = (i < n) ? counts[i] : 0;
    __syncthreads();
    for (int s = 128; s > 0; s >>= 1) {
        if (threadIdx.x < s) lds[threadIdx.x] += lds[threadIdx.x + s];
        __syncthreads();
    }
    if (threadIdx.x == 0) bsum[blockIdx.x] = lds[0];
}

__global__ void k_scan_mid(int* bsum, int nb) {
    __shared__ int lds[256];
    __shared__ int carry;
    int t = threadIdx.x;
    if (t == 0) carry = 0;
    __syncthreads();
    for (int base = 0; base < nb; base += 256) {
        int i = base + t;
        int v = (i < nb) ? bsum[i] : 0;
        int orig = v;
        lds[t] = v;
        __syncthreads();
        for (int s = 1; s < 256; s <<= 1) {
            int add = (t >= s) ? lds[t - s] : 0;
            __syncthreads();
            lds[t] += add;
            __syncthreads();
        }
        int c = carry;
        if (i < nb) bsum[i] = lds[t] - orig + c;  // exclusive + carry
        __syncthreads();
        if (t == 0) carry = c + lds[255];
        __syncthreads();
    }
}

__global__ void k_scan_final(const int* __restrict__ counts, const int* __restrict__ bsum,
                             int* offsets, int n) {
    __shared__ int lds[256];
    int t = threadIdx.x;
    int i = blockIdx.x * 256 + t;
    int v = (i < n) ? counts[i] : 0;
    lds[t] = v;
    __syncthreads();
    for (int s = 1; s < 256; s <<= 1) {
        int add = (t >= s) ? lds[t - s] : 0;
        __syncthreads();
        lds[t] += add;
        __syncthreads();
    }
    int incl = lds[t];
    int base = bsum[blockIdx.x];
    if (i < n) offsets[i] = base + incl - v;
    if (i == n - 1) offsets[n] = base + incl;
}

// ---------------- CSR scatter (by dst, src-bucketed): packed {src, weight} ----------------
__global__ void k_scatter(const int* __restrict__ src, const int* __restrict__ dst,
                          const float* __restrict__ ea, const float* __restrict__ dinv,
                          const int* __restrict__ offsets2, int* cursor2,
                          int2* __restrict__ edges) {
    int e = blockIdx.x * blockDim.x + threadIdx.x;
    if (e >= N_EDGES) return;
    int s = src[e], d = dst[e];
    int slot = d * NBUCK + s / BUCK_DIV;
    int pos = offsets2[slot] + atomicAdd(&cursor2[slot], 1);
    edges[pos] = make_int2(s, __float_as_int(dinv[s] * ea[e] * dinv[d]));
}

// ---------------- GEMM1: p = x @ W_sg  (50000x512 @ 512x64), LDS-tiled ----------------
#define G1_ROWS 32
#define G1_KC 64
__global__ __launch_bounds__(256) void k_gemm1(const float* __restrict__ x,
                                               const float* __restrict__ W,
                                               float* __restrict__ p) {
    __shared__ float xs[G1_ROWS][G1_KC];     // 8 KB, broadcast reads
    __shared__ float wsT[64][G1_KC + 1];     // 16.6 KB, pad=1 -> conflict-free
    int tid = threadIdx.x;
    int wave = tid >> 6, lane = tid & 63;
    int r0 = blockIdx.x * G1_ROWS;
    int rbase = wave * 8;
    float acc[8];
#pragma unroll
    for (int j = 0; j < 8; j++) acc[j] = 0.f;

    for (int k0 = 0; k0 < IN_CH; k0 += G1_KC) {
#pragma unroll
        for (int it = 0; it < 2; it++) {
            int idx4 = tid + it * 256;
            int row = idx4 >> 4, c0 = (idx4 & 15) * 4;
            float4 xv = make_float4(0.f, 0.f, 0.f, 0.f);
            if (r0 + row < N_NODES)
                xv = *(const float4*)(x + (size_t)(r0 + row) * IN_CH + k0 + c0);
            *(float4*)&xs[row][c0] = xv;
        }
#pragma unroll
        for (int it = 0; it < 4; it++) {
            int idx4 = tid + it * 256;
            int k = idx4 >> 4, c0 = (idx4 & 15) * 4;
            float4 wv = *(const float4*)(W + (size_t)(k0 + k) * HID + c0);
            wsT[c0 + 0][k] = wv.x;
            wsT[c0 + 1][k] = wv.y;
            wsT[c0 + 2][k] = wv.z;
            wsT[c0 + 3][k] = wv.w;
        }
        __syncthreads();
#pragma unroll
        for (int kg = 0; kg < G1_KC / 4; kg++) {
            int k = kg * 4;
            float w0 = wsT[lane][k + 0];
            float w1 = wsT[lane][k + 1];
            float w2 = wsT[lane][k + 2];
            float w3 = wsT[lane][k + 3];
#pragma unroll
            for (int j = 0; j < 8; j++) {
                float4 xv = *(const float4*)&xs[rbase + j][k];
                acc[j] += xv.x * w0 + xv.y * w1 + xv.z * w2 + xv.w * w3;
            }
        }
        __syncthreads();
    }
#pragma unroll
    for (int j = 0; j < 8; j++) {
        int r = r0 + rbase + j;
        if (r < N_NODES) p[(size_t)r * HID + lane] = acc[j];
    }
}

// ---------------- one normalized-adjacency hop (bucketed CSR) ----------------
__global__ __launch_bounds__(256) void k_hop(const float* __restrict__ hin,
                                             const int* __restrict__ offs2,
                                             const int2* __restrict__ edges,
                                             const float* __restrict__ dinv,
                                             float* __restrict__ hout) {
    int v = blockIdx.x * 4 + (threadIdx.x >> 6);
    int lane = threadIdx.x & 63;
    if (v >= N_NODES) return;
    float dv = dinv[v];
    float acc = dv * dv * hin[(size_t)v * HID + lane];  // self-loop
    int beg = offs2[v * NBUCK], end = offs2[(v + 1) * NBUCK];
    for (int i = beg; i < end; i++) {
        int2 e = edges[i];
        acc += __int_as_float(e.y) * hin[(size_t)e.x * HID + lane];
    }
    hout[(size_t)v * HID + lane] = acc;
}

// ---------------- bias + SELU + GEMM2 (g interleaved float2) + att dots ----------------
__global__ __launch_bounds__(256) void k_act_gemm2(const float* __restrict__ h2,
                                                   const float* __restrict__ bsg,
                                                   const float* __restrict__ Wg,
                                                   const float* __restrict__ att_s,
                                                   const float* __restrict__ att_d,
                                                   float2* __restrict__ g2,
                                                   float4* __restrict__ asd) {
    __shared__ float hs[G1_ROWS][HID];   // 8 KB
    int tid = threadIdx.x;
    int wave = tid >> 6, lane = tid & 63;
    int r0 = blockIdx.x * G1_ROWS;
    int rbase = wave * 8;

    // stage h rows with bias + SELU
    const float SC = 1.0507009873554805f, AL = 1.6732632423543772f;
#pragma unroll
    for (int it = 0; it < 2; it++) {
        int idx4 = tid + it * 256;
        int row = idx4 >> 4, c0 = (idx4 & 15) * 4;
        float4 hv = make_float4(0.f, 0.f, 0.f, 0.f);
        if (r0 + row < N_NODES)
            hv = *(const float4*)(h2 + (size_t)(r0 + row) * HID + c0);
        float v0 = hv.x + bsg[c0], v1 = hv.y + bsg[c0 + 1];
        float v2 = hv.z + bsg[c0 + 2], v3 = hv.w + bsg[c0 + 3];
        v0 = (v0 > 0.f) ? SC * v0 : SC * AL * (__expf(v0) - 1.f);
        v1 = (v1 > 0.f) ? SC * v1 : SC * AL * (__expf(v1) - 1.f);
        v2 = (v2 > 0.f) ? SC * v2 : SC * AL * (__expf(v2) - 1.f);
        v3 = (v3 > 0.f) ? SC * v3 : SC * AL * (__expf(v3) - 1.f);
        *(float4*)&hs[row][c0] = make_float4(v0, v1, v2, v3);
    }
    __syncthreads();

    float2 accg[8];
#pragma unroll
    for (int j = 0; j < 8; j++) accg[j] = make_float2(0.f, 0.f);
#pragma unroll 2
    for (int k = 0; k < HID; k++) {
        float w0 = Wg[(size_t)k * 128 + lane];        // coalesced, L1-resident
        float w1 = Wg[(size_t)k * 128 + 64 + lane];
#pragma unroll
        for (int j = 0; j < 8; j++) {
            float hk = hs[rbase + j][k];              // LDS broadcast
            accg[j].x += hk * w0;
            accg[j].y += hk * w1;
        }
    }
    float ats0 = att_s[lane], ats1 = att_s[64 + lane];
    float atd0 = att_d[lane], atd1 = att_d[64 + lane];
#pragma unroll
    for (int j = 0; j < 8; j++) {
        int v = r0 + rbase + j;
        if (v >= N_NODES) break;
        g2[(size_t)v * 64 + lane] = accg[j];
        float s0 = accg[j].x * ats0, s1 = accg[j].y * ats1;
        float d0 = accg[j].x * atd0, d1 = accg[j].y * atd1;
#pragma unroll
        for (int o = 32; o > 0; o >>= 1) {
            s0 += __shfl_xor(s0, o);
            s1 += __shfl_xor(s1, o);
            d0 += __shfl_xor(d0, o);
            d1 += __shfl_xor(d1, o);
        }
        if (lane == 0) asd[v] = make_float4(s0, s1, d0, d1);
    }
}

// ---------------- GAT aggregation: online softmax, one wave per node ----------------
__global__ __launch_bounds__(256) void k_gat(const float2* __restrict__ g2,
                                             const float4* __restrict__ asd,
                                             const int* __restrict__ offs2,
                                             const int2* __restrict__ edges,
                                             const float* __restrict__ bgat,
                                             float* __restrict__ out) {
    int v = blockIdx.x * 4 + (threadIdx.x >> 6);
    int lane = threadIdx.x & 63;
    if (v >= N_NODES) return;
    float4 av = asd[v];
    float ad0 = av.z, ad1 = av.w;
    float e0 = av.x + ad0; e0 = (e0 > 0.f) ? e0 : NEG_SLOPE * e0;
    float e1 = av.y + ad1; e1 = (e1 > 0.f) ? e1 : NEG_SLOPE * e1;
    float m0 = e0, m1 = e1;
    float den0 = 1.f, den1 = 1.f;
    float2 gv = g2[(size_t)v * 64 + lane];
    float acc0 = gv.x, acc1 = gv.y;
    int beg = offs2[v * NBUCK], end = offs2[(v + 1) * NBUCK];
    for (int i = beg; i < end; i++) {
        int s = edges[i].x;
        float2 as2 = *(const float2*)&asd[s];
        float t0 = as2.x + ad0; t0 = (t0 > 0.f) ? t0 : NEG_SLOPE * t0;
        float t1 = as2.y + ad1; t1 = (t1 > 0.f) ? t1 : NEG_SLOPE * t1;
        float2 gs = g2[(size_t)s * 64 + lane];
        if (t0 > m0) {
            float sc = __expf(m0 - t0);
            acc0 = acc0 * sc + gs.x;
            den0 = den0 * sc + 1.f;
            m0 = t0;
        } else {
            float p = __expf(t0 - m0);
            acc0 += p * gs.x;
            den0 += p;
        }
        if (t1 > m1) {
            float sc = __expf(m1 - t1);
            acc1 = acc1 * sc + gs.y;
            den1 = den1 * sc + 1.f;
            m1 = t1;
        } else {
            float p = __expf(t1 - m1);
            acc1 += p * gs.y;
            den1 += p;
        }
    }
    out[(size_t)v * OUTC + lane] = 0.5f * (acc0 / den0 + acc1 / den1) + bgat[lane];
}

extern "C" void kernel_launch(void* const* d_in, const int* in_sizes, int n_in,
                              void* d_out, int out_size, void* d_ws, size_t ws_size,
                              hipStream_t stream) {
    const float* x     = (const float*)d_in[0];
    const int*   ei    = (const int*)d_in[1];
    const float* ea    = (const float*)d_in[2];
    const float* Wsg   = (const float*)d_in[3];
    const float* bsg   = (const float*)d_in[4];
    const float* Wg    = (const float*)d_in[5];
    const float* att_s = (const float*)d_in[6];
    const float* att_d = (const float*)d_in[7];
    const float* bgat  = (const float*)d_in[8];
    const int* src = ei;
    const int* dst = ei + N_EDGES;
    float* out = (float*)d_out;

    char* ws = (char*)d_ws;
    size_t off = 0;
    auto alloc = [&](size_t bytes) -> void* {
        void* p = ws + off;
        off = (off + bytes + 255) & ~(size_t)255;
        return p;
    };
    float*  deg     = (float*)alloc((size_t)N_NODES * 4);        // becomes dinv
    int*    counts2 = (int*)alloc((size_t)NCNT * 4);
    int*    offs2   = (int*)alloc((size_t)(NCNT + 1) * 4);
    int*    cursor2 = (int*)alloc((size_t)NCNT * 4);
    int*    bsum    = (int*)alloc(2048 * 4);
    int2*   edges   = (int2*)alloc((size_t)N_EDGES * 8);
    float*  h0      = (float*)alloc((size_t)N_NODES * HID * 4);
    float*  h1      = (float*)alloc((size_t)N_NODES * HID * 4);
    float2* g2      = (float2*)alloc((size_t)N_NODES * 64 * 8);
    float4* asd     = (float4*)alloc((size_t)N_NODES * 16);
    (void)ws_size; (void)in_sizes; (void)n_in; (void)out_size;

    int nbc = (NCNT + 255) / 256;  // 1563

    k_init<<<nbc, 256, 0, stream>>>(deg, counts2, cursor2);
    k_deg_hist<<<(N_EDGES + 255) / 256, 256, 0, stream>>>(src, dst, ea, deg, counts2);
    k_dinv<<<(N_NODES + 255) / 256, 256, 0, stream>>>(deg);

    k_scan_reduce<<<nbc, 256, 0, stream>>>(counts2, bsum, NCNT);
    k_scan_mid<<<1, 256, 0, stream>>>(bsum, nbc);
    k_scan_final<<<nbc, 256, 0, stream>>>(counts2, bsum, offs2, NCNT);

    k_scatter<<<(N_EDGES + 255) / 256, 256, 0, stream>>>(src, dst, ea, deg, offs2, cursor2, edges);

    int gblocks = (N_NODES + G1_ROWS - 1) / G1_ROWS;  // 1563
    k_gemm1<<<gblocks, 256, 0, stream>>>(x, Wsg, h0);
    k_hop<<<N_NODES / 4, 256, 0, stream>>>(h0, offs2, edges, deg, h1);
    k_hop<<<N_NODES / 4, 256, 0, stream>>>(h1, offs2, edges, deg, h0);
    k_act_gemm2<<<gblocks, 256, 0, stream>>>(h0, bsg, Wg, att_s, att_d, g2, asd);
    k_gat<<<N_NODES / 4, 256, 0, stream>>>(g2, asd, offs2, edges, bgat, out);
}

// Round 4
// 731.531 us; speedup vs baseline: 1.3753x; 1.1587x over previous
//
#include <hip/hip_runtime.h>
#include <math.h>

#define N_NODES 50000
#define N_EDGES 1600000
#define IN_CH 512
#define HID 64
#define OUTC 64
#define NEG_SLOPE 0.2f

// ---------------- init: deg=1 (self-loop), counts=0, cursor=0 ----------------
__global__ void k_init(float* deg, int* counts, int* cursor) {
    int i = blockIdx.x * blockDim.x + threadIdx.x;
    if (i < N_NODES) { deg[i] = 1.0f; counts[i] = 0; cursor[i] = 0; }
}

__global__ void k_deg_hist(const int* __restrict__ dst, const float* __restrict__ ea,
                           float* deg, int* counts) {
    int e = blockIdx.x * blockDim.x + threadIdx.x;
    if (e >= N_EDGES) return;
    int d = dst[e];
    atomicAdd(&deg[d], ea[e]);
    atomicAdd(&counts[d], 1);
}

// ---------------- scan level 1 (+ fused dinv) ----------------
__global__ void k_scan_reduce(const int* __restrict__ counts, int* bsum, float* deg, int n) {
    __shared__ int lds[256];
    int i = blockIdx.x * 256 + threadIdx.x;
    lds[threadIdx.x] = (i < n) ? counts[i] : 0;
    if (i < n) deg[i] = rsqrtf(deg[i]);  // deg >= 1 always
    __syncthreads();
    for (int s = 128; s > 0; s >>= 1) {
        if (threadIdx.x < s) lds[threadIdx.x] += lds[threadIdx.x + s];
        __syncthreads();
    }
    if (threadIdx.x == 0) bsum[blockIdx.x] = lds[0];
}

__global__ void k_scan_bsum(int* bsum, int nb) {
    __shared__ int lds[256];
    int t = threadIdx.x;
    int v = (t < nb) ? bsum[t] : 0;
    lds[t] = v;
    __syncthreads();
    for (int s = 1; s < 256; s <<= 1) {
        int add = (t >= s) ? lds[t - s] : 0;
        __syncthreads();
        lds[t] += add;
        __syncthreads();
    }
    if (t < nb) bsum[t] = lds[t] - v;  // exclusive
}

__global__ void k_scan_final(const int* __restrict__ counts, const int* __restrict__ bsum,
                             int* offsets, int n) {
    __shared__ int lds[256];
    int t = threadIdx.x;
    int i = blockIdx.x * 256 + t;
    int v = (i < n) ? counts[i] : 0;
    lds[t] = v;
    __syncthreads();
    for (int s = 1; s < 256; s <<= 1) {
        int add = (t >= s) ? lds[t - s] : 0;
        __syncthreads();
        lds[t] += add;
        __syncthreads();
    }
    int incl = lds[t];
    int base = bsum[blockIdx.x];
    if (i < n) offsets[i] = base + incl - v;
    if (i == n - 1) offsets[n] = base + incl;
}

// ---------------- CSR scatter (by dst): packed {src, norm-weight} ----------------
__global__ void k_scatter(const int* __restrict__ src, const int* __restrict__ dst,
                          const float* __restrict__ ea, const float* __restrict__ dinv,
                          const int* __restrict__ offsets, int* cursor,
                          int2* __restrict__ edges) {
    int e = blockIdx.x * blockDim.x + threadIdx.x;
    if (e >= N_EDGES) return;
    int s = src[e], d = dst[e];
    int pos = offsets[d] + atomicAdd(&cursor[d], 1);
    edges[pos] = make_int2(s, __float_as_int(dinv[s] * ea[e] * dinv[d]));
}

// ---------------- GEMM1: p = x @ W_sg  (50000x512 @ 512x64), LDS-tiled ----------------
#define G1_ROWS 64
#define G1_KC 64
__global__ __launch_bounds__(512) void k_gemm1(const float* __restrict__ x,
                                               const float* __restrict__ W,
                                               float* __restrict__ p) {
    __shared__ float xs[G1_ROWS][G1_KC];     // 16 KB, broadcast reads
    __shared__ float wsT[64][G1_KC + 1];     // 16.6 KB
    int tid = threadIdx.x;
    int wave = tid >> 6, lane = tid & 63;
    int r0 = blockIdx.x * G1_ROWS;
    int rbase = wave * 8;
    float acc[8];
#pragma unroll
    for (int j = 0; j < 8; j++) acc[j] = 0.f;

    for (int k0 = 0; k0 < IN_CH; k0 += G1_KC) {
#pragma unroll
        for (int it = 0; it < 2; it++) {
            int idx4 = tid + it * 512;               // 0..1023
            int row = idx4 >> 4, c0 = (idx4 & 15) * 4;
            float4 xv = make_float4(0.f, 0.f, 0.f, 0.f);
            if (r0 + row < N_NODES)
                xv = *(const float4*)(x + (size_t)(r0 + row) * IN_CH + k0 + c0);
            *(float4*)&xs[row][c0] = xv;
        }
#pragma unroll
        for (int it = 0; it < 2; it++) {
            int idx4 = tid + it * 512;
            int k = idx4 >> 4, c0 = (idx4 & 15) * 4;
            float4 wv = *(const float4*)(W + (size_t)(k0 + k) * HID + c0);
            wsT[c0 + 0][k] = wv.x;
            wsT[c0 + 1][k] = wv.y;
            wsT[c0 + 2][k] = wv.z;
            wsT[c0 + 3][k] = wv.w;
        }
        __syncthreads();
#pragma unroll
        for (int kg = 0; kg < G1_KC / 4; kg++) {
            int k = kg * 4;
            float w0 = wsT[lane][k + 0];
            float w1 = wsT[lane][k + 1];
            float w2 = wsT[lane][k + 2];
            float w3 = wsT[lane][k + 3];
#pragma unroll
            for (int j = 0; j < 8; j++) {
                float4 xv = *(const float4*)&xs[rbase + j][k];
                acc[j] += xv.x * w0 + xv.y * w1 + xv.z * w2 + xv.w * w3;
            }
        }
        __syncthreads();
    }
#pragma unroll
    for (int j = 0; j < 8; j++) {
        int r = r0 + rbase + j;
        if (r < N_NODES) p[(size_t)r * HID + lane] = acc[j];
    }
}

// ---------------- one hop: 2 waves per node (edge-range split), LDS combine ----------------
__global__ __launch_bounds__(256) void k_hop(const float* __restrict__ hin,
                                             const int* __restrict__ offsets,
                                             const int2* __restrict__ edges,
                                             const float* __restrict__ dinv,
                                             float* __restrict__ hout) {
    __shared__ float part[2][64];
    int tid = threadIdx.x;
    int w = tid >> 6, lane = tid & 63;
    int slot = w >> 1, half = w & 1;
    int v = blockIdx.x * 2 + slot;          // grid = N/2, always valid
    int beg = offsets[v], end = offsets[v + 1];
    int mid = beg + ((end - beg) >> 1);
    int lo = half ? mid : beg;
    int hi = half ? end : mid;
    float acc = 0.f, acc2 = 0.f;
    if (!half) {
        float dv = dinv[v];
        acc = dv * dv * hin[(size_t)v * HID + lane];  // self-loop
    }
    int i = lo;
    for (; i + 2 <= hi; i += 2) {
        int2 e0 = edges[i];
        int2 e1 = edges[i + 1];
        float h0 = hin[(size_t)e0.x * HID + lane];
        float h1 = hin[(size_t)e1.x * HID + lane];
        acc += __int_as_float(e0.y) * h0;
        acc2 += __int_as_float(e1.y) * h1;
    }
    if (i < hi) {
        int2 e0 = edges[i];
        acc += __int_as_float(e0.y) * hin[(size_t)e0.x * HID + lane];
    }
    acc += acc2;
    if (half) part[slot][lane] = acc;
    __syncthreads();
    if (!half) hout[(size_t)v * HID + lane] = acc + part[slot][lane];
}

// ---------------- bias + SELU + GEMM2 (per-head g arrays) + att dots ----------------
#define G2_ROWS 32
__global__ __launch_bounds__(256) void k_act_gemm2(const float* __restrict__ h2,
                                                   const float* __restrict__ bsg,
                                                   const float* __restrict__ Wg,
                                                   const float* __restrict__ att_s,
                                                   const float* __restrict__ att_d,
                                                   float* __restrict__ g0o,
                                                   float* __restrict__ g1o,
                                                   float4* __restrict__ asd) {
    __shared__ float hs[G2_ROWS][HID];   // 8 KB
    int tid = threadIdx.x;
    int wave = tid >> 6, lane = tid & 63;
    int r0 = blockIdx.x * G2_ROWS;
    int rbase = wave * 8;

    const float SC = 1.0507009873554805f, AL = 1.6732632423543772f;
#pragma unroll
    for (int it = 0; it < 2; it++) {
        int idx4 = tid + it * 256;
        int row = idx4 >> 4, c0 = (idx4 & 15) * 4;
        float4 hv = make_float4(0.f, 0.f, 0.f, 0.f);
        if (r0 + row < N_NODES)
            hv = *(const float4*)(h2 + (size_t)(r0 + row) * HID + c0);
        float v0 = hv.x + bsg[c0], v1 = hv.y + bsg[c0 + 1];
        float v2 = hv.z + bsg[c0 + 2], v3 = hv.w + bsg[c0 + 3];
        v0 = (v0 > 0.f) ? SC * v0 : SC * AL * (__expf(v0) - 1.f);
        v1 = (v1 > 0.f) ? SC * v1 : SC * AL * (__expf(v1) - 1.f);
        v2 = (v2 > 0.f) ? SC * v2 : SC * AL * (__expf(v2) - 1.f);
        v3 = (v3 > 0.f) ? SC * v3 : SC * AL * (__expf(v3) - 1.f);
        *(float4*)&hs[row][c0] = make_float4(v0, v1, v2, v3);
    }
    __syncthreads();

    float accx[8], accy[8];
#pragma unroll
    for (int j = 0; j < 8; j++) { accx[j] = 0.f; accy[j] = 0.f; }
#pragma unroll 2
    for (int k = 0; k < HID; k++) {
        float w0 = Wg[(size_t)k * 128 + lane];        // coalesced, L1-resident
        float w1 = Wg[(size_t)k * 128 + 64 + lane];
#pragma unroll
        for (int j = 0; j < 8; j++) {
            float hk = hs[rbase + j][k];              // LDS broadcast
            accx[j] += hk * w0;
            accy[j] += hk * w1;
        }
    }
    float ats0 = att_s[lane], ats1 = att_s[64 + lane];
    float atd0 = att_d[lane], atd1 = att_d[64 + lane];
#pragma unroll
    for (int j = 0; j < 8; j++) {
        int v = r0 + rbase + j;
        if (v >= N_NODES) break;
        g0o[(size_t)v * 64 + lane] = accx[j];
        g1o[(size_t)v * 64 + lane] = accy[j];
        float s0 = accx[j] * ats0, s1 = accy[j] * ats1;
        float d0 = accx[j] * atd0, d1 = accy[j] * atd1;
#pragma unroll
        for (int o = 32; o > 0; o >>= 1) {
            s0 += __shfl_xor(s0, o);
            s1 += __shfl_xor(s1, o);
            d0 += __shfl_xor(d0, o);
            d1 += __shfl_xor(d1, o);
        }
        if (lane == 0) asd[v] = make_float4(s0, s1, d0, d1);
    }
}

// ---------------- GAT: 2 waves per node (head split), fixed softmax ref ----------------
__global__ __launch_bounds__(256) void k_gat(const float* __restrict__ g0,
                                             const float* __restrict__ g1,
                                             const float* __restrict__ asd_f,
                                             const int* __restrict__ offsets,
                                             const int2* __restrict__ edges,
                                             const float* __restrict__ bgat,
                                             float* __restrict__ out) {
    __shared__ float part[2][64];
    int tid = threadIdx.x;
    int w = tid >> 6, lane = tid & 63;
    int slot = w >> 1, head = w & 1;
    int v = blockIdx.x * 2 + slot;          // grid = N/2, always valid
    const float* gh = head ? g1 : g0;
    float asv = asd_f[4 * v + head];
    float adv = asd_f[4 * v + 2 + head];
    float m = asv + adv; m = (m > 0.f) ? m : NEG_SLOPE * m;   // self-loop score = ref
    float acc = gh[(size_t)v * 64 + lane];  // p_self = 1
    float den = 1.f, acc2 = 0.f, den2 = 0.f;
    int beg = offsets[v], end = offsets[v + 1];
    int i = beg;
    for (; i + 2 <= end; i += 2) {
        int s0 = edges[i].x;
        int s1 = edges[i + 1].x;
        float a0 = asd_f[4 * s0 + head];
        float a1 = asd_f[4 * s1 + head];
        float gv0 = gh[(size_t)s0 * 64 + lane];
        float gv1 = gh[(size_t)s1 * 64 + lane];
        float t0 = a0 + adv; t0 = (t0 > 0.f) ? t0 : NEG_SLOPE * t0;
        float t1 = a1 + adv; t1 = (t1 > 0.f) ? t1 : NEG_SLOPE * t1;
        float p0 = __expf(t0 - m);
        float p1 = __expf(t1 - m);
        acc += p0 * gv0; den += p0;
        acc2 += p1 * gv1; den2 += p1;
    }
    if (i < end) {
        int s0 = edges[i].x;
        float a0 = asd_f[4 * s0 + head];
        float gv0 = gh[(size_t)s0 * 64 + lane];
        float t0 = a0 + adv; t0 = (t0 > 0.f) ? t0 : NEG_SLOPE * t0;
        float p0 = __expf(t0 - m);
        acc += p0 * gv0; den += p0;
    }
    acc += acc2; den += den2;
    float r = acc / den;
    if (head) part[slot][lane] = r;
    __syncthreads();
    if (!head) out[(size_t)v * OUTC + lane] = 0.5f * (r + part[slot][lane]) + bgat[lane];
}

extern "C" void kernel_launch(void* const* d_in, const int* in_sizes, int n_in,
                              void* d_out, int out_size, void* d_ws, size_t ws_size,
                              hipStream_t stream) {
    const float* x     = (const float*)d_in[0];
    const int*   ei    = (const int*)d_in[1];
    const float* ea    = (const float*)d_in[2];
    const float* Wsg   = (const float*)d_in[3];
    const float* bsg   = (const float*)d_in[4];
    const float* Wg    = (const float*)d_in[5];
    const float* att_s = (const float*)d_in[6];
    const float* att_d = (const float*)d_in[7];
    const float* bgat  = (const float*)d_in[8];
    const int* src = ei;
    const int* dst = ei + N_EDGES;
    float* out = (float*)d_out;

    char* ws = (char*)d_ws;
    size_t off = 0;
    auto alloc = [&](size_t bytes) -> void* {
        void* p = ws + off;
        off = (off + bytes + 255) & ~(size_t)255;
        return p;
    };
    float*  deg    = (float*)alloc((size_t)N_NODES * 4);        // becomes dinv
    int*    counts = (int*)alloc((size_t)N_NODES * 4);
    int*    offs   = (int*)alloc((size_t)(N_NODES + 1) * 4);
    int*    cursor = (int*)alloc((size_t)N_NODES * 4);
    int*    bsum   = (int*)alloc(256 * 4);
    int2*   edges  = (int2*)alloc((size_t)N_EDGES * 8);
    float*  h0     = (float*)alloc((size_t)N_NODES * HID * 4);
    float*  h1     = (float*)alloc((size_t)N_NODES * HID * 4);
    float*  g0     = (float*)alloc((size_t)N_NODES * 64 * 4);
    float*  g1     = (float*)alloc((size_t)N_NODES * 64 * 4);
    float4* asd    = (float4*)alloc((size_t)N_NODES * 16);
    (void)ws_size; (void)in_sizes; (void)n_in; (void)out_size;

    int nb = (N_NODES + 255) / 256;  // 196

    k_init<<<nb, 256, 0, stream>>>(deg, counts, cursor);
    k_deg_hist<<<(N_EDGES + 255) / 256, 256, 0, stream>>>(dst, ea, deg, counts);

    k_scan_reduce<<<nb, 256, 0, stream>>>(counts, bsum, deg, N_NODES);
    k_scan_bsum<<<1, 256, 0, stream>>>(bsum, nb);
    k_scan_final<<<nb, 256, 0, stream>>>(counts, bsum, offs, N_NODES);

    k_scatter<<<(N_EDGES + 255) / 256, 256, 0, stream>>>(src, dst, ea, deg, offs, cursor, edges);

    k_gemm1<<<(N_NODES + G1_ROWS - 1) / G1_ROWS, 512, 0, stream>>>(x, Wsg, h0);
    k_hop<<<N_NODES / 2, 256, 0, stream>>>(h0, offs, edges, deg, h1);
    k_hop<<<N_NODES / 2, 256, 0, stream>>>(h1, offs, edges, deg, h0);
    k_act_gemm2<<<(N_NODES + G2_ROWS - 1) / G2_ROWS, 256, 0, stream>>>(h0, bsg, Wg, att_s, att_d, g0, g1, asd);
    k_gat<<<N_NODES / 2, 256, 0, stream>>>(g0, g1, (const float*)asd, offs, edges, bgat, out);
}

// Round 5
// 649.948 us; speedup vs baseline: 1.5479x; 1.1255x over previous
//
#include <hip/hip_runtime.h>
#include <hip/hip_fp16.h>
#include <math.h>

#define N_NODES 50000
#define N_EDGES 1600000
#define IN_CH 512
#define HID 64
#define OUTC 64
#define NEG_SLOPE 0.2f

// ---------------- init: deg=1 (self-loop), counts=0, cursor=0 ----------------
__global__ void k_init(float* deg, int* counts, int* cursor) {
    int i = blockIdx.x * blockDim.x + threadIdx.x;
    if (i < N_NODES) { deg[i] = 1.0f; counts[i] = 0; cursor[i] = 0; }
}

__global__ void k_deg_hist(const int* __restrict__ dst, const float* __restrict__ ea,
                           float* deg, int* counts) {
    int e = blockIdx.x * blockDim.x + threadIdx.x;
    if (e >= N_EDGES) return;
    int d = dst[e];
    atomicAdd(&deg[d], ea[e]);
    atomicAdd(&counts[d], 1);
}

// ---------------- scan level 1 (+ fused dinv) ----------------
__global__ void k_scan_reduce(const int* __restrict__ counts, int* bsum, float* deg, int n) {
    __shared__ int lds[256];
    int i = blockIdx.x * 256 + threadIdx.x;
    lds[threadIdx.x] = (i < n) ? counts[i] : 0;
    if (i < n) deg[i] = rsqrtf(deg[i]);  // deg >= 1 always
    __syncthreads();
    for (int s = 128; s > 0; s >>= 1) {
        if (threadIdx.x < s) lds[threadIdx.x] += lds[threadIdx.x + s];
        __syncthreads();
    }
    if (threadIdx.x == 0) bsum[blockIdx.x] = lds[0];
}

__global__ void k_scan_bsum(int* bsum, int nb) {
    __shared__ int lds[256];
    int t = threadIdx.x;
    int v = (t < nb) ? bsum[t] : 0;
    lds[t] = v;
    __syncthreads();
    for (int s = 1; s < 256; s <<= 1) {
        int add = (t >= s) ? lds[t - s] : 0;
        __syncthreads();
        lds[t] += add;
        __syncthreads();
    }
    if (t < nb) bsum[t] = lds[t] - v;  // exclusive
}

__global__ void k_scan_final(const int* __restrict__ counts, const int* __restrict__ bsum,
                             int* offsets, int n) {
    __shared__ int lds[256];
    int t = threadIdx.x;
    int i = blockIdx.x * 256 + t;
    int v = (i < n) ? counts[i] : 0;
    lds[t] = v;
    __syncthreads();
    for (int s = 1; s < 256; s <<= 1) {
        int add = (t >= s) ? lds[t - s] : 0;
        __syncthreads();
        lds[t] += add;
        __syncthreads();
    }
    int incl = lds[t];
    int base = bsum[blockIdx.x];
    if (i < n) offsets[i] = base + incl - v;
    if (i == n - 1) offsets[n] = base + incl;
}

// ---------------- CSR scatter (by dst): packed {src*64, norm-weight} ----------------
__global__ void k_scatter(const int* __restrict__ src, const int* __restrict__ dst,
                          const float* __restrict__ ea, const float* __restrict__ dinv,
                          const int* __restrict__ offsets, int* cursor,
                          int2* __restrict__ edges) {
    int e = blockIdx.x * blockDim.x + threadIdx.x;
    if (e >= N_EDGES) return;
    int s = src[e], d = dst[e];
    int pos = offsets[d] + atomicAdd(&cursor[d], 1);
    edges[pos] = make_int2(s << 6, __float_as_int(dinv[s] * ea[e] * dinv[d]));
}

// ---------------- GEMM1: h0 = x @ W_sg  (fp16 out), LDS-tiled ----------------
#define G1_ROWS 64
#define G1_KC 64
__global__ __launch_bounds__(512) void k_gemm1(const float* __restrict__ x,
                                               const float* __restrict__ W,
                                               __half* __restrict__ p) {
    __shared__ float xs[G1_ROWS][G1_KC];
    __shared__ float wsT[64][G1_KC + 1];
    int tid = threadIdx.x;
    int wave = tid >> 6, lane = tid & 63;
    int r0 = blockIdx.x * G1_ROWS;
    int rbase = wave * 8;
    float acc[8];
#pragma unroll
    for (int j = 0; j < 8; j++) acc[j] = 0.f;

    for (int k0 = 0; k0 < IN_CH; k0 += G1_KC) {
#pragma unroll
        for (int it = 0; it < 2; it++) {
            int idx4 = tid + it * 512;
            int row = idx4 >> 4, c0 = (idx4 & 15) * 4;
            float4 xv = make_float4(0.f, 0.f, 0.f, 0.f);
            if (r0 + row < N_NODES)
                xv = *(const float4*)(x + (size_t)(r0 + row) * IN_CH + k0 + c0);
            *(float4*)&xs[row][c0] = xv;
        }
#pragma unroll
        for (int it = 0; it < 2; it++) {
            int idx4 = tid + it * 512;
            int k = idx4 >> 4, c0 = (idx4 & 15) * 4;
            float4 wv = *(const float4*)(W + (size_t)(k0 + k) * HID + c0);
            wsT[c0 + 0][k] = wv.x;
            wsT[c0 + 1][k] = wv.y;
            wsT[c0 + 2][k] = wv.z;
            wsT[c0 + 3][k] = wv.w;
        }
        __syncthreads();
#pragma unroll
        for (int kg = 0; kg < G1_KC / 4; kg++) {
            int k = kg * 4;
            float w0 = wsT[lane][k + 0];
            float w1 = wsT[lane][k + 1];
            float w2 = wsT[lane][k + 2];
            float w3 = wsT[lane][k + 3];
#pragma unroll
            for (int j = 0; j < 8; j++) {
                float4 xv = *(const float4*)&xs[rbase + j][k];
                acc[j] += xv.x * w0 + xv.y * w1 + xv.z * w2 + xv.w * w3;
            }
        }
        __syncthreads();
    }
#pragma unroll
    for (int j = 0; j < 8; j++) {
        int r = r0 + rbase + j;
        if (r < N_NODES) p[(unsigned)r * HID + lane] = __float2half(acc[j]);
    }
}

// ---------------- one hop: fp16 gathers, 2 waves/node, LDS combine ----------------
__global__ __launch_bounds__(256) void k_hop(const __half* __restrict__ hin,
                                             const int* __restrict__ offsets,
                                             const int2* __restrict__ edges,
                                             const float* __restrict__ dinv,
                                             __half* __restrict__ hout) {
    __shared__ float part[2][64];
    int tid = threadIdx.x;
    int w = tid >> 6, lane = tid & 63;
    int slot = w >> 1, half = w & 1;
    int v = blockIdx.x * 2 + slot;
    int beg = offsets[v], end = offsets[v + 1];
    int mid = beg + ((end - beg) >> 1);
    int lo = half ? mid : beg;
    int hi = half ? end : mid;
    float acc = 0.f, acc2 = 0.f;
    if (!half) {
        float dv = dinv[v];
        acc = dv * dv * __half2float(hin[(unsigned)v * HID + lane]);  // self-loop
    }
    int i = lo;
    for (; i + 2 <= hi; i += 2) {
        int2 e0 = edges[i];
        int2 e1 = edges[i + 1];
        float h0 = __half2float(hin[(unsigned)(e0.x + lane)]);
        float h1 = __half2float(hin[(unsigned)(e1.x + lane)]);
        acc += __int_as_float(e0.y) * h0;
        acc2 += __int_as_float(e1.y) * h1;
    }
    if (i < hi) {
        int2 e0 = edges[i];
        acc += __int_as_float(e0.y) * __half2float(hin[(unsigned)(e0.x + lane)]);
    }
    acc += acc2;
    if (half) part[slot][lane] = acc;
    __syncthreads();
    if (!half) hout[(unsigned)v * HID + lane] = __float2half(acc + part[slot][lane]);
}

// ---------------- bias + SELU + GEMM2 -> packed fp16 g, score tables ----------------
#define G2_ROWS 32
__global__ __launch_bounds__(256) void k_act_gemm2(const __half* __restrict__ h2,
                                                   const float* __restrict__ bsg,
                                                   const float* __restrict__ Wg,
                                                   const float* __restrict__ att_s,
                                                   const float* __restrict__ att_d,
                                                   unsigned* __restrict__ g2h,
                                                   float2* __restrict__ asrc2,
                                                   float4* __restrict__ admm) {
    __shared__ float hs[G2_ROWS][HID];   // 8 KB
    int tid = threadIdx.x;
    int wave = tid >> 6, lane = tid & 63;
    int r0 = blockIdx.x * G2_ROWS;
    int rbase = wave * 8;

    const float SC = 1.0507009873554805f, AL = 1.6732632423543772f;
    {
        // 256 threads x 8 halves = 2048 = 32x64
        int row = tid >> 3, c0 = (tid & 7) * 8;
        int r = r0 + row;
        float vals[8];
        if (r < N_NODES) {
            uint4 raw = *(const uint4*)(h2 + (unsigned)r * HID + c0);
            float2 f0 = __half22float2(*(__half2*)&raw.x);
            float2 f1 = __half22float2(*(__half2*)&raw.y);
            float2 f2 = __half22float2(*(__half2*)&raw.z);
            float2 f3 = __half22float2(*(__half2*)&raw.w);
            vals[0] = f0.x; vals[1] = f0.y; vals[2] = f1.x; vals[3] = f1.y;
            vals[4] = f2.x; vals[5] = f2.y; vals[6] = f3.x; vals[7] = f3.y;
        } else {
#pragma unroll
            for (int j = 0; j < 8; j++) vals[j] = 0.f;
        }
#pragma unroll
        for (int j = 0; j < 8; j++) {
            float hv = vals[j] + bsg[c0 + j];
            hv = (hv > 0.f) ? SC * hv : SC * AL * (__expf(hv) - 1.f);
            hs[row][c0 + j] = hv;
        }
    }
    __syncthreads();

    float accx[8], accy[8];
#pragma unroll
    for (int j = 0; j < 8; j++) { accx[j] = 0.f; accy[j] = 0.f; }
#pragma unroll 2
    for (int k = 0; k < HID; k++) {
        float w0 = Wg[(size_t)k * 128 + lane];        // coalesced, L1-resident
        float w1 = Wg[(size_t)k * 128 + 64 + lane];
#pragma unroll
        for (int j = 0; j < 8; j++) {
            float hk = hs[rbase + j][k];              // LDS broadcast
            accx[j] += hk * w0;
            accy[j] += hk * w1;
        }
    }
    float ats0 = att_s[lane], ats1 = att_s[64 + lane];
    float atd0 = att_d[lane], atd1 = att_d[64 + lane];
#pragma unroll
    for (int j = 0; j < 8; j++) {
        int v = r0 + rbase + j;
        if (v >= N_NODES) break;
        __half2 gp = __floats2half2_rn(accx[j], accy[j]);
        g2h[(unsigned)v * 64 + lane] = *(unsigned*)&gp;
        float s0 = accx[j] * ats0, s1 = accy[j] * ats1;
        float d0 = accx[j] * atd0, d1 = accy[j] * atd1;
#pragma unroll
        for (int o = 32; o > 0; o >>= 1) {
            s0 += __shfl_xor(s0, o);
            s1 += __shfl_xor(s1, o);
            d0 += __shfl_xor(d0, o);
            d1 += __shfl_xor(d1, o);
        }
        if (lane == 0) {
            asrc2[v] = make_float2(s0, s1);
            float m0 = s0 + d0; m0 = (m0 > 0.f) ? m0 : NEG_SLOPE * m0;
            float m1 = s1 + d1; m1 = (m1 > 0.f) ? m1 : NEG_SLOPE * m1;
            admm[v] = make_float4(d0, d1, m0, m1);
        }
    }
}

// ---------------- edge-parallel p precompute + per-node 1/den ----------------
__global__ __launch_bounds__(256) void k_edge_p(const int2* __restrict__ edges,
                                                const float2* __restrict__ asrc2,
                                                const float4* __restrict__ admm,
                                                const int* __restrict__ offsets,
                                                int2* __restrict__ pedges,
                                                float2* __restrict__ rden2) {
    int tid = threadIdx.x;
    int w = tid >> 6, lane = tid & 63;
    int v = blockIdx.x * 4 + w;
    float4 am = admm[v];   // wave-uniform
    float adv0 = am.x, adv1 = am.y, m0 = am.z, m1 = am.w;
    int beg = offsets[v], end = offsets[v + 1];
    float pd0 = 0.f, pd1 = 0.f;
    for (int i0 = beg; i0 < end; i0 += 64) {
        int i = i0 + lane;
        if (i < end) {
            int2 e = edges[i];
            float2 a = asrc2[(unsigned)e.x >> 6];
            float t0 = a.x + adv0; t0 = (t0 > 0.f) ? t0 : NEG_SLOPE * t0;
            float t1 = a.y + adv1; t1 = (t1 > 0.f) ? t1 : NEG_SLOPE * t1;
            float p0 = __expf(t0 - m0);
            float p1 = __expf(t1 - m1);
            __half2 ph = __floats2half2_rn(p0, p1);
            pedges[i] = make_int2(e.x, *(int*)&ph);
            pd0 += p0; pd1 += p1;
        }
    }
#pragma unroll
    for (int o = 32; o > 0; o >>= 1) {
        pd0 += __shfl_xor(pd0, o);
        pd1 += __shfl_xor(pd1, o);
    }
    if (lane == 0)
        rden2[v] = make_float2(1.f / (1.f + pd0), 1.f / (1.f + pd1));
}

// ---------------- GAT: both heads/wave, 2 waves/node, fp16 payloads ----------------
__global__ __launch_bounds__(256) void k_gat(const unsigned* __restrict__ g2h,
                                             const int2* __restrict__ pedges,
                                             const int* __restrict__ offsets,
                                             const float2* __restrict__ rden2,
                                             const float* __restrict__ bgat,
                                             float* __restrict__ out) {
    __shared__ float2 part[2][64];
    int tid = threadIdx.x;
    int w = tid >> 6, lane = tid & 63;
    int slot = w >> 1, half = w & 1;
    int v = blockIdx.x * 2 + slot;
    int beg = offsets[v], end = offsets[v + 1];
    int mid = beg + ((end - beg) >> 1);
    int lo = half ? mid : beg;
    int hi = half ? end : mid;
    float acc0 = 0.f, acc1 = 0.f, b0 = 0.f, b1 = 0.f;
    if (!half) {
        unsigned gs = g2h[(unsigned)v * 64 + lane];   // self, p=1
        float2 gf = __half22float2(*(__half2*)&gs);
        acc0 = gf.x; acc1 = gf.y;
    }
    int i = lo;
    for (; i + 2 <= hi; i += 2) {
        int2 e0 = pedges[i];
        int2 e1 = pedges[i + 1];
        unsigned gv0 = g2h[(unsigned)(e0.x + lane)];
        unsigned gv1 = g2h[(unsigned)(e1.x + lane)];
        float2 p0 = __half22float2(*(__half2*)&e0.y);
        float2 p1 = __half22float2(*(__half2*)&e1.y);
        float2 gf0 = __half22float2(*(__half2*)&gv0);
        float2 gf1 = __half22float2(*(__half2*)&gv1);
        acc0 += p0.x * gf0.x; acc1 += p0.y * gf0.y;
        b0 += p1.x * gf1.x; b1 += p1.y * gf1.y;
    }
    if (i < hi) {
        int2 e0 = pedges[i];
        unsigned gv0 = g2h[(unsigned)(e0.x + lane)];
        float2 p0 = __half22float2(*(__half2*)&e0.y);
        float2 gf0 = __half22float2(*(__half2*)&gv0);
        acc0 += p0.x * gf0.x; acc1 += p0.y * gf0.y;
    }
    acc0 += b0; acc1 += b1;
    if (half) part[slot][lane] = make_float2(acc0, acc1);
    __syncthreads();
    if (!half) {
        float2 pp = part[slot][lane];
        float2 rd = rden2[v];
        out[(unsigned)v * OUTC + lane] =
            0.5f * ((acc0 + pp.x) * rd.x + (acc1 + pp.y) * rd.y) + bgat[lane];
    }
}

extern "C" void kernel_launch(void* const* d_in, const int* in_sizes, int n_in,
                              void* d_out, int out_size, void* d_ws, size_t ws_size,
                              hipStream_t stream) {
    const float* x     = (const float*)d_in[0];
    const int*   ei    = (const int*)d_in[1];
    const float* ea    = (const float*)d_in[2];
    const float* Wsg   = (const float*)d_in[3];
    const float* bsg   = (const float*)d_in[4];
    const float* Wg    = (const float*)d_in[5];
    const float* att_s = (const float*)d_in[6];
    const float* att_d = (const float*)d_in[7];
    const float* bgat  = (const float*)d_in[8];
    const int* src = ei;
    const int* dst = ei + N_EDGES;
    float* out = (float*)d_out;

    char* ws = (char*)d_ws;
    size_t off = 0;
    auto alloc = [&](size_t bytes) -> void* {
        void* p = ws + off;
        off = (off + bytes + 255) & ~(size_t)255;
        return p;
    };
    float*    deg    = (float*)alloc((size_t)N_NODES * 4);        // becomes dinv
    int*      counts = (int*)alloc((size_t)N_NODES * 4);
    int*      offs   = (int*)alloc((size_t)(N_NODES + 1) * 4);
    int*      cursor = (int*)alloc((size_t)N_NODES * 4);
    int*      bsum   = (int*)alloc(256 * 4);
    int2*     edges  = (int2*)alloc((size_t)N_EDGES * 8);
    int2*     pedges = (int2*)alloc((size_t)N_EDGES * 8);
    __half*   h0     = (__half*)alloc((size_t)N_NODES * HID * 2);
    __half*   h1     = (__half*)alloc((size_t)N_NODES * HID * 2);
    unsigned* g2h    = (unsigned*)alloc((size_t)N_NODES * 64 * 4);
    float2*   asrc2  = (float2*)alloc((size_t)N_NODES * 8);
    float4*   admm   = (float4*)alloc((size_t)N_NODES * 16);
    float2*   rden2  = (float2*)alloc((size_t)N_NODES * 8);
    (void)ws_size; (void)in_sizes; (void)n_in; (void)out_size;

    int nb = (N_NODES + 255) / 256;  // 196

    k_init<<<nb, 256, 0, stream>>>(deg, counts, cursor);
    k_deg_hist<<<(N_EDGES + 255) / 256, 256, 0, stream>>>(dst, ea, deg, counts);

    k_scan_reduce<<<nb, 256, 0, stream>>>(counts, bsum, deg, N_NODES);
    k_scan_bsum<<<1, 256, 0, stream>>>(bsum, nb);
    k_scan_final<<<nb, 256, 0, stream>>>(counts, bsum, offs, N_NODES);

    k_scatter<<<(N_EDGES + 255) / 256, 256, 0, stream>>>(src, dst, ea, deg, offs, cursor, edges);

    k_gemm1<<<(N_NODES + G1_ROWS - 1) / G1_ROWS, 512, 0, stream>>>(x, Wsg, h0);
    k_hop<<<N_NODES / 2, 256, 0, stream>>>(h0, offs, edges, deg, h1);
    k_hop<<<N_NODES / 2, 256, 0, stream>>>(h1, offs, edges, deg, h0);
    k_act_gemm2<<<(N_NODES + G2_ROWS - 1) / G2_ROWS, 256, 0, stream>>>(h0, bsg, Wg, att_s, att_d, g2h, asrc2, admm);
    k_edge_p<<<N_NODES / 4, 256, 0, stream>>>(edges, asrc2, admm, offs, pedges, rden2);
    k_gat<<<N_NODES / 2, 256, 0, stream>>>(g2h, pedges, offs, rden2, bgat, out);
}

// Round 6
// 529.313 us; speedup vs baseline: 1.9007x; 1.2279x over previous
//
#include <hip/hip_runtime.h>
#include <hip/hip_fp16.h>
#include <math.h>

#define N_NODES 50000
#define N_EDGES 1600000
#define IN_CH 512
#define HID 64
#define OUTC 64
#define NEG_SLOPE 0.2f
#define CNT_SHIFT 44
#define SUM_MASK 0xFFFFFFFFFFFull

// ---------------- fused histogram: 1 packed atomic/edge, rank capture ----------------
__global__ void k_hist(const int* __restrict__ dst, const float* __restrict__ ea,
                       unsigned long long* __restrict__ deg64,
                       unsigned short* __restrict__ rank) {
    int e = blockIdx.x * blockDim.x + threadIdx.x;
    if (e >= N_EDGES) return;
    int d = dst[e];
    unsigned long long pack = (1ull << CNT_SHIFT) |
                              (unsigned long long)(ea[e] * 4294967296.0f);
    unsigned long long old = atomicAdd(&deg64[d], pack);
    rank[e] = (unsigned short)(old >> CNT_SHIFT);
}

// ---------------- scan level 1 (+ fused dinv decode) ----------------
__global__ void k_scan_reduce(const unsigned long long* __restrict__ deg64,
                              int* bsum, float* dinv, int n) {
    __shared__ int lds[256];
    int i = blockIdx.x * 256 + threadIdx.x;
    unsigned long long dv = (i < n) ? deg64[i] : 0ull;
    lds[threadIdx.x] = (int)(dv >> CNT_SHIFT);
    if (i < n)
        dinv[i] = rsqrtf(1.0f + (float)(dv & SUM_MASK) * 0x1p-32f);  // deg >= 1
    __syncthreads();
    for (int s = 128; s > 0; s >>= 1) {
        if (threadIdx.x < s) lds[threadIdx.x] += lds[threadIdx.x + s];
        __syncthreads();
    }
    if (threadIdx.x == 0) bsum[blockIdx.x] = lds[0];
}

__global__ void k_scan_bsum(int* bsum, int nb) {
    __shared__ int lds[256];
    int t = threadIdx.x;
    int v = (t < nb) ? bsum[t] : 0;
    lds[t] = v;
    __syncthreads();
    for (int s = 1; s < 256; s <<= 1) {
        int add = (t >= s) ? lds[t - s] : 0;
        __syncthreads();
        lds[t] += add;
        __syncthreads();
    }
    if (t < nb) bsum[t] = lds[t] - v;  // exclusive
}

__global__ void k_scan_final(const unsigned long long* __restrict__ deg64,
                             const int* __restrict__ bsum,
                             int* offsets, int n) {
    __shared__ int lds[256];
    int t = threadIdx.x;
    int i = blockIdx.x * 256 + t;
    int v = (i < n) ? (int)(deg64[i] >> CNT_SHIFT) : 0;
    lds[t] = v;
    __syncthreads();
    for (int s = 1; s < 256; s <<= 1) {
        int add = (t >= s) ? lds[t - s] : 0;
        __syncthreads();
        lds[t] += add;
        __syncthreads();
    }
    int incl = lds[t];
    int base = bsum[blockIdx.x];
    if (i < n) offsets[i] = base + incl - v;
    if (i == n - 1) offsets[n] = base + incl;
}

// ---------------- CSR scatter (atomic-free via rank) ----------------
__global__ void k_scatter(const int* __restrict__ src, const int* __restrict__ dst,
                          const float* __restrict__ ea, const float* __restrict__ dinv,
                          const int* __restrict__ offsets,
                          const unsigned short* __restrict__ rank,
                          int2* __restrict__ edges) {
    int e = blockIdx.x * blockDim.x + threadIdx.x;
    if (e >= N_EDGES) return;
    int s = src[e], d = dst[e];
    int pos = offsets[d] + rank[e];
    edges[pos] = make_int2(s << 6, __float_as_int(dinv[s] * ea[e] * dinv[d]));
}

// ---------------- GEMM1: h0 = x @ W_sg  (fp16 out), LDS-tiled ----------------
#define G1_ROWS 64
#define G1_KC 64
__global__ __launch_bounds__(512) void k_gemm1(const float* __restrict__ x,
                                               const float* __restrict__ W,
                                               __half* __restrict__ p) {
    __shared__ float xs[G1_ROWS][G1_KC];
    __shared__ float wsT[64][G1_KC + 1];
    int tid = threadIdx.x;
    int wave = tid >> 6, lane = tid & 63;
    int r0 = blockIdx.x * G1_ROWS;
    int rbase = wave * 8;
    float acc[8];
#pragma unroll
    for (int j = 0; j < 8; j++) acc[j] = 0.f;

    for (int k0 = 0; k0 < IN_CH; k0 += G1_KC) {
#pragma unroll
        for (int it = 0; it < 2; it++) {
            int idx4 = tid + it * 512;
            int row = idx4 >> 4, c0 = (idx4 & 15) * 4;
            float4 xv = make_float4(0.f, 0.f, 0.f, 0.f);
            if (r0 + row < N_NODES)
                xv = *(const float4*)(x + (size_t)(r0 + row) * IN_CH + k0 + c0);
            *(float4*)&xs[row][c0] = xv;
        }
#pragma unroll
        for (int it = 0; it < 2; it++) {
            int idx4 = tid + it * 512;
            int k = idx4 >> 4, c0 = (idx4 & 15) * 4;
            float4 wv = *(const float4*)(W + (size_t)(k0 + k) * HID + c0);
            wsT[c0 + 0][k] = wv.x;
            wsT[c0 + 1][k] = wv.y;
            wsT[c0 + 2][k] = wv.z;
            wsT[c0 + 3][k] = wv.w;
        }
        __syncthreads();
#pragma unroll
        for (int kg = 0; kg < G1_KC / 4; kg++) {
            int k = kg * 4;
            float w0 = wsT[lane][k + 0];
            float w1 = wsT[lane][k + 1];
            float w2 = wsT[lane][k + 2];
            float w3 = wsT[lane][k + 3];
#pragma unroll
            for (int j = 0; j < 8; j++) {
                float4 xv = *(const float4*)&xs[rbase + j][k];
                acc[j] += xv.x * w0 + xv.y * w1 + xv.z * w2 + xv.w * w3;
            }
        }
        __syncthreads();
    }
#pragma unroll
    for (int j = 0; j < 8; j++) {
        int r = r0 + rbase + j;
        if (r < N_NODES) p[(unsigned)r * HID + lane] = __float2half(acc[j]);
    }
}

// ---------------- one hop: fp16 gathers, 2 waves/node, LDS combine ----------------
__global__ __launch_bounds__(256) void k_hop(const __half* __restrict__ hin,
                                             const int* __restrict__ offsets,
                                             const int2* __restrict__ edges,
                                             const float* __restrict__ dinv,
                                             __half* __restrict__ hout) {
    __shared__ float part[2][64];
    int tid = threadIdx.x;
    int w = tid >> 6, lane = tid & 63;
    int slot = w >> 1, half = w & 1;
    int v = blockIdx.x * 2 + slot;
    int beg = offsets[v], end = offsets[v + 1];
    int mid = beg + ((end - beg) >> 1);
    int lo = half ? mid : beg;
    int hi = half ? end : mid;
    float acc = 0.f, acc2 = 0.f;
    if (!half) {
        float dv = dinv[v];
        acc = dv * dv * __half2float(hin[(unsigned)v * HID + lane]);  // self-loop
    }
    int i = lo;
    for (; i + 2 <= hi; i += 2) {
        int2 e0 = edges[i];
        int2 e1 = edges[i + 1];
        float h0 = __half2float(hin[(unsigned)(e0.x + lane)]);
        float h1 = __half2float(hin[(unsigned)(e1.x + lane)]);
        acc += __int_as_float(e0.y) * h0;
        acc2 += __int_as_float(e1.y) * h1;
    }
    if (i < hi) {
        int2 e0 = edges[i];
        acc += __int_as_float(e0.y) * __half2float(hin[(unsigned)(e0.x + lane)]);
    }
    acc += acc2;
    if (half) part[slot][lane] = acc;
    __syncthreads();
    if (!half) hout[(unsigned)v * HID + lane] = __float2half(acc + part[slot][lane]);
}

// ---------------- bias + SELU + GEMM2 -> packed fp16 g, score tables ----------------
#define G2_ROWS 32
__global__ __launch_bounds__(256) void k_act_gemm2(const __half* __restrict__ h2,
                                                   const float* __restrict__ bsg,
                                                   const float* __restrict__ Wg,
                                                   const float* __restrict__ att_s,
                                                   const float* __restrict__ att_d,
                                                   unsigned* __restrict__ g2h,
                                                   float2* __restrict__ asrc2,
                                                   float4* __restrict__ admm) {
    __shared__ float hs[G2_ROWS][HID];   // 8 KB
    int tid = threadIdx.x;
    int wave = tid >> 6, lane = tid & 63;
    int r0 = blockIdx.x * G2_ROWS;
    int rbase = wave * 8;

    const float SC = 1.0507009873554805f, AL = 1.6732632423543772f;
    {
        int row = tid >> 3, c0 = (tid & 7) * 8;
        int r = r0 + row;
        float vals[8];
        if (r < N_NODES) {
            uint4 raw = *(const uint4*)(h2 + (unsigned)r * HID + c0);
            float2 f0 = __half22float2(*(__half2*)&raw.x);
            float2 f1 = __half22float2(*(__half2*)&raw.y);
            float2 f2 = __half22float2(*(__half2*)&raw.z);
            float2 f3 = __half22float2(*(__half2*)&raw.w);
            vals[0] = f0.x; vals[1] = f0.y; vals[2] = f1.x; vals[3] = f1.y;
            vals[4] = f2.x; vals[5] = f2.y; vals[6] = f3.x; vals[7] = f3.y;
        } else {
#pragma unroll
            for (int j = 0; j < 8; j++) vals[j] = 0.f;
        }
#pragma unroll
        for (int j = 0; j < 8; j++) {
            float hv = vals[j] + bsg[c0 + j];
            hv = (hv > 0.f) ? SC * hv : SC * AL * (__expf(hv) - 1.f);
            hs[row][c0 + j] = hv;
        }
    }
    __syncthreads();

    float accx[8], accy[8];
#pragma unroll
    for (int j = 0; j < 8; j++) { accx[j] = 0.f; accy[j] = 0.f; }
#pragma unroll 2
    for (int k = 0; k < HID; k++) {
        float w0 = Wg[(size_t)k * 128 + lane];        // coalesced, L1-resident
        float w1 = Wg[(size_t)k * 128 + 64 + lane];
#pragma unroll
        for (int j = 0; j < 8; j++) {
            float hk = hs[rbase + j][k];              // LDS broadcast
            accx[j] += hk * w0;
            accy[j] += hk * w1;
        }
    }
    float ats0 = att_s[lane], ats1 = att_s[64 + lane];
    float atd0 = att_d[lane], atd1 = att_d[64 + lane];
#pragma unroll
    for (int j = 0; j < 8; j++) {
        int v = r0 + rbase + j;
        if (v >= N_NODES) break;
        __half2 gp = __floats2half2_rn(accx[j], accy[j]);
        g2h[(unsigned)v * 64 + lane] = *(unsigned*)&gp;
        float s0 = accx[j] * ats0, s1 = accy[j] * ats1;
        float d0 = accx[j] * atd0, d1 = accy[j] * atd1;
#pragma unroll
        for (int o = 32; o > 0; o >>= 1) {
            s0 += __shfl_xor(s0, o);
            s1 += __shfl_xor(s1, o);
            d0 += __shfl_xor(d0, o);
            d1 += __shfl_xor(d1, o);
        }
        if (lane == 0) {
            asrc2[v] = make_float2(s0, s1);
            float m0 = s0 + d0; m0 = (m0 > 0.f) ? m0 : NEG_SLOPE * m0;
            float m1 = s1 + d1; m1 = (m1 > 0.f) ? m1 : NEG_SLOPE * m1;
            admm[v] = make_float4(d0, d1, m0, m1);
        }
    }
}

// ---------------- GAT: fused scores, both heads/wave, 2 waves/node ----------------
__global__ __launch_bounds__(256) void k_gat(const unsigned* __restrict__ g2h,
                                             const float2* __restrict__ asrc2,
                                             const float4* __restrict__ admm,
                                             const int* __restrict__ offsets,
                                             const int2* __restrict__ edges,
                                             const float* __restrict__ bgat,
                                             float* __restrict__ out) {
    __shared__ float4 part[2][64];
    int tid = threadIdx.x;
    int w = tid >> 6, lane = tid & 63;
    int slot = w >> 1, half = w & 1;
    int v = blockIdx.x * 2 + slot;
    float4 am = admm[v];   // ad0, ad1, m0, m1 (wave-uniform)
    int beg = offsets[v], end = offsets[v + 1];
    int mid = beg + ((end - beg) >> 1);
    int lo = half ? mid : beg;
    int hi = half ? end : mid;
    float acc0 = 0.f, acc1 = 0.f, den0 = 0.f, den1 = 0.f;
    float b0 = 0.f, b1 = 0.f, dn0 = 0.f, dn1 = 0.f;
    if (!half) {
        unsigned gs = g2h[(unsigned)v * 64 + lane];   // self, p=1
        float2 gf = __half22float2(*(__half2*)&gs);
        acc0 = gf.x; acc1 = gf.y; den0 = 1.f; den1 = 1.f;
    }
    int i = lo;
    for (; i + 2 <= hi; i += 2) {
        int2 e0 = edges[i];
        int2 e1 = edges[i + 1];
        float2 a0 = asrc2[(unsigned)e0.x >> 6];       // wave-uniform broadcast
        float2 a1 = asrc2[(unsigned)e1.x >> 6];
        unsigned gv0 = g2h[(unsigned)(e0.x + lane)];
        unsigned gv1 = g2h[(unsigned)(e1.x + lane)];
        float t00 = a0.x + am.x; t00 = (t00 > 0.f) ? t00 : NEG_SLOPE * t00;
        float t01 = a0.y + am.y; t01 = (t01 > 0.f) ? t01 : NEG_SLOPE * t01;
        float t10 = a1.x + am.x; t10 = (t10 > 0.f) ? t10 : NEG_SLOPE * t10;
        float t11 = a1.y + am.y; t11 = (t11 > 0.f) ? t11 : NEG_SLOPE * t11;
        float p00 = __expf(t00 - am.z), p01 = __expf(t01 - am.w);
        float p10 = __expf(t10 - am.z), p11 = __expf(t11 - am.w);
        float2 gf0 = __half22float2(*(__half2*)&gv0);
        float2 gf1 = __half22float2(*(__half2*)&gv1);
        acc0 += p00 * gf0.x; acc1 += p01 * gf0.y; den0 += p00; den1 += p01;
        b0 += p10 * gf1.x; b1 += p11 * gf1.y; dn0 += p10; dn1 += p11;
    }
    if (i < hi) {
        int2 e0 = edges[i];
        float2 a0 = asrc2[(unsigned)e0.x >> 6];
        unsigned gv0 = g2h[(unsigned)(e0.x + lane)];
        float t00 = a0.x + am.x; t00 = (t00 > 0.f) ? t00 : NEG_SLOPE * t00;
        float t01 = a0.y + am.y; t01 = (t01 > 0.f) ? t01 : NEG_SLOPE * t01;
        float p00 = __expf(t00 - am.z), p01 = __expf(t01 - am.w);
        float2 gf0 = __half22float2(*(__half2*)&gv0);
        acc0 += p00 * gf0.x; acc1 += p01 * gf0.y; den0 += p00; den1 += p01;
    }
    acc0 += b0; acc1 += b1; den0 += dn0; den1 += dn1;
    if (half) part[slot][lane] = make_float4(acc0, acc1, den0, den1);
    __syncthreads();
    if (!half) {
        float4 pp = part[slot][lane];
        out[(unsigned)v * OUTC + lane] =
            0.5f * ((acc0 + pp.x) / (den0 + pp.z) + (acc1 + pp.y) / (den1 + pp.w))
            + bgat[lane];
    }
}

extern "C" void kernel_launch(void* const* d_in, const int* in_sizes, int n_in,
                              void* d_out, int out_size, void* d_ws, size_t ws_size,
                              hipStream_t stream) {
    const float* x     = (const float*)d_in[0];
    const int*   ei    = (const int*)d_in[1];
    const float* ea    = (const float*)d_in[2];
    const float* Wsg   = (const float*)d_in[3];
    const float* bsg   = (const float*)d_in[4];
    const float* Wg    = (const float*)d_in[5];
    const float* att_s = (const float*)d_in[6];
    const float* att_d = (const float*)d_in[7];
    const float* bgat  = (const float*)d_in[8];
    const int* src = ei;
    const int* dst = ei + N_EDGES;
    float* out = (float*)d_out;

    char* ws = (char*)d_ws;
    size_t off = 0;
    auto alloc = [&](size_t bytes) -> void* {
        void* p = ws + off;
        off = (off + bytes + 255) & ~(size_t)255;
        return p;
    };
    unsigned long long* deg64 = (unsigned long long*)alloc((size_t)N_NODES * 8);
    float*          dinv   = (float*)alloc((size_t)N_NODES * 4);
    unsigned short* rank   = (unsigned short*)alloc((size_t)N_EDGES * 2);
    int*            offs   = (int*)alloc((size_t)(N_NODES + 1) * 4);
    int*            bsum   = (int*)alloc(256 * 4);
    int2*           edges  = (int2*)alloc((size_t)N_EDGES * 8);
    __half*         h0     = (__half*)alloc((size_t)N_NODES * HID * 2);
    __half*         h1     = (__half*)alloc((size_t)N_NODES * HID * 2);
    unsigned*       g2h    = (unsigned*)alloc((size_t)N_NODES * 64 * 4);
    float2*         asrc2  = (float2*)alloc((size_t)N_NODES * 8);
    float4*         admm   = (float4*)alloc((size_t)N_NODES * 16);
    (void)ws_size; (void)in_sizes; (void)n_in; (void)out_size;

    hipMemsetAsync(deg64, 0, (size_t)N_NODES * 8, stream);

    k_hist<<<(N_EDGES + 255) / 256, 256, 0, stream>>>(dst, ea, deg64, rank);

    int nb = (N_NODES + 255) / 256;  // 196
    k_scan_reduce<<<nb, 256, 0, stream>>>(deg64, bsum, dinv, N_NODES);
    k_scan_bsum<<<1, 256, 0, stream>>>(bsum, nb);
    k_scan_final<<<nb, 256, 0, stream>>>(deg64, bsum, offs, N_NODES);

    k_scatter<<<(N_EDGES + 255) / 256, 256, 0, stream>>>(src, dst, ea, dinv, offs, rank, edges);

    k_gemm1<<<(N_NODES + G1_ROWS - 1) / G1_ROWS, 512, 0, stream>>>(x, Wsg, h0);
    k_hop<<<N_NODES / 2, 256, 0, stream>>>(h0, offs, edges, dinv, h1);
    k_hop<<<N_NODES / 2, 256, 0, stream>>>(h1, offs, edges, dinv, h0);
    k_act_gemm2<<<(N_NODES + G2_ROWS - 1) / G2_ROWS, 256, 0, stream>>>(h0, bsg, Wg, att_s, att_d, g2h, asrc2, admm);
    k_gat<<<N_NODES / 2, 256, 0, stream>>>(g2h, asrc2, admm, offs, edges, bgat, out);
}

// Round 7
// 419.093 us; speedup vs baseline: 2.4005x; 1.2630x over previous
//
#include <hip/hip_runtime.h>
#include <hip/hip_fp16.h>
#include <math.h>

#define N_NODES 50000
#define N_EDGES 1600000
#define IN_CH 512
#define HID 64
#define OUTC 64
#define NEG_SLOPE 0.2f
#define CNT_SHIFT 44
#define SUM_MASK 0xFFFFFFFFFFFull

typedef __attribute__((ext_vector_type(8))) short bf16x8;
typedef __attribute__((ext_vector_type(4))) float f32x4;

__device__ __forceinline__ unsigned bf16r(float f) {
    unsigned b = __float_as_uint(f);
    return (b + 0x7FFFu + ((b >> 16) & 1u)) >> 16;
}

// ---------------- fused histogram: 1 packed atomic/edge, rank capture ----------------
__global__ void k_hist(const int* __restrict__ dst, const float* __restrict__ ea,
                       unsigned long long* __restrict__ deg64,
                       unsigned short* __restrict__ rank) {
    int e = blockIdx.x * blockDim.x + threadIdx.x;
    if (e >= N_EDGES) return;
    int d = dst[e];
    unsigned long long pack = (1ull << CNT_SHIFT) |
                              (unsigned long long)(ea[e] * 4294967296.0f);
    unsigned long long old = atomicAdd(&deg64[d], pack);
    rank[e] = (unsigned short)(old >> CNT_SHIFT);
}

// ---------------- W split+transpose: WhT/WlT [c][k] bf16 ----------------
__global__ void k_wsplit(const float* __restrict__ W,
                         short* __restrict__ WhT, short* __restrict__ WlT) {
    int idx = blockIdx.x * 256 + threadIdx.x;
    if (idx >= IN_CH * HID) return;
    int k = idx >> 6, c = idx & 63;
    float wv = W[idx];
    unsigned h = bf16r(wv);
    float res = wv - __uint_as_float(h << 16);
    unsigned l = bf16r(res);
    WhT[c * IN_CH + k] = (short)h;
    WlT[c * IN_CH + k] = (short)l;
}

// ---------------- scan level 1 (+ fused dinv decode) ----------------
__global__ void k_scan_reduce(const unsigned long long* __restrict__ deg64,
                              int* bsum, float* dinv, int n) {
    __shared__ int lds[256];
    int i = blockIdx.x * 256 + threadIdx.x;
    unsigned long long dv = (i < n) ? deg64[i] : 0ull;
    lds[threadIdx.x] = (int)(dv >> CNT_SHIFT);
    if (i < n)
        dinv[i] = rsqrtf(1.0f + (float)(dv & SUM_MASK) * 0x1p-32f);  // deg >= 1
    __syncthreads();
    for (int s = 128; s > 0; s >>= 1) {
        if (threadIdx.x < s) lds[threadIdx.x] += lds[threadIdx.x + s];
        __syncthreads();
    }
    if (threadIdx.x == 0) bsum[blockIdx.x] = lds[0];
}

__global__ void k_scan_bsum(int* bsum, int nb) {
    __shared__ int lds[256];
    int t = threadIdx.x;
    int v = (t < nb) ? bsum[t] : 0;
    lds[t] = v;
    __syncthreads();
    for (int s = 1; s < 256; s <<= 1) {
        int add = (t >= s) ? lds[t - s] : 0;
        __syncthreads();
        lds[t] += add;
        __syncthreads();
    }
    if (t < nb) bsum[t] = lds[t] - v;  // exclusive
}

__global__ void k_scan_final(const unsigned long long* __restrict__ deg64,
                             const int* __restrict__ bsum,
                             int* offsets, int n) {
    __shared__ int lds[256];
    int t = threadIdx.x;
    int i = blockIdx.x * 256 + t;
    int v = (i < n) ? (int)(deg64[i] >> CNT_SHIFT) : 0;
    lds[t] = v;
    __syncthreads();
    for (int s = 1; s < 256; s <<= 1) {
        int add = (t >= s) ? lds[t - s] : 0;
        __syncthreads();
        lds[t] += add;
        __syncthreads();
    }
    int incl = lds[t];
    int base = bsum[blockIdx.x];
    if (i < n) offsets[i] = base + incl - v;
    if (i == n - 1) offsets[n] = base + incl;
}

// ---------------- CSR scatter (atomic-free via rank): {src*32, weight} ----------------
__global__ void k_scatter(const int* __restrict__ src, const int* __restrict__ dst,
                          const float* __restrict__ ea, const float* __restrict__ dinv,
                          const int* __restrict__ offsets,
                          const unsigned short* __restrict__ rank,
                          int2* __restrict__ edges) {
    int e = blockIdx.x * blockDim.x + threadIdx.x;
    if (e >= N_EDGES) return;
    int s = src[e], d = dst[e];
    int pos = offsets[d] + rank[e];
    edges[pos] = make_int2(s << 5, __float_as_int(dinv[s] * ea[e] * dinv[d]));
}

// ---------------- GEMM1 via MFMA split-bf16: h0 = x @ W_sg (fp16 out) ----------------
__global__ __launch_bounds__(256) void k_gemm1(const float* __restrict__ x,
                                               const short* __restrict__ WhT,
                                               const short* __restrict__ WlT,
                                               __half* __restrict__ p) {
    int lane = threadIdx.x & 63;
    int wv = threadIdx.x >> 6;
    int row = blockIdx.x * 64 + wv * 16 + (lane & 15);
    bool rv = row < N_NODES;
    const float* xr = x + (size_t)(rv ? row : 0) * IN_CH + ((lane >> 4) << 3);
    const int bo0 = (lane & 15) * IN_CH + ((lane >> 4) << 3);
    f32x4 acc0 = {0.f, 0.f, 0.f, 0.f};
    f32x4 acc1 = {0.f, 0.f, 0.f, 0.f};
    f32x4 acc2 = {0.f, 0.f, 0.f, 0.f};
    f32x4 acc3 = {0.f, 0.f, 0.f, 0.f};
#pragma unroll 2
    for (int k0 = 0; k0 < IN_CH; k0 += 32) {
        float4 xa = *(const float4*)(xr + k0);
        float4 xb = *(const float4*)(xr + k0 + 4);
        float xv[8] = {xa.x, xa.y, xa.z, xa.w, xb.x, xb.y, xb.z, xb.w};
        bf16x8 ah, al;
#pragma unroll
        for (int j = 0; j < 8; j++) {
            unsigned hb = bf16r(xv[j]);
            float res = xv[j] - __uint_as_float(hb << 16);
            ah[j] = (short)hb;
            al[j] = (short)bf16r(res);
        }
        const short* bp = WhT + bo0 + k0;
        const short* lp = WlT + bo0 + k0;
        bf16x8 bh, bl;
        bh = *(const bf16x8*)(bp);
        bl = *(const bf16x8*)(lp);
        acc0 = __builtin_amdgcn_mfma_f32_16x16x32_bf16(ah, bh, acc0, 0, 0, 0);
        acc0 = __builtin_amdgcn_mfma_f32_16x16x32_bf16(ah, bl, acc0, 0, 0, 0);
        acc0 = __builtin_amdgcn_mfma_f32_16x16x32_bf16(al, bh, acc0, 0, 0, 0);
        bh = *(const bf16x8*)(bp + 16 * IN_CH);
        bl = *(const bf16x8*)(lp + 16 * IN_CH);
        acc1 = __builtin_amdgcn_mfma_f32_16x16x32_bf16(ah, bh, acc1, 0, 0, 0);
        acc1 = __builtin_amdgcn_mfma_f32_16x16x32_bf16(ah, bl, acc1, 0, 0, 0);
        acc1 = __builtin_amdgcn_mfma_f32_16x16x32_bf16(al, bh, acc1, 0, 0, 0);
        bh = *(const bf16x8*)(bp + 32 * IN_CH);
        bl = *(const bf16x8*)(lp + 32 * IN_CH);
        acc2 = __builtin_amdgcn_mfma_f32_16x16x32_bf16(ah, bh, acc2, 0, 0, 0);
        acc2 = __builtin_amdgcn_mfma_f32_16x16x32_bf16(ah, bl, acc2, 0, 0, 0);
        acc2 = __builtin_amdgcn_mfma_f32_16x16x32_bf16(al, bh, acc2, 0, 0, 0);
        bh = *(const bf16x8*)(bp + 48 * IN_CH);
        bl = *(const bf16x8*)(lp + 48 * IN_CH);
        acc3 = __builtin_amdgcn_mfma_f32_16x16x32_bf16(ah, bh, acc3, 0, 0, 0);
        acc3 = __builtin_amdgcn_mfma_f32_16x16x32_bf16(ah, bl, acc3, 0, 0, 0);
        acc3 = __builtin_amdgcn_mfma_f32_16x16x32_bf16(al, bh, acc3, 0, 0, 0);
    }
    int crow = blockIdx.x * 64 + wv * 16 + ((lane >> 4) << 2);
    int ccol = lane & 15;
#pragma unroll
    for (int r = 0; r < 4; r++) {
        int gr = crow + r;
        if (gr < N_NODES) {
            p[(unsigned)gr * HID + ccol]      = __float2half(acc0[r]);
            p[(unsigned)gr * HID + 16 + ccol] = __float2half(acc1[r]);
            p[(unsigned)gr * HID + 32 + ccol] = __float2half(acc2[r]);
            p[(unsigned)gr * HID + 48 + ccol] = __float2half(acc3[r]);
        }
    }
}

// ---------------- one hop: half2 gathers, 2 edges/instr, 2 waves/node ----------------
__global__ __launch_bounds__(256) void k_hop(const unsigned* __restrict__ hin2,
                                             const int* __restrict__ offsets,
                                             const int2* __restrict__ edges,
                                             const float* __restrict__ dinv,
                                             unsigned* __restrict__ hout2) {
    __shared__ float2 part[2][32];
    int tid = threadIdx.x;
    int w = tid >> 6, lane = tid & 63;
    int slot = w >> 1, half = w & 1;
    int cl = lane & 31, es = lane >> 5;
    int v = blockIdx.x * 2 + slot;
    int beg = offsets[v], end = offsets[v + 1];
    int mid = beg + ((end - beg) >> 1);
    int lo = half ? mid : beg;
    int hi = half ? end : mid;
    float ax = 0.f, ay = 0.f, bx = 0.f, by = 0.f;
    if (!half && !es) {
        float dv = dinv[v];
        float sw = dv * dv;
        unsigned gh = hin2[(unsigned)v * 32 + cl];
        float2 hf = __half22float2(*(__half2*)&gh);
        ax = sw * hf.x; ay = sw * hf.y;
    }
    int i = lo;
    for (; i + 4 <= hi; i += 4) {
        int2 e0 = edges[i + es];
        int2 e1 = edges[i + 2 + es];
        unsigned g0 = hin2[(unsigned)(e0.x + cl)];
        unsigned g1 = hin2[(unsigned)(e1.x + cl)];
        float w0 = __int_as_float(e0.y);
        float w1 = __int_as_float(e1.y);
        float2 h0 = __half22float2(*(__half2*)&g0);
        float2 h1 = __half22float2(*(__half2*)&g1);
        ax += w0 * h0.x; ay += w0 * h0.y;
        bx += w1 * h1.x; by += w1 * h1.y;
    }
    for (; i + es < hi; i += 2) {
        int2 e0 = edges[i + es];
        unsigned g0 = hin2[(unsigned)(e0.x + cl)];
        float w0 = __int_as_float(e0.y);
        float2 h0 = __half22float2(*(__half2*)&g0);
        ax += w0 * h0.x; ay += w0 * h0.y;
    }
    ax += bx; ay += by;
    ax += __shfl_xor(ax, 32);
    ay += __shfl_xor(ay, 32);
    if (half && lane < 32) part[slot][cl] = make_float2(ax, ay);
    __syncthreads();
    if (!half && lane < 32) {
        float2 pp = part[slot][cl];
        __half2 hp = __floats2half2_rn(ax + pp.x, ay + pp.y);
        hout2[(unsigned)v * 32 + cl] = *(unsigned*)&hp;
    }
}

// ---------------- bias + SELU + GEMM2 -> packed uint2 g, score tables ----------------
#define G2_ROWS 32
__global__ __launch_bounds__(256) void k_act_gemm2(const __half* __restrict__ h2,
                                                   const float* __restrict__ bsg,
                                                   const float* __restrict__ Wg,
                                                   const float* __restrict__ att_s,
                                                   const float* __restrict__ att_d,
                                                   uint2* __restrict__ g4h,
                                                   float2* __restrict__ asrc2,
                                                   float4* __restrict__ admm) {
    __shared__ float hs[G2_ROWS][HID];   // 8 KB
    int tid = threadIdx.x;
    int wave = tid >> 6, lane = tid & 63;
    int r0 = blockIdx.x * G2_ROWS;
    int rbase = wave * 8;

    const float SC = 1.0507009873554805f, AL = 1.6732632423543772f;
    {
        int row = tid >> 3, c0 = (tid & 7) * 8;
        int r = r0 + row;
        float vals[8];
        if (r < N_NODES) {
            uint4 raw = *(const uint4*)(h2 + (unsigned)r * HID + c0);
            float2 f0 = __half22float2(*(__half2*)&raw.x);
            float2 f1 = __half22float2(*(__half2*)&raw.y);
            float2 f2 = __half22float2(*(__half2*)&raw.z);
            float2 f3 = __half22float2(*(__half2*)&raw.w);
            vals[0] = f0.x; vals[1] = f0.y; vals[2] = f1.x; vals[3] = f1.y;
            vals[4] = f2.x; vals[5] = f2.y; vals[6] = f3.x; vals[7] = f3.y;
        } else {
#pragma unroll
            for (int j = 0; j < 8; j++) vals[j] = 0.f;
        }
#pragma unroll
        for (int j = 0; j < 8; j++) {
            float hv = vals[j] + bsg[c0 + j];
            hv = (hv > 0.f) ? SC * hv : SC * AL * (__expf(hv) - 1.f);
            hs[row][c0 + j] = hv;
        }
    }
    __syncthreads();

    float accx[8], accy[8];
#pragma unroll
    for (int j = 0; j < 8; j++) { accx[j] = 0.f; accy[j] = 0.f; }
#pragma unroll 2
    for (int k = 0; k < HID; k++) {
        float w0 = Wg[(size_t)k * 128 + lane];        // coalesced, L1-resident
        float w1 = Wg[(size_t)k * 128 + 64 + lane];
#pragma unroll
        for (int j = 0; j < 8; j++) {
            float hk = hs[rbase + j][k];              // LDS broadcast
            accx[j] += hk * w0;
            accy[j] += hk * w1;
        }
    }
    float ats0 = att_s[lane], ats1 = att_s[64 + lane];
    float atd0 = att_d[lane], atd1 = att_d[64 + lane];
#pragma unroll
    for (int j = 0; j < 8; j++) {
        int v = r0 + rbase + j;
        if (v >= N_NODES) break;
        __half2 gp = __floats2half2_rn(accx[j], accy[j]);
        unsigned gpu = *(unsigned*)&gp;
        unsigned other = (unsigned)__shfl_xor((int)gpu, 1);
        if (!(lane & 1)) g4h[(unsigned)v * 32 + (lane >> 1)] = make_uint2(gpu, other);
        float s0 = accx[j] * ats0, s1 = accy[j] * ats1;
        float d0 = accx[j] * atd0, d1 = accy[j] * atd1;
#pragma unroll
        for (int o = 32; o > 0; o >>= 1) {
            s0 += __shfl_xor(s0, o);
            s1 += __shfl_xor(s1, o);
            d0 += __shfl_xor(d0, o);
            d1 += __shfl_xor(d1, o);
        }
        if (lane == 0) {
            asrc2[v] = make_float2(s0, s1);
            float m0 = s0 + d0; m0 = (m0 > 0.f) ? m0 : NEG_SLOPE * m0;
            float m1 = s1 + d1; m1 = (m1 > 0.f) ? m1 : NEG_SLOPE * m1;
            admm[v] = make_float4(d0, d1, m0, m1);
        }
    }
}

// ---------------- GAT: uint2 gathers, 2 edges/instr, 2 waves/node ----------------
__global__ __launch_bounds__(256) void k_gat(const uint2* __restrict__ g4h,
                                             const float2* __restrict__ asrc2,
                                             const float4* __restrict__ admm,
                                             const int* __restrict__ offsets,
                                             const int2* __restrict__ edges,
                                             const float* __restrict__ bgat,
                                             float* __restrict__ out) {
    __shared__ float4 pacc[2][32];
    __shared__ float2 pden[2][32];
    int tid = threadIdx.x;
    int w = tid >> 6, lane = tid & 63;
    int slot = w >> 1, half = w & 1;
    int cl = lane & 31, es = lane >> 5;
    int v = blockIdx.x * 2 + slot;
    float4 am = admm[v];   // ad0, ad1, m0, m1
    float aA = 0.f, aB = 0.f, aC = 0.f, aD = 0.f, d0 = 0.f, d1 = 0.f;
    float bA = 0.f, bB = 0.f, bC = 0.f, bD = 0.f, e0d = 0.f, e1d = 0.f;
    if (!half && !es) {
        uint2 gs = g4h[(unsigned)v * 32 + cl];
        float2 gx = __half22float2(*(__half2*)&gs.x);
        float2 gy = __half22float2(*(__half2*)&gs.y);
        aA = gx.x; aB = gx.y; aC = gy.x; aD = gy.y;
        d0 = 1.f; d1 = 1.f;
    }
    int beg = offsets[v], end = offsets[v + 1];
    int mid = beg + ((end - beg) >> 1);
    int lo = half ? mid : beg;
    int hi = half ? end : mid;
    int i = lo;
    for (; i + 4 <= hi; i += 4) {
        int2 ed0 = edges[i + es];
        int2 ed1 = edges[i + 2 + es];
        float2 a0 = asrc2[(unsigned)ed0.x >> 5];
        float2 a1 = asrc2[(unsigned)ed1.x >> 5];
        uint2 g0 = g4h[(unsigned)(ed0.x + cl)];
        uint2 g1 = g4h[(unsigned)(ed1.x + cl)];
        float t00 = a0.x + am.x; t00 = (t00 > 0.f) ? t00 : NEG_SLOPE * t00;
        float t01 = a0.y + am.y; t01 = (t01 > 0.f) ? t01 : NEG_SLOPE * t01;
        float t10 = a1.x + am.x; t10 = (t10 > 0.f) ? t10 : NEG_SLOPE * t10;
        float t11 = a1.y + am.y; t11 = (t11 > 0.f) ? t11 : NEG_SLOPE * t11;
        float p00 = __expf(t00 - am.z), p01 = __expf(t01 - am.w);
        float p10 = __expf(t10 - am.z), p11 = __expf(t11 - am.w);
        float2 g0x = __half22float2(*(__half2*)&g0.x);
        float2 g0y = __half22float2(*(__half2*)&g0.y);
        float2 g1x = __half22float2(*(__half2*)&g1.x);
        float2 g1y = __half22float2(*(__half2*)&g1.y);
        aA += p00 * g0x.x; aB += p01 * g0x.y; aC += p00 * g0y.x; aD += p01 * g0y.y;
        d0 += p00; d1 += p01;
        bA += p10 * g1x.x; bB += p11 * g1x.y; bC += p10 * g1y.x; bD += p11 * g1y.y;
        e0d += p10; e1d += p11;
    }
    for (; i + es < hi; i += 2) {
        int2 ed0 = edges[i + es];
        float2 a0 = asrc2[(unsigned)ed0.x >> 5];
        uint2 g0 = g4h[(unsigned)(ed0.x + cl)];
        float t00 = a0.x + am.x; t00 = (t00 > 0.f) ? t00 : NEG_SLOPE * t00;
        float t01 = a0.y + am.y; t01 = (t01 > 0.f) ? t01 : NEG_SLOPE * t01;
        float p00 = __expf(t00 - am.z), p01 = __expf(t01 - am.w);
        float2 g0x = __half22float2(*(__half2*)&g0.x);
        float2 g0y = __half22float2(*(__half2*)&g0.y);
        aA += p00 * g0x.x; aB += p01 * g0x.y; aC += p00 * g0y.x; aD += p01 * g0y.y;
        d0 += p00; d1 += p01;
    }
    aA += bA; aB += bB; aC += bC; aD += bD; d0 += e0d; d1 += e1d;
    aA += __shfl_xor(aA, 32); aB += __shfl_xor(aB, 32);
    aC += __shfl_xor(aC, 32); aD += __shfl_xor(aD, 32);
    d0 += __shfl_xor(d0, 32); d1 += __shfl_xor(d1, 32);
    if (half && lane < 32) {
        pacc[slot][cl] = make_float4(aA, aB, aC, aD);
        pden[slot][cl] = make_float2(d0, d1);
    }
    __syncthreads();
    if (!half && lane < 32) {
        float4 pa = pacc[slot][cl];
        float2 pd = pden[slot][cl];
        float r0 = 1.f / (d0 + pd.x), r1 = 1.f / (d1 + pd.y);
        float oe = 0.5f * ((aA + pa.x) * r0 + (aB + pa.y) * r1) + bgat[cl * 2];
        float oo = 0.5f * ((aC + pa.z) * r0 + (aD + pa.w) * r1) + bgat[cl * 2 + 1];
        *(float2*)&out[(unsigned)v * OUTC + cl * 2] = make_float2(oe, oo);
    }
}

extern "C" void kernel_launch(void* const* d_in, const int* in_sizes, int n_in,
                              void* d_out, int out_size, void* d_ws, size_t ws_size,
                              hipStream_t stream) {
    const float* x     = (const float*)d_in[0];
    const int*   ei    = (const int*)d_in[1];
    const float* ea    = (const float*)d_in[2];
    const float* Wsg   = (const float*)d_in[3];
    const float* bsg   = (const float*)d_in[4];
    const float* Wg    = (const float*)d_in[5];
    const float* att_s = (const float*)d_in[6];
    const float* att_d = (const float*)d_in[7];
    const float* bgat  = (const float*)d_in[8];
    const int* src = ei;
    const int* dst = ei + N_EDGES;
    float* out = (float*)d_out;

    char* ws = (char*)d_ws;
    size_t off = 0;
    auto alloc = [&](size_t bytes) -> void* {
        void* p = ws + off;
        off = (off + bytes + 255) & ~(size_t)255;
        return p;
    };
    unsigned long long* deg64 = (unsigned long long*)alloc((size_t)N_NODES * 8);
    float*          dinv   = (float*)alloc((size_t)N_NODES * 4);
    unsigned short* rank   = (unsigned short*)alloc((size_t)N_EDGES * 2);
    int*            offs   = (int*)alloc((size_t)(N_NODES + 1) * 4);
    int*            bsum   = (int*)alloc(256 * 4);
    int2*           edges  = (int2*)alloc((size_t)N_EDGES * 8);
    short*          WhT    = (short*)alloc((size_t)IN_CH * HID * 2);
    short*          WlT    = (short*)alloc((size_t)IN_CH * HID * 2);
    __half*         h0     = (__half*)alloc((size_t)N_NODES * HID * 2);
    __half*         h1     = (__half*)alloc((size_t)N_NODES * HID * 2);
    uint2*          g4h    = (uint2*)alloc((size_t)N_NODES * 32 * 8);
    float2*         asrc2  = (float2*)alloc((size_t)N_NODES * 8);
    float4*         admm   = (float4*)alloc((size_t)N_NODES * 16);
    (void)ws_size; (void)in_sizes; (void)n_in; (void)out_size;

    hipMemsetAsync(deg64, 0, (size_t)N_NODES * 8, stream);

    k_wsplit<<<(IN_CH * HID + 255) / 256, 256, 0, stream>>>(Wsg, WhT, WlT);
    k_hist<<<(N_EDGES + 255) / 256, 256, 0, stream>>>(dst, ea, deg64, rank);

    int nb = (N_NODES + 255) / 256;  // 196
    k_scan_reduce<<<nb, 256, 0, stream>>>(deg64, bsum, dinv, N_NODES);
    k_scan_bsum<<<1, 256, 0, stream>>>(bsum, nb);
    k_scan_final<<<nb, 256, 0, stream>>>(deg64, bsum, offs, N_NODES);

    k_scatter<<<(N_EDGES + 255) / 256, 256, 0, stream>>>(src, dst, ea, dinv, offs, rank, edges);

    k_gemm1<<<(N_NODES + 63) / 64, 256, 0, stream>>>(x, WhT, WlT, h0);
    k_hop<<<N_NODES / 2, 256, 0, stream>>>((const unsigned*)h0, offs, edges, dinv, (unsigned*)h1);
    k_hop<<<N_NODES / 2, 256, 0, stream>>>((const unsigned*)h1, offs, edges, dinv, (unsigned*)h0);
    k_act_gemm2<<<(N_NODES + G2_ROWS - 1) / G2_ROWS, 256, 0, stream>>>(h0, bsg, Wg, att_s, att_d, g4h, asrc2, admm);
    k_gat<<<N_NODES / 2, 256, 0, stream>>>(g4h, asrc2, admm, offs, edges, bgat, out);
}

// Round 8
// 389.148 us; speedup vs baseline: 2.5853x; 1.0770x over previous
//
#include <hip/hip_runtime.h>
#include <hip/hip_fp16.h>
#include <math.h>

#define N_NODES 50000
#define N_EDGES 1600000
#define IN_CH 512
#define HID 64
#define OUTC 64
#define NEG_SLOPE 0.2f
#define EA_SCALE 131072.0f   // 2^17
#define PCAP 128             // LDS p-cache entries per half-wave

typedef __attribute__((ext_vector_type(8))) short bf16x8;
typedef __attribute__((ext_vector_type(4))) float f32x4;

__device__ __forceinline__ unsigned bf16r(float f) {
    unsigned b = __float_as_uint(f);
    return (b + 0x7FFFu + ((b >> 16) & 1u)) >> 16;
}

// ---------------- fused histogram: 1x 32-bit packed atomic/edge ----------------
__global__ void k_hist(const int* __restrict__ dst, const float* __restrict__ ea,
                       unsigned* __restrict__ deg32,
                       unsigned short* __restrict__ rank) {
    int e = blockIdx.x * blockDim.x + threadIdx.x;
    if (e >= N_EDGES) return;
    int d = dst[e];
    unsigned pack = (1u << 24) | (unsigned)(ea[e] * EA_SCALE);
    unsigned old = atomicAdd(&deg32[d], pack);
    rank[e] = (unsigned short)(old >> 24);
}

// ---------------- W split+transpose: WhT/WlT [c][k] bf16 ----------------
__global__ void k_wsplit(const float* __restrict__ W,
                         short* __restrict__ WhT, short* __restrict__ WlT) {
    int idx = blockIdx.x * 256 + threadIdx.x;
    if (idx >= IN_CH * HID) return;
    int k = idx >> 6, c = idx & 63;
    float wv = W[idx];
    unsigned h = bf16r(wv);
    float res = wv - __uint_as_float(h << 16);
    unsigned l = bf16r(res);
    WhT[c * IN_CH + k] = (short)h;
    WlT[c * IN_CH + k] = (short)l;
}

// ---------------- scan level 1 (+ fused dinv decode) ----------------
__global__ void k_scan_reduce(const unsigned* __restrict__ deg32,
                              int* bsum, float* dinv, int n) {
    __shared__ int lds[256];
    int i = blockIdx.x * 256 + threadIdx.x;
    unsigned dv = (i < n) ? deg32[i] : 0u;
    lds[threadIdx.x] = (int)(dv >> 24);
    if (i < n)
        dinv[i] = rsqrtf(1.0f + (float)(dv & 0xFFFFFFu) * (1.0f / EA_SCALE));
    __syncthreads();
    for (int s = 128; s > 0; s >>= 1) {
        if (threadIdx.x < s) lds[threadIdx.x] += lds[threadIdx.x + s];
        __syncthreads();
    }
    if (threadIdx.x == 0) bsum[blockIdx.x] = lds[0];
}

__global__ void k_scan_bsum(int* bsum, int nb) {
    __shared__ int lds[256];
    int t = threadIdx.x;
    int v = (t < nb) ? bsum[t] : 0;
    lds[t] = v;
    __syncthreads();
    for (int s = 1; s < 256; s <<= 1) {
        int add = (t >= s) ? lds[t - s] : 0;
        __syncthreads();
        lds[t] += add;
        __syncthreads();
    }
    if (t < nb) bsum[t] = lds[t] - v;  // exclusive
}

__global__ void k_scan_final(const unsigned* __restrict__ deg32,
                             const int* __restrict__ bsum,
                             int* offsets, int n) {
    __shared__ int lds[256];
    int t = threadIdx.x;
    int i = blockIdx.x * 256 + t;
    int v = (i < n) ? (int)(deg32[i] >> 24) : 0;
    lds[t] = v;
    __syncthreads();
    for (int s = 1; s < 256; s <<= 1) {
        int add = (t >= s) ? lds[t - s] : 0;
        __syncthreads();
        lds[t] += add;
        __syncthreads();
    }
    int incl = lds[t];
    int base = bsum[blockIdx.x];
    if (i < n) offsets[i] = base + incl - v;
    if (i == n - 1) offsets[n] = base + incl;
}

// ---------------- CSR scatter (atomic-free via rank): {src*32, weight} ----------------
__global__ void k_scatter(const int* __restrict__ src, const int* __restrict__ dst,
                          const float* __restrict__ ea, const float* __restrict__ dinv,
                          const int* __restrict__ offsets,
                          const unsigned short* __restrict__ rank,
                          int2* __restrict__ edges) {
    int e = blockIdx.x * blockDim.x + threadIdx.x;
    if (e >= N_EDGES) return;
    int s = src[e], d = dst[e];
    int pos = offsets[d] + rank[e];
    edges[pos] = make_int2(s << 5, __float_as_int(dinv[s] * ea[e] * dinv[d]));
}

// ---------------- GEMM1 via MFMA split-bf16: h0 = x @ W_sg (fp16 out) ----------------
__global__ __launch_bounds__(256) void k_gemm1(const float* __restrict__ x,
                                               const short* __restrict__ WhT,
                                               const short* __restrict__ WlT,
                                               __half* __restrict__ p) {
    int lane = threadIdx.x & 63;
    int wv = threadIdx.x >> 6;
    int row = blockIdx.x * 64 + wv * 16 + (lane & 15);
    bool rv = row < N_NODES;
    const float* xr = x + (size_t)(rv ? row : 0) * IN_CH + ((lane >> 4) << 3);
    const int bo0 = (lane & 15) * IN_CH + ((lane >> 4) << 3);
    f32x4 acc0 = {0.f, 0.f, 0.f, 0.f};
    f32x4 acc1 = {0.f, 0.f, 0.f, 0.f};
    f32x4 acc2 = {0.f, 0.f, 0.f, 0.f};
    f32x4 acc3 = {0.f, 0.f, 0.f, 0.f};
#pragma unroll 2
    for (int k0 = 0; k0 < IN_CH; k0 += 32) {
        float4 xa = *(const float4*)(xr + k0);
        float4 xb = *(const float4*)(xr + k0 + 4);
        float xv[8] = {xa.x, xa.y, xa.z, xa.w, xb.x, xb.y, xb.z, xb.w};
        bf16x8 ah, al;
#pragma unroll
        for (int j = 0; j < 8; j++) {
            unsigned hb = bf16r(xv[j]);
            float res = xv[j] - __uint_as_float(hb << 16);
            ah[j] = (short)hb;
            al[j] = (short)bf16r(res);
        }
        const short* bp = WhT + bo0 + k0;
        const short* lp = WlT + bo0 + k0;
        bf16x8 bh, bl;
        bh = *(const bf16x8*)(bp);
        bl = *(const bf16x8*)(lp);
        acc0 = __builtin_amdgcn_mfma_f32_16x16x32_bf16(ah, bh, acc0, 0, 0, 0);
        acc0 = __builtin_amdgcn_mfma_f32_16x16x32_bf16(ah, bl, acc0, 0, 0, 0);
        acc0 = __builtin_amdgcn_mfma_f32_16x16x32_bf16(al, bh, acc0, 0, 0, 0);
        bh = *(const bf16x8*)(bp + 16 * IN_CH);
        bl = *(const bf16x8*)(lp + 16 * IN_CH);
        acc1 = __builtin_amdgcn_mfma_f32_16x16x32_bf16(ah, bh, acc1, 0, 0, 0);
        acc1 = __builtin_amdgcn_mfma_f32_16x16x32_bf16(ah, bl, acc1, 0, 0, 0);
        acc1 = __builtin_amdgcn_mfma_f32_16x16x32_bf16(al, bh, acc1, 0, 0, 0);
        bh = *(const bf16x8*)(bp + 32 * IN_CH);
        bl = *(const bf16x8*)(lp + 32 * IN_CH);
        acc2 = __builtin_amdgcn_mfma_f32_16x16x32_bf16(ah, bh, acc2, 0, 0, 0);
        acc2 = __builtin_amdgcn_mfma_f32_16x16x32_bf16(ah, bl, acc2, 0, 0, 0);
        acc2 = __builtin_amdgcn_mfma_f32_16x16x32_bf16(al, bh, acc2, 0, 0, 0);
        bh = *(const bf16x8*)(bp + 48 * IN_CH);
        bl = *(const bf16x8*)(lp + 48 * IN_CH);
        acc3 = __builtin_amdgcn_mfma_f32_16x16x32_bf16(ah, bh, acc3, 0, 0, 0);
        acc3 = __builtin_amdgcn_mfma_f32_16x16x32_bf16(ah, bl, acc3, 0, 0, 0);
        acc3 = __builtin_amdgcn_mfma_f32_16x16x32_bf16(al, bh, acc3, 0, 0, 0);
    }
    int crow = blockIdx.x * 64 + wv * 16 + ((lane >> 4) << 2);
    int ccol = lane & 15;
#pragma unroll
    for (int r = 0; r < 4; r++) {
        int gr = crow + r;
        if (gr < N_NODES) {
            p[(unsigned)gr * HID + ccol]      = __float2half(acc0[r]);
            p[(unsigned)gr * HID + 16 + ccol] = __float2half(acc1[r]);
            p[(unsigned)gr * HID + 32 + ccol] = __float2half(acc2[r]);
            p[(unsigned)gr * HID + 48 + ccol] = __float2half(acc3[r]);
        }
    }
}

// ---------------- one hop: half2 gathers, 8 edges in flight, 2 waves/node ----------------
__global__ __launch_bounds__(256) void k_hop(const unsigned* __restrict__ hin2,
                                             const int* __restrict__ offsets,
                                             const int2* __restrict__ edges,
                                             const float* __restrict__ dinv,
                                             unsigned* __restrict__ hout2) {
    __shared__ float2 part[2][32];
    int tid = threadIdx.x;
    int w = tid >> 6, lane = tid & 63;
    int slot = w >> 1, half = w & 1;
    int cl = lane & 31, es = lane >> 5;
    int v = blockIdx.x * 2 + slot;
    int beg = offsets[v], end = offsets[v + 1];
    int mid = beg + ((end - beg) >> 1);
    int lo = half ? mid : beg;
    int hi = half ? end : mid;
    float ax = 0.f, ay = 0.f, bx = 0.f, by = 0.f;
    float cx = 0.f, cy = 0.f, dx = 0.f, dy = 0.f;
    if (!half && !es) {
        float dv = dinv[v];
        float sw = dv * dv;
        unsigned gh = hin2[(unsigned)v * 32 + cl];
        float2 hf = __half22float2(*(__half2*)&gh);
        ax = sw * hf.x; ay = sw * hf.y;
    }
    int i = lo;
    for (; i + 8 <= hi; i += 8) {
        int2 e0 = edges[i + es];
        int2 e1 = edges[i + 2 + es];
        int2 e2 = edges[i + 4 + es];
        int2 e3 = edges[i + 6 + es];
        unsigned g0 = hin2[(unsigned)(e0.x + cl)];
        unsigned g1 = hin2[(unsigned)(e1.x + cl)];
        unsigned g2 = hin2[(unsigned)(e2.x + cl)];
        unsigned g3 = hin2[(unsigned)(e3.x + cl)];
        float w0 = __int_as_float(e0.y), w1 = __int_as_float(e1.y);
        float w2 = __int_as_float(e2.y), w3 = __int_as_float(e3.y);
        float2 h0 = __half22float2(*(__half2*)&g0);
        float2 h1 = __half22float2(*(__half2*)&g1);
        float2 h2 = __half22float2(*(__half2*)&g2);
        float2 h3 = __half22float2(*(__half2*)&g3);
        ax += w0 * h0.x; ay += w0 * h0.y;
        bx += w1 * h1.x; by += w1 * h1.y;
        cx += w2 * h2.x; cy += w2 * h2.y;
        dx += w3 * h3.x; dy += w3 * h3.y;
    }
    for (; i + es < hi; i += 2) {
        int2 e0 = edges[i + es];
        unsigned g0 = hin2[(unsigned)(e0.x + cl)];
        float w0 = __int_as_float(e0.y);
        float2 h0 = __half22float2(*(__half2*)&g0);
        ax += w0 * h0.x; ay += w0 * h0.y;
    }
    ax += bx + cx + dx; ay += by + cy + dy;
    ax += __shfl_xor(ax, 32);
    ay += __shfl_xor(ay, 32);
    if (half && lane < 32) part[slot][cl] = make_float2(ax, ay);
    __syncthreads();
    if (!half && lane < 32) {
        float2 pp = part[slot][cl];
        __half2 hp = __floats2half2_rn(ax + pp.x, ay + pp.y);
        hout2[(unsigned)v * 32 + cl] = *(unsigned*)&hp;
    }
}

// ---------------- bias + SELU + GEMM2 -> packed uint2 g, score tables ----------------
#define G2_ROWS 32
__global__ __launch_bounds__(256) void k_act_gemm2(const __half* __restrict__ h2,
                                                   const float* __restrict__ bsg,
                                                   const float* __restrict__ Wg,
                                                   const float* __restrict__ att_s,
                                                   const float* __restrict__ att_d,
                                                   uint2* __restrict__ g4h,
                                                   float2* __restrict__ asrc2,
                                                   float4* __restrict__ admm) {
    __shared__ float hs[G2_ROWS][HID];   // 8 KB
    int tid = threadIdx.x;
    int wave = tid >> 6, lane = tid & 63;
    int r0 = blockIdx.x * G2_ROWS;
    int rbase = wave * 8;

    const float SC = 1.0507009873554805f, AL = 1.6732632423543772f;
    {
        int row = tid >> 3, c0 = (tid & 7) * 8;
        int r = r0 + row;
        float vals[8];
        if (r < N_NODES) {
            uint4 raw = *(const uint4*)(h2 + (unsigned)r * HID + c0);
            float2 f0 = __half22float2(*(__half2*)&raw.x);
            float2 f1 = __half22float2(*(__half2*)&raw.y);
            float2 f2 = __half22float2(*(__half2*)&raw.z);
            float2 f3 = __half22float2(*(__half2*)&raw.w);
            vals[0] = f0.x; vals[1] = f0.y; vals[2] = f1.x; vals[3] = f1.y;
            vals[4] = f2.x; vals[5] = f2.y; vals[6] = f3.x; vals[7] = f3.y;
        } else {
#pragma unroll
            for (int j = 0; j < 8; j++) vals[j] = 0.f;
        }
#pragma unroll
        for (int j = 0; j < 8; j++) {
            float hv = vals[j] + bsg[c0 + j];
            hv = (hv > 0.f) ? SC * hv : SC * AL * (__expf(hv) - 1.f);
            hs[row][c0 + j] = hv;
        }
    }
    __syncthreads();

    float accx[8], accy[8];
#pragma unroll
    for (int j = 0; j < 8; j++) { accx[j] = 0.f; accy[j] = 0.f; }
#pragma unroll 2
    for (int k = 0; k < HID; k++) {
        float w0 = Wg[(size_t)k * 128 + lane];        // coalesced, L1-resident
        float w1 = Wg[(size_t)k * 128 + 64 + lane];
#pragma unroll
        for (int j = 0; j < 8; j++) {
            float hk = hs[rbase + j][k];              // LDS broadcast
            accx[j] += hk * w0;
            accy[j] += hk * w1;
        }
    }
    float ats0 = att_s[lane], ats1 = att_s[64 + lane];
    float atd0 = att_d[lane], atd1 = att_d[64 + lane];
#pragma unroll
    for (int j = 0; j < 8; j++) {
        int v = r0 + rbase + j;
        if (v >= N_NODES) break;
        __half2 gp = __floats2half2_rn(accx[j], accy[j]);
        unsigned gpu = *(unsigned*)&gp;
        unsigned other = (unsigned)__shfl_xor((int)gpu, 1);
        if (!(lane & 1)) g4h[(unsigned)v * 32 + (lane >> 1)] = make_uint2(gpu, other);
        float s0 = accx[j] * ats0, s1 = accy[j] * ats1;
        float d0 = accx[j] * atd0, d1 = accy[j] * atd1;
#pragma unroll
        for (int o = 32; o > 0; o >>= 1) {
            s0 += __shfl_xor(s0, o);
            s1 += __shfl_xor(s1, o);
            d0 += __shfl_xor(d0, o);
            d1 += __shfl_xor(d1, o);
        }
        if (lane == 0) {
            asrc2[v] = make_float2(s0, s1);
            float m0 = s0 + d0; m0 = (m0 > 0.f) ? m0 : NEG_SLOPE * m0;
            float m1 = s1 + d1; m1 = (m1 > 0.f) ? m1 : NEG_SLOPE * m1;
            admm[v] = make_float4(d0, d1, m0, m1);
        }
    }
}

// ---------------- GAT: two-phase (lane-parallel scores -> LDS p-cache) ----------------
__global__ __launch_bounds__(256) void k_gat(const uint2* __restrict__ g4h,
                                             const float2* __restrict__ asrc2,
                                             const float4* __restrict__ admm,
                                             const int* __restrict__ offsets,
                                             const int2* __restrict__ edges,
                                             const float* __restrict__ bgat,
                                             float* __restrict__ out) {
    __shared__ int4 pbuf[2][2][PCAP];    // 8 KB: {src*32, p0, p1, -}
    __shared__ float4 pacc[2][32];
    __shared__ float2 pden[2][32];
    int tid = threadIdx.x;
    int w = tid >> 6, lane = tid & 63;
    int slot = w >> 1, half = w & 1;
    int cl = lane & 31, es = lane >> 5;
    int v = blockIdx.x * 2 + slot;
    float4 am = admm[v];   // ad0, ad1, m0, m1 (wave-uniform)
    int beg = offsets[v], end = offsets[v + 1];
    int mid = beg + ((end - beg) >> 1);
    int lo = half ? mid : beg;
    int hi = half ? end : mid;
    int n = hi - lo;

    // ---- phase 1: lane-parallel scores, den reduce, p-cache fill ----
    float pd0 = 0.f, pd1 = 0.f;
    for (int i = lo + lane; i < hi; i += 64) {
        int2 e = edges[i];                          // coalesced
        float2 a = asrc2[(unsigned)e.x >> 5];       // 8B gather, L2-resident
        float t0 = a.x + am.x; t0 = (t0 > 0.f) ? t0 : NEG_SLOPE * t0;
        float t1 = a.y + am.y; t1 = (t1 > 0.f) ? t1 : NEG_SLOPE * t1;
        float p0 = __expf(t0 - am.z);
        float p1 = __expf(t1 - am.w);
        int idx = i - lo;
        if (idx < PCAP)
            pbuf[slot][half][idx] = make_int4(e.x, __float_as_int(p0), __float_as_int(p1), 0);
        pd0 += p0; pd1 += p1;
    }
#pragma unroll
    for (int o = 32; o > 0; o >>= 1) {
        pd0 += __shfl_xor(pd0, o);
        pd1 += __shfl_xor(pd1, o);
    }
    if (!half) { pd0 += 1.f; pd1 += 1.f; }   // self-loop p=1 (once per node)

    // ---- phase 2: gather+accumulate using cached p ----
    float aA = 0.f, aB = 0.f, aC = 0.f, aD = 0.f;
    float bA = 0.f, bB = 0.f, bC = 0.f, bD = 0.f;
    if (!half && !es) {
        uint2 gs = g4h[(unsigned)v * 32 + cl];   // self, p=1
        float2 gx = __half22float2(*(__half2*)&gs.x);
        float2 gy = __half22float2(*(__half2*)&gs.y);
        aA = gx.x; aB = gx.y; aC = gy.x; aD = gy.y;
    }
    int n1 = (n < PCAP) ? n : PCAP;
    int ii = 0;
    for (; ii + 8 <= n1; ii += 8) {
        int4 e0 = pbuf[slot][half][ii + es];
        int4 e1 = pbuf[slot][half][ii + 2 + es];
        int4 e2 = pbuf[slot][half][ii + 4 + es];
        int4 e3 = pbuf[slot][half][ii + 6 + es];
        uint2 g0 = g4h[(unsigned)(e0.x + cl)];
        uint2 g1 = g4h[(unsigned)(e1.x + cl)];
        uint2 g2 = g4h[(unsigned)(e2.x + cl)];
        uint2 g3 = g4h[(unsigned)(e3.x + cl)];
        float p00 = __int_as_float(e0.y), p01 = __int_as_float(e0.z);
        float p10 = __int_as_float(e1.y), p11 = __int_as_float(e1.z);
        float p20 = __int_as_float(e2.y), p21 = __int_as_float(e2.z);
        float p30 = __int_as_float(e3.y), p31 = __int_as_float(e3.z);
        float2 g0x = __half22float2(*(__half2*)&g0.x);
        float2 g0y = __half22float2(*(__half2*)&g0.y);
        float2 g1x = __half22float2(*(__half2*)&g1.x);
        float2 g1y = __half22float2(*(__half2*)&g1.y);
        float2 g2x = __half22float2(*(__half2*)&g2.x);
        float2 g2y = __half22float2(*(__half2*)&g2.y);
        float2 g3x = __half22float2(*(__half2*)&g3.x);
        float2 g3y = __half22float2(*(__half2*)&g3.y);
        aA += p00 * g0x.x; aB += p01 * g0x.y; aC += p00 * g0y.x; aD += p01 * g0y.y;
        bA += p10 * g1x.x; bB += p11 * g1x.y; bC += p10 * g1y.x; bD += p11 * g1y.y;
        aA += p20 * g2x.x; aB += p21 * g2x.y; aC += p20 * g2y.x; aD += p21 * g2y.y;
        bA += p30 * g3x.x; bB += p31 * g3x.y; bC += p30 * g3y.x; bD += p31 * g3y.y;
    }
    for (; ii + es < n1; ii += 2) {
        int4 e0 = pbuf[slot][half][ii + es];
        uint2 g0 = g4h[(unsigned)(e0.x + cl)];
        float p00 = __int_as_float(e0.y), p01 = __int_as_float(e0.z);
        float2 g0x = __half22float2(*(__half2*)&g0.x);
        float2 g0y = __half22float2(*(__half2*)&g0.y);
        aA += p00 * g0x.x; aB += p01 * g0x.y; aC += p00 * g0y.x; aD += p01 * g0y.y;
    }
    // rare overflow tail (deg/2 > PCAP): inline scores
    for (int jj = PCAP + es; jj < n; jj += 2) {
        int2 e = edges[lo + jj];
        float2 a = asrc2[(unsigned)e.x >> 5];
        float t0 = a.x + am.x; t0 = (t0 > 0.f) ? t0 : NEG_SLOPE * t0;
        float t1 = a.y + am.y; t1 = (t1 > 0.f) ? t1 : NEG_SLOPE * t1;
        float p0 = __expf(t0 - am.z);
        float p1 = __expf(t1 - am.w);
        uint2 g0 = g4h[(unsigned)(e.x + cl)];
        float2 g0x = __half22float2(*(__half2*)&g0.x);
        float2 g0y = __half22float2(*(__half2*)&g0.y);
        aA += p0 * g0x.x; aB += p1 * g0x.y; aC += p0 * g0y.x; aD += p1 * g0y.y;
    }
    aA += bA; aB += bB; aC += bC; aD += bD;
    aA += __shfl_xor(aA, 32); aB += __shfl_xor(aB, 32);
    aC += __shfl_xor(aC, 32); aD += __shfl_xor(aD, 32);
    if (half && lane < 32) {
        pacc[slot][cl] = make_float4(aA, aB, aC, aD);
        pden[slot][cl] = make_float2(pd0, pd1);
    }
    __syncthreads();
    if (!half && lane < 32) {
        float4 pa = pacc[slot][cl];
        float2 pd = pden[slot][cl];
        float r0 = 1.f / (pd0 + pd.x), r1 = 1.f / (pd1 + pd.y);
        float oe = 0.5f * ((aA + pa.x) * r0 + (aB + pa.y) * r1) + bgat[cl * 2];
        float oo = 0.5f * ((aC + pa.z) * r0 + (aD + pa.w) * r1) + bgat[cl * 2 + 1];
        *(float2*)&out[(unsigned)v * OUTC + cl * 2] = make_float2(oe, oo);
    }
}

extern "C" void kernel_launch(void* const* d_in, const int* in_sizes, int n_in,
                              void* d_out, int out_size, void* d_ws, size_t ws_size,
                              hipStream_t stream) {
    const float* x     = (const float*)d_in[0];
    const int*   ei    = (const int*)d_in[1];
    const float* ea    = (const float*)d_in[2];
    const float* Wsg   = (const float*)d_in[3];
    const float* bsg   = (const float*)d_in[4];
    const float* Wg    = (const float*)d_in[5];
    const float* att_s = (const float*)d_in[6];
    const float* att_d = (const float*)d_in[7];
    const float* bgat  = (const float*)d_in[8];
    const int* src = ei;
    const int* dst = ei + N_EDGES;
    float* out = (float*)d_out;

    char* ws = (char*)d_ws;
    size_t off = 0;
    auto alloc = [&](size_t bytes) -> void* {
        void* p = ws + off;
        off = (off + bytes + 255) & ~(size_t)255;
        return p;
    };
    unsigned*       deg32  = (unsigned*)alloc((size_t)N_NODES * 4);
    float*          dinv   = (float*)alloc((size_t)N_NODES * 4);
    unsigned short* rank   = (unsigned short*)alloc((size_t)N_EDGES * 2);
    int*            offs   = (int*)alloc((size_t)(N_NODES + 1) * 4);
    int*            bsum   = (int*)alloc(256 * 4);
    int2*           edges  = (int2*)alloc((size_t)N_EDGES * 8);
    short*          WhT    = (short*)alloc((size_t)IN_CH * HID * 2);
    short*          WlT    = (short*)alloc((size_t)IN_CH * HID * 2);
    __half*         h0     = (__half*)alloc((size_t)N_NODES * HID * 2);
    __half*         h1     = (__half*)alloc((size_t)N_NODES * HID * 2);
    uint2*          g4h    = (uint2*)alloc((size_t)N_NODES * 32 * 8);
    float2*         asrc2  = (float2*)alloc((size_t)N_NODES * 8);
    float4*         admm   = (float4*)alloc((size_t)N_NODES * 16);
    (void)ws_size; (void)in_sizes; (void)n_in; (void)out_size;

    hipMemsetAsync(deg32, 0, (size_t)N_NODES * 4, stream);

    k_wsplit<<<(IN_CH * HID + 255) / 256, 256, 0, stream>>>(Wsg, WhT, WlT);
    k_hist<<<(N_EDGES + 255) / 256, 256, 0, stream>>>(dst, ea, deg32, rank);

    int nb = (N_NODES + 255) / 256;  // 196
    k_scan_reduce<<<nb, 256, 0, stream>>>(deg32, bsum, dinv, N_NODES);
    k_scan_bsum<<<1, 256, 0, stream>>>(bsum, nb);
    k_scan_final<<<nb, 256, 0, stream>>>(deg32, bsum, offs, N_NODES);

    k_scatter<<<(N_EDGES + 255) / 256, 256, 0, stream>>>(src, dst, ea, dinv, offs, rank, edges);

    k_gemm1<<<(N_NODES + 63) / 64, 256, 0, stream>>>(x, WhT, WlT, h0);
    k_hop<<<N_NODES / 2, 256, 0, stream>>>((const unsigned*)h0, offs, edges, dinv, (unsigned*)h1);
    k_hop<<<N_NODES / 2, 256, 0, stream>>>((const unsigned*)h1, offs, edges, dinv, (unsigned*)h0);
    k_act_gemm2<<<(N_NODES + G2_ROWS - 1) / G2_ROWS, 256, 0, stream>>>(h0, bsg, Wg, att_s, att_d, g4h, asrc2, admm);
    k_gat<<<N_NODES / 2, 256, 0, stream>>>(g4h, asrc2, admm, offs, edges, bgat, out);
}

// Round 9
// 385.897 us; speedup vs baseline: 2.6070x; 1.0084x over previous
//
#include <hip/hip_runtime.h>
#include <hip/hip_fp16.h>
#include <math.h>

#define N_NODES 50000
#define N_EDGES 1600000
#define IN_CH 512
#define HID 64
#define OUTC 64
#define NEG_SLOPE 0.2f
#define EA_SCALE 131072.0f   // 2^17
#define PCAP 128             // LDS p-cache entries per half-wave

typedef __attribute__((ext_vector_type(8))) short bf16x8;
typedef __attribute__((ext_vector_type(4))) float f32x4;

__device__ __forceinline__ unsigned bf16r(float f) {
    unsigned b = __float_as_uint(f);
    return (b + 0x7FFFu + ((b >> 16) & 1u)) >> 16;
}

// ---------------- fused histogram: 1x 32-bit packed atomic/edge ----------------
__global__ void k_hist(const int* __restrict__ dst, const float* __restrict__ ea,
                       unsigned* __restrict__ deg32,
                       unsigned short* __restrict__ rank) {
    int e = blockIdx.x * blockDim.x + threadIdx.x;
    if (e >= N_EDGES) return;
    int d = dst[e];
    unsigned pack = (1u << 24) | (unsigned)(ea[e] * EA_SCALE);
    unsigned old = atomicAdd(&deg32[d], pack);
    rank[e] = (unsigned short)(old >> 24);
}

// ---------------- W split+transpose: WhT/WlT [c][k] bf16 ----------------
__global__ void k_wsplit(const float* __restrict__ W,
                         short* __restrict__ WhT, short* __restrict__ WlT) {
    int idx = blockIdx.x * 256 + threadIdx.x;
    if (idx >= IN_CH * HID) return;
    int k = idx >> 6, c = idx & 63;
    float wv = W[idx];
    unsigned h = bf16r(wv);
    float res = wv - __uint_as_float(h << 16);
    unsigned l = bf16r(res);
    WhT[c * IN_CH + k] = (short)h;
    WlT[c * IN_CH + k] = (short)l;
}

// ---------------- scan level 1 (+ fused dinv decode) ----------------
__global__ void k_scan_reduce(const unsigned* __restrict__ deg32,
                              int* bsum, float* dinv, int n) {
    __shared__ int lds[256];
    int i = blockIdx.x * 256 + threadIdx.x;
    unsigned dv = (i < n) ? deg32[i] : 0u;
    lds[threadIdx.x] = (int)(dv >> 24);
    if (i < n)
        dinv[i] = rsqrtf(1.0f + (float)(dv & 0xFFFFFFu) * (1.0f / EA_SCALE));
    __syncthreads();
    for (int s = 128; s > 0; s >>= 1) {
        if (threadIdx.x < s) lds[threadIdx.x] += lds[threadIdx.x + s];
        __syncthreads();
    }
    if (threadIdx.x == 0) bsum[blockIdx.x] = lds[0];
}

__global__ void k_scan_bsum(int* bsum, int nb) {
    __shared__ int lds[256];
    int t = threadIdx.x;
    int v = (t < nb) ? bsum[t] : 0;
    lds[t] = v;
    __syncthreads();
    for (int s = 1; s < 256; s <<= 1) {
        int add = (t >= s) ? lds[t - s] : 0;
        __syncthreads();
        lds[t] += add;
        __syncthreads();
    }
    if (t < nb) bsum[t] = lds[t] - v;  // exclusive
}

__global__ void k_scan_final(const unsigned* __restrict__ deg32,
                             const int* __restrict__ bsum,
                             int* offsets, int n) {
    __shared__ int lds[256];
    int t = threadIdx.x;
    int i = blockIdx.x * 256 + t;
    int v = (i < n) ? (int)(deg32[i] >> 24) : 0;
    lds[t] = v;
    __syncthreads();
    for (int s = 1; s < 256; s <<= 1) {
        int add = (t >= s) ? lds[t - s] : 0;
        __syncthreads();
        lds[t] += add;
        __syncthreads();
    }
    int incl = lds[t];
    int base = bsum[blockIdx.x];
    if (i < n) offsets[i] = base + incl - v;
    if (i == n - 1) offsets[n] = base + incl;
}

// ---------------- CSR scatter (atomic-free via rank): {src*32, weight} ----------------
__global__ void k_scatter(const int* __restrict__ src, const int* __restrict__ dst,
                          const float* __restrict__ ea, const float* __restrict__ dinv,
                          const int* __restrict__ offsets,
                          const unsigned short* __restrict__ rank,
                          int2* __restrict__ edges) {
    int e = blockIdx.x * blockDim.x + threadIdx.x;
    if (e >= N_EDGES) return;
    int s = src[e], d = dst[e];
    int pos = offsets[d] + rank[e];
    edges[pos] = make_int2(s << 5, __float_as_int(dinv[s] * ea[e] * dinv[d]));
}

// ---------------- GEMM1 via MFMA split-bf16, LDS-staged x-tile ----------------
#define G1R 64
#define G1KC 128
__global__ __launch_bounds__(256) void k_gemm1(const float* __restrict__ x,
                                               const short* __restrict__ WhT,
                                               const short* __restrict__ WlT,
                                               __half* __restrict__ p) {
    __shared__ float xs[G1R][G1KC + 4];   // 33.8 KB; +4 pad -> even bank spread
    int tid = threadIdx.x;
    int lane = tid & 63, wv = tid >> 6;
    int r0 = blockIdx.x * G1R;
    const int bo0 = (lane & 15) * IN_CH + ((lane >> 4) << 3);
    int srow = tid >> 5;            // 0..7
    int scol = (tid & 31) * 4;      // 0..124
    f32x4 acc0 = {0.f, 0.f, 0.f, 0.f};
    f32x4 acc1 = {0.f, 0.f, 0.f, 0.f};
    f32x4 acc2 = {0.f, 0.f, 0.f, 0.f};
    f32x4 acc3 = {0.f, 0.f, 0.f, 0.f};

    for (int k0 = 0; k0 < IN_CH; k0 += G1KC) {
        // stage 64x128 x-tile, fully coalesced, 8 loads in flight
#pragma unroll
        for (int pp = 0; pp < 8; pp++) {
            int row = pp * 8 + srow;
            int gr = r0 + row;
            float4 v = make_float4(0.f, 0.f, 0.f, 0.f);
            if (gr < N_NODES)
                v = *(const float4*)(x + (size_t)gr * IN_CH + k0 + scol);
            *(float4*)&xs[row][scol] = v;
        }
        __syncthreads();
#pragma unroll
        for (int kk = 0; kk < G1KC; kk += 32) {
            int arow = wv * 16 + (lane & 15);
            int acol = kk + ((lane >> 4) << 3);
            float4 xa = *(const float4*)&xs[arow][acol];
            float4 xb = *(const float4*)&xs[arow][acol + 4];
            float xv[8] = {xa.x, xa.y, xa.z, xa.w, xb.x, xb.y, xb.z, xb.w};
            bf16x8 ah, al;
#pragma unroll
            for (int j = 0; j < 8; j++) {
                unsigned b = __float_as_uint(xv[j]);
                float res = xv[j] - __uint_as_float(b & 0xFFFF0000u);
                ah[j] = (short)(b >> 16);
                al[j] = (short)(__float_as_uint(res) >> 16);
            }
            const short* bp = WhT + bo0 + k0 + kk;
            const short* lp = WlT + bo0 + k0 + kk;
            bf16x8 bh, bl;
            bh = *(const bf16x8*)(bp);
            bl = *(const bf16x8*)(lp);
            acc0 = __builtin_amdgcn_mfma_f32_16x16x32_bf16(ah, bh, acc0, 0, 0, 0);
            acc0 = __builtin_amdgcn_mfma_f32_16x16x32_bf16(ah, bl, acc0, 0, 0, 0);
            acc0 = __builtin_amdgcn_mfma_f32_16x16x32_bf16(al, bh, acc0, 0, 0, 0);
            bh = *(const bf16x8*)(bp + 16 * IN_CH);
            bl = *(const bf16x8*)(lp + 16 * IN_CH);
            acc1 = __builtin_amdgcn_mfma_f32_16x16x32_bf16(ah, bh, acc1, 0, 0, 0);
            acc1 = __builtin_amdgcn_mfma_f32_16x16x32_bf16(ah, bl, acc1, 0, 0, 0);
            acc1 = __builtin_amdgcn_mfma_f32_16x16x32_bf16(al, bh, acc1, 0, 0, 0);
            bh = *(const bf16x8*)(bp + 32 * IN_CH);
            bl = *(const bf16x8*)(lp + 32 * IN_CH);
            acc2 = __builtin_amdgcn_mfma_f32_16x16x32_bf16(ah, bh, acc2, 0, 0, 0);
            acc2 = __builtin_amdgcn_mfma_f32_16x16x32_bf16(ah, bl, acc2, 0, 0, 0);
            acc2 = __builtin_amdgcn_mfma_f32_16x16x32_bf16(al, bh, acc2, 0, 0, 0);
            bh = *(const bf16x8*)(bp + 48 * IN_CH);
            bl = *(const bf16x8*)(lp + 48 * IN_CH);
            acc3 = __builtin_amdgcn_mfma_f32_16x16x32_bf16(ah, bh, acc3, 0, 0, 0);
            acc3 = __builtin_amdgcn_mfma_f32_16x16x32_bf16(ah, bl, acc3, 0, 0, 0);
            acc3 = __builtin_amdgcn_mfma_f32_16x16x32_bf16(al, bh, acc3, 0, 0, 0);
        }
        __syncthreads();
    }
    int crow = r0 + wv * 16 + ((lane >> 4) << 2);
    int ccol = lane & 15;
#pragma unroll
    for (int r = 0; r < 4; r++) {
        int gr = crow + r;
        if (gr < N_NODES) {
            p[(unsigned)gr * HID + ccol]      = __float2half(acc0[r]);
            p[(unsigned)gr * HID + 16 + ccol] = __float2half(acc1[r]);
            p[(unsigned)gr * HID + 32 + ccol] = __float2half(acc2[r]);
            p[(unsigned)gr * HID + 48 + ccol] = __float2half(acc3[r]);
        }
    }
}

// ---------------- one hop: half2 gathers, 8 edges in flight, 2 waves/node ----------------
__global__ __launch_bounds__(256) void k_hop(const unsigned* __restrict__ hin2,
                                             const int* __restrict__ offsets,
                                             const int2* __restrict__ edges,
                                             const float* __restrict__ dinv,
                                             unsigned* __restrict__ hout2) {
    __shared__ float2 part[2][32];
    int tid = threadIdx.x;
    int w = tid >> 6, lane = tid & 63;
    int slot = w >> 1, half = w & 1;
    int cl = lane & 31, es = lane >> 5;
    int v = blockIdx.x * 2 + slot;
    int beg = offsets[v], end = offsets[v + 1];
    int mid = beg + ((end - beg) >> 1);
    int lo = half ? mid : beg;
    int hi = half ? end : mid;
    float ax = 0.f, ay = 0.f, bx = 0.f, by = 0.f;
    float cx = 0.f, cy = 0.f, dx = 0.f, dy = 0.f;
    if (!half && !es) {
        float dv = dinv[v];
        float sw = dv * dv;
        unsigned gh = hin2[(unsigned)v * 32 + cl];
        float2 hf = __half22float2(*(__half2*)&gh);
        ax = sw * hf.x; ay = sw * hf.y;
    }
    int i = lo;
    for (; i + 8 <= hi; i += 8) {
        int2 e0 = edges[i + es];
        int2 e1 = edges[i + 2 + es];
        int2 e2 = edges[i + 4 + es];
        int2 e3 = edges[i + 6 + es];
        unsigned g0 = hin2[(unsigned)(e0.x + cl)];
        unsigned g1 = hin2[(unsigned)(e1.x + cl)];
        unsigned g2 = hin2[(unsigned)(e2.x + cl)];
        unsigned g3 = hin2[(unsigned)(e3.x + cl)];
        float w0 = __int_as_float(e0.y), w1 = __int_as_float(e1.y);
        float w2 = __int_as_float(e2.y), w3 = __int_as_float(e3.y);
        float2 h0 = __half22float2(*(__half2*)&g0);
        float2 h1 = __half22float2(*(__half2*)&g1);
        float2 h2 = __half22float2(*(__half2*)&g2);
        float2 h3 = __half22float2(*(__half2*)&g3);
        ax += w0 * h0.x; ay += w0 * h0.y;
        bx += w1 * h1.x; by += w1 * h1.y;
        cx += w2 * h2.x; cy += w2 * h2.y;
        dx += w3 * h3.x; dy += w3 * h3.y;
    }
    for (; i + es < hi; i += 2) {
        int2 e0 = edges[i + es];
        unsigned g0 = hin2[(unsigned)(e0.x + cl)];
        float w0 = __int_as_float(e0.y);
        float2 h0 = __half22float2(*(__half2*)&g0);
        ax += w0 * h0.x; ay += w0 * h0.y;
    }
    ax += bx + cx + dx; ay += by + cy + dy;
    ax += __shfl_xor(ax, 32);
    ay += __shfl_xor(ay, 32);
    if (half && lane < 32) part[slot][cl] = make_float2(ax, ay);
    __syncthreads();
    if (!half && lane < 32) {
        float2 pp = part[slot][cl];
        __half2 hp = __floats2half2_rn(ax + pp.x, ay + pp.y);
        hout2[(unsigned)v * 32 + cl] = *(unsigned*)&hp;
    }
}

// ---------------- bias + SELU + GEMM2 -> packed uint2 g, score tables ----------------
#define G2_ROWS 32
__global__ __launch_bounds__(256) void k_act_gemm2(const __half* __restrict__ h2,
                                                   const float* __restrict__ bsg,
                                                   const float* __restrict__ Wg,
                                                   const float* __restrict__ att_s,
                                                   const float* __restrict__ att_d,
                                                   uint2* __restrict__ g4h,
                                                   float2* __restrict__ asrc2,
                                                   float4* __restrict__ admm) {
    __shared__ float hs[G2_ROWS][HID];   // 8 KB
    int tid = threadIdx.x;
    int wave = tid >> 6, lane = tid & 63;
    int r0 = blockIdx.x * G2_ROWS;
    int rbase = wave * 8;

    const float SC = 1.0507009873554805f, AL = 1.6732632423543772f;
    {
        int row = tid >> 3, c0 = (tid & 7) * 8;
        int r = r0 + row;
        float vals[8];
        if (r < N_NODES) {
            uint4 raw = *(const uint4*)(h2 + (unsigned)r * HID + c0);
            float2 f0 = __half22float2(*(__half2*)&raw.x);
            float2 f1 = __half22float2(*(__half2*)&raw.y);
            float2 f2 = __half22float2(*(__half2*)&raw.z);
            float2 f3 = __half22float2(*(__half2*)&raw.w);
            vals[0] = f0.x; vals[1] = f0.y; vals[2] = f1.x; vals[3] = f1.y;
            vals[4] = f2.x; vals[5] = f2.y; vals[6] = f3.x; vals[7] = f3.y;
        } else {
#pragma unroll
            for (int j = 0; j < 8; j++) vals[j] = 0.f;
        }
#pragma unroll
        for (int j = 0; j < 8; j++) {
            float hv = vals[j] + bsg[c0 + j];
            hv = (hv > 0.f) ? SC * hv : SC * AL * (__expf(hv) - 1.f);
            hs[row][c0 + j] = hv;
        }
    }
    __syncthreads();

    float accx[8], accy[8];
#pragma unroll
    for (int j = 0; j < 8; j++) { accx[j] = 0.f; accy[j] = 0.f; }
#pragma unroll 2
    for (int k = 0; k < HID; k++) {
        float w0 = Wg[(size_t)k * 128 + lane];        // coalesced, L1-resident
        float w1 = Wg[(size_t)k * 128 + 64 + lane];
#pragma unroll
        for (int j = 0; j < 8; j++) {
            float hk = hs[rbase + j][k];              // LDS broadcast
            accx[j] += hk * w0;
            accy[j] += hk * w1;
        }
    }
    float ats0 = att_s[lane], ats1 = att_s[64 + lane];
    float atd0 = att_d[lane], atd1 = att_d[64 + lane];
#pragma unroll
    for (int j = 0; j < 8; j++) {
        int v = r0 + rbase + j;
        if (v >= N_NODES) break;
        __half2 gp = __floats2half2_rn(accx[j], accy[j]);
        unsigned gpu = *(unsigned*)&gp;
        unsigned other = (unsigned)__shfl_xor((int)gpu, 1);
        if (!(lane & 1)) g4h[(unsigned)v * 32 + (lane >> 1)] = make_uint2(gpu, other);
        float s0 = accx[j] * ats0, s1 = accy[j] * ats1;
        float d0 = accx[j] * atd0, d1 = accy[j] * atd1;
#pragma unroll
        for (int o = 32; o > 0; o >>= 1) {
            s0 += __shfl_xor(s0, o);
            s1 += __shfl_xor(s1, o);
            d0 += __shfl_xor(d0, o);
            d1 += __shfl_xor(d1, o);
        }
        if (lane == 0) {
            asrc2[v] = make_float2(s0, s1);
            float m0 = s0 + d0; m0 = (m0 > 0.f) ? m0 : NEG_SLOPE * m0;
            float m1 = s1 + d1; m1 = (m1 > 0.f) ? m1 : NEG_SLOPE * m1;
            admm[v] = make_float4(d0, d1, m0, m1);
        }
    }
}

// ---------------- GAT: two-phase (lane-parallel scores -> LDS p-cache) ----------------
__global__ __launch_bounds__(256) void k_gat(const uint2* __restrict__ g4h,
                                             const float2* __restrict__ asrc2,
                                             const float4* __restrict__ admm,
                                             const int* __restrict__ offsets,
                                             const int2* __restrict__ edges,
                                             const float* __restrict__ bgat,
                                             float* __restrict__ out) {
    __shared__ int4 pbuf[2][2][PCAP];    // 8 KB: {src*32, p0, p1, -}
    __shared__ float4 pacc[2][32];
    __shared__ float2 pden[2][32];
    int tid = threadIdx.x;
    int w = tid >> 6, lane = tid & 63;
    int slot = w >> 1, half = w & 1;
    int cl = lane & 31, es = lane >> 5;
    int v = blockIdx.x * 2 + slot;
    float4 am = admm[v];   // ad0, ad1, m0, m1 (wave-uniform)
    int beg = offsets[v], end = offsets[v + 1];
    int mid = beg + ((end - beg) >> 1);
    int lo = half ? mid : beg;
    int hi = half ? end : mid;
    int n = hi - lo;

    // ---- phase 1: lane-parallel scores, den reduce, p-cache fill ----
    float pd0 = 0.f, pd1 = 0.f;
    for (int i = lo + lane; i < hi; i += 64) {
        int2 e = edges[i];                          // coalesced
        float2 a = asrc2[(unsigned)e.x >> 5];       // 8B gather, L2-resident
        float t0 = a.x + am.x; t0 = (t0 > 0.f) ? t0 : NEG_SLOPE * t0;
        float t1 = a.y + am.y; t1 = (t1 > 0.f) ? t1 : NEG_SLOPE * t1;
        float p0 = __expf(t0 - am.z);
        float p1 = __expf(t1 - am.w);
        int idx = i - lo;
        if (idx < PCAP)
            pbuf[slot][half][idx] = make_int4(e.x, __float_as_int(p0), __float_as_int(p1), 0);
        pd0 += p0; pd1 += p1;
    }
#pragma unroll
    for (int o = 32; o > 0; o >>= 1) {
        pd0 += __shfl_xor(pd0, o);
        pd1 += __shfl_xor(pd1, o);
    }
    if (!half) { pd0 += 1.f; pd1 += 1.f; }   // self-loop p=1 (once per node)

    // ---- phase 2: gather+accumulate using cached p ----
    float aA = 0.f, aB = 0.f, aC = 0.f, aD = 0.f;
    float bA = 0.f, bB = 0.f, bC = 0.f, bD = 0.f;
    if (!half && !es) {
        uint2 gs = g4h[(unsigned)v * 32 + cl];   // self, p=1
        float2 gx = __half22float2(*(__half2*)&gs.x);
        float2 gy = __half22float2(*(__half2*)&gs.y);
        aA = gx.x; aB = gx.y; aC = gy.x; aD = gy.y;
    }
    int n1 = (n < PCAP) ? n : PCAP;
    int ii = 0;
    for (; ii + 8 <= n1; ii += 8) {
        int4 e0 = pbuf[slot][half][ii + es];
        int4 e1 = pbuf[slot][half][ii + 2 + es];
        int4 e2 = pbuf[slot][half][ii + 4 + es];
        int4 e3 = pbuf[slot][half][ii + 6 + es];
        uint2 g0 = g4h[(unsigned)(e0.x + cl)];
        uint2 g1 = g4h[(unsigned)(e1.x + cl)];
        uint2 g2 = g4h[(unsigned)(e2.x + cl)];
        uint2 g3 = g4h[(unsigned)(e3.x + cl)];
        float p00 = __int_as_float(e0.y), p01 = __int_as_float(e0.z);
        float p10 = __int_as_float(e1.y), p11 = __int_as_float(e1.z);
        float p20 = __int_as_float(e2.y), p21 = __int_as_float(e2.z);
        float p30 = __int_as_float(e3.y), p31 = __int_as_float(e3.z);
        float2 g0x = __half22float2(*(__half2*)&g0.x);
        float2 g0y = __half22float2(*(__half2*)&g0.y);
        float2 g1x = __half22float2(*(__half2*)&g1.x);
        float2 g1y = __half22float2(*(__half2*)&g1.y);
        float2 g2x = __half22float2(*(__half2*)&g2.x);
        float2 g2y = __half22float2(*(__half2*)&g2.y);
        float2 g3x = __half22float2(*(__half2*)&g3.x);
        float2 g3y = __half22float2(*(__half2*)&g3.y);
        aA += p00 * g0x.x; aB += p01 * g0x.y; aC += p00 * g0y.x; aD += p01 * g0y.y;
        bA += p10 * g1x.x; bB += p11 * g1x.y; bC += p10 * g1y.x; bD += p11 * g1y.y;
        aA += p20 * g2x.x; aB += p21 * g2x.y; aC += p20 * g2y.x; aD += p21 * g2y.y;
        bA += p30 * g3x.x; bB += p31 * g3x.y; bC += p30 * g3y.x; bD += p31 * g3y.y;
    }
    for (; ii + es < n1; ii += 2) {
        int4 e0 = pbuf[slot][half][ii + es];
        uint2 g0 = g4h[(unsigned)(e0.x + cl)];
        float p00 = __int_as_float(e0.y), p01 = __int_as_float(e0.z);
        float2 g0x = __half22float2(*(__half2*)&g0.x);
        float2 g0y = __half22float2(*(__half2*)&g0.y);
        aA += p00 * g0x.x; aB += p01 * g0x.y; aC += p00 * g0y.x; aD += p01 * g0y.y;
    }
    // rare overflow tail (deg/2 > PCAP): inline scores
    for (int jj = PCAP + es; jj < n; jj += 2) {
        int2 e = edges[lo + jj];
        float2 a = asrc2[(unsigned)e.x >> 5];
        float t0 = a.x + am.x; t0 = (t0 > 0.f) ? t0 : NEG_SLOPE * t0;
        float t1 = a.y + am.y; t1 = (t1 > 0.f) ? t1 : NEG_SLOPE * t1;
        float p0 = __expf(t0 - am.z);
        float p1 = __expf(t1 - am.w);
        uint2 g0 = g4h[(unsigned)(e.x + cl)];
        float2 g0x = __half22float2(*(__half2*)&g0.x);
        float2 g0y = __half22float2(*(__half2*)&g0.y);
        aA += p0 * g0x.x; aB += p1 * g0x.y; aC += p0 * g0y.x; aD += p1 * g0y.y;
    }
    aA += bA; aB += bB; aC += bC; aD += bD;
    aA += __shfl_xor(aA, 32); aB += __shfl_xor(aB, 32);
    aC += __shfl_xor(aC, 32); aD += __shfl_xor(aD, 32);
    if (half && lane < 32) {
        pacc[slot][cl] = make_float4(aA, aB, aC, aD);
        pden[slot][cl] = make_float2(pd0, pd1);
    }
    __syncthreads();
    if (!half && lane < 32) {
        float4 pa = pacc[slot][cl];
        float2 pd = pden[slot][cl];
        float r0 = 1.f / (pd0 + pd.x), r1 = 1.f / (pd1 + pd.y);
        float oe = 0.5f * ((aA + pa.x) * r0 + (aB + pa.y) * r1) + bgat[cl * 2];
        float oo = 0.5f * ((aC + pa.z) * r0 + (aD + pa.w) * r1) + bgat[cl * 2 + 1];
        *(float2*)&out[(unsigned)v * OUTC + cl * 2] = make_float2(oe, oo);
    }
}

extern "C" void kernel_launch(void* const* d_in, const int* in_sizes, int n_in,
                              void* d_out, int out_size, void* d_ws, size_t ws_size,
                              hipStream_t stream) {
    const float* x     = (const float*)d_in[0];
    const int*   ei    = (const int*)d_in[1];
    const float* ea    = (const float*)d_in[2];
    const float* Wsg   = (const float*)d_in[3];
    const float* bsg   = (const float*)d_in[4];
    const float* Wg    = (const float*)d_in[5];
    const float* att_s = (const float*)d_in[6];
    const float* att_d = (const float*)d_in[7];
    const float* bgat  = (const float*)d_in[8];
    const int* src = ei;
    const int* dst = ei + N_EDGES;
    float* out = (float*)d_out;

    char* ws = (char*)d_ws;
    size_t off = 0;
    auto alloc = [&](size_t bytes) -> void* {
        void* p = ws + off;
        off = (off + bytes + 255) & ~(size_t)255;
        return p;
    };
    unsigned*       deg32  = (unsigned*)alloc((size_t)N_NODES * 4);
    float*          dinv   = (float*)alloc((size_t)N_NODES * 4);
    unsigned short* rank   = (unsigned short*)alloc((size_t)N_EDGES * 2);
    int*            offs   = (int*)alloc((size_t)(N_NODES + 1) * 4);
    int*            bsum   = (int*)alloc(256 * 4);
    int2*           edges  = (int2*)alloc((size_t)N_EDGES * 8);
    short*          WhT    = (short*)alloc((size_t)IN_CH * HID * 2);
    short*          WlT    = (short*)alloc((size_t)IN_CH * HID * 2);
    __half*         h0     = (__half*)alloc((size_t)N_NODES * HID * 2);
    __half*         h1     = (__half*)alloc((size_t)N_NODES * HID * 2);
    uint2*          g4h    = (uint2*)alloc((size_t)N_NODES * 32 * 8);
    float2*         asrc2  = (float2*)alloc((size_t)N_NODES * 8);
    float4*         admm   = (float4*)alloc((size_t)N_NODES * 16);
    (void)ws_size; (void)in_sizes; (void)n_in; (void)out_size;

    hipMemsetAsync(deg32, 0, (size_t)N_NODES * 4, stream);

    k_wsplit<<<(IN_CH * HID + 255) / 256, 256, 0, stream>>>(Wsg, WhT, WlT);
    k_hist<<<(N_EDGES + 255) / 256, 256, 0, stream>>>(dst, ea, deg32, rank);

    int nb = (N_NODES + 255) / 256;  // 196
    k_scan_reduce<<<nb, 256, 0, stream>>>(deg32, bsum, dinv, N_NODES);
    k_scan_bsum<<<1, 256, 0, stream>>>(bsum, nb);
    k_scan_final<<<nb, 256, 0, stream>>>(deg32, bsum, offs, N_NODES);

    k_scatter<<<(N_EDGES + 255) / 256, 256, 0, stream>>>(src, dst, ea, dinv, offs, rank, edges);

    k_gemm1<<<(N_NODES + G1R - 1) / G1R, 256, 0, stream>>>(x, WhT, WlT, h0);
    k_hop<<<N_NODES / 2, 256, 0, stream>>>((const unsigned*)h0, offs, edges, dinv, (unsigned*)h1);
    k_hop<<<N_NODES / 2, 256, 0, stream>>>((const unsigned*)h1, offs, edges, dinv, (unsigned*)h0);
    k_act_gemm2<<<(N_NODES + G2_ROWS - 1) / G2_ROWS, 256, 0, stream>>>(h0, bsg, Wg, att_s, att_d, g4h, asrc2, admm);
    k_gat<<<N_NODES / 2, 256, 0, stream>>>(g4h, asrc2, admm, offs, edges, bgat, out);
}

// Round 10
// 320.408 us; speedup vs baseline: 3.1399x; 1.2044x over previous
//
#include <hip/hip_runtime.h>
#include <hip/hip_fp16.h>
#include <math.h>

#define N_NODES 50000
#define N_EDGES 1600000
#define IN_CH 512
#define HID 64
#define OUTC 64
#define NEG_SLOPE 0.2f
#define EA_SCALE 131072.0f   // 2^17
#define PCAP 128             // LDS p-cache entries per half-wave

typedef __attribute__((ext_vector_type(8))) short bf16x8;
typedef __attribute__((ext_vector_type(4))) float f32x4;

__device__ __forceinline__ unsigned bf16r(float f) {
    unsigned b = __float_as_uint(f);
    return (b + 0x7FFFu + ((b >> 16) & 1u)) >> 16;
}

// ---- W split into MFMA-fragment-order bf16 hi/lo ----
// Layout: Wfrag[((kstep*4 + cb)*2 + hl)*512 + lane*8 + j], kstep=k>>5, cb=c>>4,
// lane=(c&15)|(((k>>3)&3)<<4), j=k&7  ->  B-frag load is 1KB fully coalesced.
__global__ void k_wsplit(const float* __restrict__ W, short* __restrict__ Wfrag) {
    int idx = blockIdx.x * 256 + threadIdx.x;
    if (idx >= IN_CH * HID) return;
    int k = idx >> 6, c = idx & 63;
    float wv = W[idx];
    unsigned h = bf16r(wv);
    float res = wv - __uint_as_float(h << 16);
    unsigned l = bf16r(res);
    int kstep = k >> 5, cb = c >> 4;
    int lane = (c & 15) | (((k >> 3) & 3) << 4);
    int j = k & 7;
    int base = ((kstep * 4 + cb) * 2) * 512 + lane * 8 + j;
    Wfrag[base] = (short)h;
    Wfrag[base + 512] = (short)l;
}

// ---------------- FUSED: gemm1 (MFMA split-bf16) + histogram ----------------
#define G1R 64
#define G1KC 64
__global__ __launch_bounds__(256) void k_gemm_hist(const float* __restrict__ x,
                                                   const short* __restrict__ Wfrag,
                                                   __half* __restrict__ p,
                                                   const int* __restrict__ dst,
                                                   const float* __restrict__ ea,
                                                   unsigned* __restrict__ deg32,
                                                   unsigned short* __restrict__ rank) {
    __shared__ float xs[G1R][G1KC + 4];   // 17.4 KB
    int tid = threadIdx.x;
    int bid = blockIdx.x;

    if (bid & 1) {
        // ---- histogram role: 2048-edge chunk, 1x packed 32-bit atomic/edge ----
        int e0 = (bid >> 1) * 2048;
        int e1 = e0 + 2048; if (e1 > N_EDGES) e1 = N_EDGES;
        for (int e = e0 + tid; e < e1; e += 256) {
            int d = dst[e];
            unsigned pack = (1u << 24) | (unsigned)(ea[e] * EA_SCALE);
            unsigned old = atomicAdd(&deg32[d], pack);
            rank[e] = (unsigned short)(old >> 24);
        }
        return;
    }

    // ---- gemm role ----
    int lane = tid & 63, wv = tid >> 6;
    int r0 = (bid >> 1) * G1R;
    f32x4 acc0 = {0.f, 0.f, 0.f, 0.f};
    f32x4 acc1 = {0.f, 0.f, 0.f, 0.f};
    f32x4 acc2 = {0.f, 0.f, 0.f, 0.f};
    f32x4 acc3 = {0.f, 0.f, 0.f, 0.f};

    for (int k0 = 0; k0 < IN_CH; k0 += G1KC) {
        // stage 64x64 x-tile: 4 instr/thread, each wave = 4 full 256B rows
#pragma unroll
        for (int it = 0; it < 4; it++) {
            int row = it * 16 + (tid >> 4);
            int gr = r0 + row;
            float4 v = make_float4(0.f, 0.f, 0.f, 0.f);
            if (gr < N_NODES)
                v = *(const float4*)(x + (size_t)gr * IN_CH + k0 + (tid & 15) * 4);
            *(float4*)&xs[row][(tid & 15) * 4] = v;
        }
        __syncthreads();
#pragma unroll
        for (int kk = 0; kk < 2; kk++) {
            int ks = (k0 >> 5) + kk;
            const short* wb = Wfrag + ks * 4096 + (lane << 3);
            bf16x8 bh0 = *(const bf16x8*)(wb);
            bf16x8 bl0 = *(const bf16x8*)(wb + 512);
            bf16x8 bh1 = *(const bf16x8*)(wb + 1024);
            bf16x8 bl1 = *(const bf16x8*)(wb + 1536);
            bf16x8 bh2 = *(const bf16x8*)(wb + 2048);
            bf16x8 bl2 = *(const bf16x8*)(wb + 2560);
            bf16x8 bh3 = *(const bf16x8*)(wb + 3072);
            bf16x8 bl3 = *(const bf16x8*)(wb + 3584);
            int arow = wv * 16 + (lane & 15);
            int acol = kk * 32 + ((lane >> 4) << 3);
            float4 xa = *(const float4*)&xs[arow][acol];
            float4 xb = *(const float4*)&xs[arow][acol + 4];
            float xv[8] = {xa.x, xa.y, xa.z, xa.w, xb.x, xb.y, xb.z, xb.w};
            bf16x8 ah, al;
#pragma unroll
            for (int j = 0; j < 8; j++) {
                unsigned b = __float_as_uint(xv[j]);
                float res = xv[j] - __uint_as_float(b & 0xFFFF0000u);
                ah[j] = (short)(b >> 16);
                al[j] = (short)(__float_as_uint(res) >> 16);
            }
            acc0 = __builtin_amdgcn_mfma_f32_16x16x32_bf16(ah, bh0, acc0, 0, 0, 0);
            acc0 = __builtin_amdgcn_mfma_f32_16x16x32_bf16(ah, bl0, acc0, 0, 0, 0);
            acc0 = __builtin_amdgcn_mfma_f32_16x16x32_bf16(al, bh0, acc0, 0, 0, 0);
            acc1 = __builtin_amdgcn_mfma_f32_16x16x32_bf16(ah, bh1, acc1, 0, 0, 0);
            acc1 = __builtin_amdgcn_mfma_f32_16x16x32_bf16(ah, bl1, acc1, 0, 0, 0);
            acc1 = __builtin_amdgcn_mfma_f32_16x16x32_bf16(al, bh1, acc1, 0, 0, 0);
            acc2 = __builtin_amdgcn_mfma_f32_16x16x32_bf16(ah, bh2, acc2, 0, 0, 0);
            acc2 = __builtin_amdgcn_mfma_f32_16x16x32_bf16(ah, bl2, acc2, 0, 0, 0);
            acc2 = __builtin_amdgcn_mfma_f32_16x16x32_bf16(al, bh2, acc2, 0, 0, 0);
            acc3 = __builtin_amdgcn_mfma_f32_16x16x32_bf16(ah, bh3, acc3, 0, 0, 0);
            acc3 = __builtin_amdgcn_mfma_f32_16x16x32_bf16(ah, bl3, acc3, 0, 0, 0);
            acc3 = __builtin_amdgcn_mfma_f32_16x16x32_bf16(al, bh3, acc3, 0, 0, 0);
        }
        __syncthreads();
    }
    int crow = r0 + wv * 16 + ((lane >> 4) << 2);
    int ccol = lane & 15;
#pragma unroll
    for (int r = 0; r < 4; r++) {
        int gr = crow + r;
        if (gr < N_NODES) {
            p[(unsigned)gr * HID + ccol]      = __float2half(acc0[r]);
            p[(unsigned)gr * HID + 16 + ccol] = __float2half(acc1[r]);
            p[(unsigned)gr * HID + 32 + ccol] = __float2half(acc2[r]);
            p[(unsigned)gr * HID + 48 + ccol] = __float2half(acc3[r]);
        }
    }
}

// ---------------- scan level 1 (+ fused dinv decode) ----------------
__global__ void k_scan_reduce(const unsigned* __restrict__ deg32,
                              int* bsum, float* dinv, int n) {
    __shared__ int lds[256];
    int i = blockIdx.x * 256 + threadIdx.x;
    unsigned dv = (i < n) ? deg32[i] : 0u;
    lds[threadIdx.x] = (int)(dv >> 24);
    if (i < n)
        dinv[i] = rsqrtf(1.0f + (float)(dv & 0xFFFFFFu) * (1.0f / EA_SCALE));
    __syncthreads();
    for (int s = 128; s > 0; s >>= 1) {
        if (threadIdx.x < s) lds[threadIdx.x] += lds[threadIdx.x + s];
        __syncthreads();
    }
    if (threadIdx.x == 0) bsum[blockIdx.x] = lds[0];
}

__global__ void k_scan_bsum(int* bsum, int nb) {
    __shared__ int lds[256];
    int t = threadIdx.x;
    int v = (t < nb) ? bsum[t] : 0;
    lds[t] = v;
    __syncthreads();
    for (int s = 1; s < 256; s <<= 1) {
        int add = (t >= s) ? lds[t - s] : 0;
        __syncthreads();
        lds[t] += add;
        __syncthreads();
    }
    if (t < nb) bsum[t] = lds[t] - v;  // exclusive
}

__global__ void k_scan_final(const unsigned* __restrict__ deg32,
                             const int* __restrict__ bsum,
                             int* offsets, int n) {
    __shared__ int lds[256];
    int t = threadIdx.x;
    int i = blockIdx.x * 256 + t;
    int v = (i < n) ? (int)(deg32[i] >> 24) : 0;
    lds[t] = v;
    __syncthreads();
    for (int s = 1; s < 256; s <<= 1) {
        int add = (t >= s) ? lds[t - s] : 0;
        __syncthreads();
        lds[t] += add;
        __syncthreads();
    }
    int incl = lds[t];
    int base = bsum[blockIdx.x];
    if (i < n) offsets[i] = base + incl - v;
    if (i == n - 1) offsets[n] = base + incl;
}

// ---------------- CSR scatter (atomic-free via rank): {src*32, weight} ----------------
__global__ void k_scatter(const int* __restrict__ src, const int* __restrict__ dst,
                          const float* __restrict__ ea, const float* __restrict__ dinv,
                          const int* __restrict__ offsets,
                          const unsigned short* __restrict__ rank,
                          int2* __restrict__ edges) {
    int e = blockIdx.x * blockDim.x + threadIdx.x;
    if (e >= N_EDGES) return;
    int s = src[e], d = dst[e];
    int pos = offsets[d] + rank[e];
    edges[pos] = make_int2(s << 5, __float_as_int(dinv[s] * ea[e] * dinv[d]));
}

// ---------------- one hop: half2 gathers, 8 edges in flight, 2 waves/node ----------------
__global__ __launch_bounds__(256) void k_hop(const unsigned* __restrict__ hin2,
                                             const int* __restrict__ offsets,
                                             const int2* __restrict__ edges,
                                             const float* __restrict__ dinv,
                                             unsigned* __restrict__ hout2) {
    __shared__ float2 part[2][32];
    int tid = threadIdx.x;
    int w = tid >> 6, lane = tid & 63;
    int slot = w >> 1, half = w & 1;
    int cl = lane & 31, es = lane >> 5;
    int v = blockIdx.x * 2 + slot;
    int beg = offsets[v], end = offsets[v + 1];
    int mid = beg + ((end - beg) >> 1);
    int lo = half ? mid : beg;
    int hi = half ? end : mid;
    float ax = 0.f, ay = 0.f, bx = 0.f, by = 0.f;
    float cx = 0.f, cy = 0.f, dx = 0.f, dy = 0.f;
    if (!half && !es) {
        float dv = dinv[v];
        float sw = dv * dv;
        unsigned gh = hin2[(unsigned)v * 32 + cl];
        float2 hf = __half22float2(*(__half2*)&gh);
        ax = sw * hf.x; ay = sw * hf.y;
    }
    int i = lo;
    for (; i + 8 <= hi; i += 8) {
        int2 e0 = edges[i + es];
        int2 e1 = edges[i + 2 + es];
        int2 e2 = edges[i + 4 + es];
        int2 e3 = edges[i + 6 + es];
        unsigned g0 = hin2[(unsigned)(e0.x + cl)];
        unsigned g1 = hin2[(unsigned)(e1.x + cl)];
        unsigned g2 = hin2[(unsigned)(e2.x + cl)];
        unsigned g3 = hin2[(unsigned)(e3.x + cl)];
        float w0 = __int_as_float(e0.y), w1 = __int_as_float(e1.y);
        float w2 = __int_as_float(e2.y), w3 = __int_as_float(e3.y);
        float2 h0 = __half22float2(*(__half2*)&g0);
        float2 h1 = __half22float2(*(__half2*)&g1);
        float2 h2 = __half22float2(*(__half2*)&g2);
        float2 h3 = __half22float2(*(__half2*)&g3);
        ax += w0 * h0.x; ay += w0 * h0.y;
        bx += w1 * h1.x; by += w1 * h1.y;
        cx += w2 * h2.x; cy += w2 * h2.y;
        dx += w3 * h3.x; dy += w3 * h3.y;
    }
    for (; i + es < hi; i += 2) {
        int2 e0 = edges[i + es];
        unsigned g0 = hin2[(unsigned)(e0.x + cl)];
        float w0 = __int_as_float(e0.y);
        float2 h0 = __half22float2(*(__half2*)&g0);
        ax += w0 * h0.x; ay += w0 * h0.y;
    }
    ax += bx + cx + dx; ay += by + cy + dy;
    ax += __shfl_xor(ax, 32);
    ay += __shfl_xor(ay, 32);
    if (half && lane < 32) part[slot][cl] = make_float2(ax, ay);
    __syncthreads();
    if (!half && lane < 32) {
        float2 pp = part[slot][cl];
        __half2 hp = __floats2half2_rn(ax + pp.x, ay + pp.y);
        hout2[(unsigned)v * 32 + cl] = *(unsigned*)&hp;
    }
}

// ---------------- bias + SELU + GEMM2 -> packed uint2 g, score tables ----------------
#define G2_ROWS 32
__global__ __launch_bounds__(256) void k_act_gemm2(const __half* __restrict__ h2,
                                                   const float* __restrict__ bsg,
                                                   const float* __restrict__ Wg,
                                                   const float* __restrict__ att_s,
                                                   const float* __restrict__ att_d,
                                                   uint2* __restrict__ g4h,
                                                   float2* __restrict__ asrc2,
                                                   float4* __restrict__ admm) {
    __shared__ float hs[G2_ROWS][HID];   // 8 KB
    int tid = threadIdx.x;
    int wave = tid >> 6, lane = tid & 63;
    int r0 = blockIdx.x * G2_ROWS;
    int rbase = wave * 8;

    const float SC = 1.0507009873554805f, AL = 1.6732632423543772f;
    {
        int row = tid >> 3, c0 = (tid & 7) * 8;
        int r = r0 + row;
        float vals[8];
        if (r < N_NODES) {
            uint4 raw = *(const uint4*)(h2 + (unsigned)r * HID + c0);
            float2 f0 = __half22float2(*(__half2*)&raw.x);
            float2 f1 = __half22float2(*(__half2*)&raw.y);
            float2 f2 = __half22float2(*(__half2*)&raw.z);
            float2 f3 = __half22float2(*(__half2*)&raw.w);
            vals[0] = f0.x; vals[1] = f0.y; vals[2] = f1.x; vals[3] = f1.y;
            vals[4] = f2.x; vals[5] = f2.y; vals[6] = f3.x; vals[7] = f3.y;
        } else {
#pragma unroll
            for (int j = 0; j < 8; j++) vals[j] = 0.f;
        }
#pragma unroll
        for (int j = 0; j < 8; j++) {
            float hv = vals[j] + bsg[c0 + j];
            hv = (hv > 0.f) ? SC * hv : SC * AL * (__expf(hv) - 1.f);
            hs[row][c0 + j] = hv;
        }
    }
    __syncthreads();

    float accx[8], accy[8];
#pragma unroll
    for (int j = 0; j < 8; j++) { accx[j] = 0.f; accy[j] = 0.f; }
#pragma unroll 2
    for (int k = 0; k < HID; k++) {
        float w0 = Wg[(size_t)k * 128 + lane];        // coalesced, L1-resident
        float w1 = Wg[(size_t)k * 128 + 64 + lane];
#pragma unroll
        for (int j = 0; j < 8; j++) {
            float hk = hs[rbase + j][k];              // LDS broadcast
            accx[j] += hk * w0;
            accy[j] += hk * w1;
        }
    }
    float ats0 = att_s[lane], ats1 = att_s[64 + lane];
    float atd0 = att_d[lane], atd1 = att_d[64 + lane];
#pragma unroll
    for (int j = 0; j < 8; j++) {
        int v = r0 + rbase + j;
        if (v >= N_NODES) break;
        __half2 gp = __floats2half2_rn(accx[j], accy[j]);
        unsigned gpu = *(unsigned*)&gp;
        unsigned other = (unsigned)__shfl_xor((int)gpu, 1);
        if (!(lane & 1)) g4h[(unsigned)v * 32 + (lane >> 1)] = make_uint2(gpu, other);
        float s0 = accx[j] * ats0, s1 = accy[j] * ats1;
        float d0 = accx[j] * atd0, d1 = accy[j] * atd1;
#pragma unroll
        for (int o = 32; o > 0; o >>= 1) {
            s0 += __shfl_xor(s0, o);
            s1 += __shfl_xor(s1, o);
            d0 += __shfl_xor(d0, o);
            d1 += __shfl_xor(d1, o);
        }
        if (lane == 0) {
            asrc2[v] = make_float2(s0, s1);
            float m0 = s0 + d0; m0 = (m0 > 0.f) ? m0 : NEG_SLOPE * m0;
            float m1 = s1 + d1; m1 = (m1 > 0.f) ? m1 : NEG_SLOPE * m1;
            admm[v] = make_float4(d0, d1, m0, m1);
        }
    }
}

// ---------------- GAT: two-phase (lane-parallel scores -> LDS p-cache) ----------------
__global__ __launch_bounds__(256) void k_gat(const uint2* __restrict__ g4h,
                                             const float2* __restrict__ asrc2,
                                             const float4* __restrict__ admm,
                                             const int* __restrict__ offsets,
                                             const int2* __restrict__ edges,
                                             const float* __restrict__ bgat,
                                             float* __restrict__ out) {
    __shared__ int4 pbuf[2][2][PCAP];    // 8 KB: {src*32, p0, p1, -}
    __shared__ float4 pacc[2][32];
    __shared__ float2 pden[2][32];
    int tid = threadIdx.x;
    int w = tid >> 6, lane = tid & 63;
    int slot = w >> 1, half = w & 1;
    int cl = lane & 31, es = lane >> 5;
    int v = blockIdx.x * 2 + slot;
    float4 am = admm[v];   // ad0, ad1, m0, m1 (wave-uniform)
    int beg = offsets[v], end = offsets[v + 1];
    int mid = beg + ((end - beg) >> 1);
    int lo = half ? mid : beg;
    int hi = half ? end : mid;
    int n = hi - lo;

    // ---- phase 1: lane-parallel scores, den reduce, p-cache fill ----
    float pd0 = 0.f, pd1 = 0.f;
    for (int i = lo + lane; i < hi; i += 64) {
        int2 e = edges[i];                          // coalesced
        float2 a = asrc2[(unsigned)e.x >> 5];       // 8B gather, L2-resident
        float t0 = a.x + am.x; t0 = (t0 > 0.f) ? t0 : NEG_SLOPE * t0;
        float t1 = a.y + am.y; t1 = (t1 > 0.f) ? t1 : NEG_SLOPE * t1;
        float p0 = __expf(t0 - am.z);
        float p1 = __expf(t1 - am.w);
        int idx = i - lo;
        if (idx < PCAP)
            pbuf[slot][half][idx] = make_int4(e.x, __float_as_int(p0), __float_as_int(p1), 0);
        pd0 += p0; pd1 += p1;
    }
#pragma unroll
    for (int o = 32; o > 0; o >>= 1) {
        pd0 += __shfl_xor(pd0, o);
        pd1 += __shfl_xor(pd1, o);
    }
    if (!half) { pd0 += 1.f; pd1 += 1.f; }   // self-loop p=1 (once per node)

    // ---- phase 2: gather+accumulate using cached p ----
    float aA = 0.f, aB = 0.f, aC = 0.f, aD = 0.f;
    float bA = 0.f, bB = 0.f, bC = 0.f, bD = 0.f;
    if (!half && !es) {
        uint2 gs = g4h[(unsigned)v * 32 + cl];   // self, p=1
        float2 gx = __half22float2(*(__half2*)&gs.x);
        float2 gy = __half22float2(*(__half2*)&gs.y);
        aA = gx.x; aB = gx.y; aC = gy.x; aD = gy.y;
    }
    int n1 = (n < PCAP) ? n : PCAP;
    int ii = 0;
    for (; ii + 8 <= n1; ii += 8) {
        int4 e0 = pbuf[slot][half][ii + es];
        int4 e1 = pbuf[slot][half][ii + 2 + es];
        int4 e2 = pbuf[slot][half][ii + 4 + es];
        int4 e3 = pbuf[slot][half][ii + 6 + es];
        uint2 g0 = g4h[(unsigned)(e0.x + cl)];
        uint2 g1 = g4h[(unsigned)(e1.x + cl)];
        uint2 g2 = g4h[(unsigned)(e2.x + cl)];
        uint2 g3 = g4h[(unsigned)(e3.x + cl)];
        float p00 = __int_as_float(e0.y), p01 = __int_as_float(e0.z);
        float p10 = __int_as_float(e1.y), p11 = __int_as_float(e1.z);
        float p20 = __int_as_float(e2.y), p21 = __int_as_float(e2.z);
        float p30 = __int_as_float(e3.y), p31 = __int_as_float(e3.z);
        float2 g0x = __half22float2(*(__half2*)&g0.x);
        float2 g0y = __half22float2(*(__half2*)&g0.y);
        float2 g1x = __half22float2(*(__half2*)&g1.x);
        float2 g1y = __half22float2(*(__half2*)&g1.y);
        float2 g2x = __half22float2(*(__half2*)&g2.x);
        float2 g2y = __half22float2(*(__half2*)&g2.y);
        float2 g3x = __half22float2(*(__half2*)&g3.x);
        float2 g3y = __half22float2(*(__half2*)&g3.y);
        aA += p00 * g0x.x; aB += p01 * g0x.y; aC += p00 * g0y.x; aD += p01 * g0y.y;
        bA += p10 * g1x.x; bB += p11 * g1x.y; bC += p10 * g1y.x; bD += p11 * g1y.y;
        aA += p20 * g2x.x; aB += p21 * g2x.y; aC += p20 * g2y.x; aD += p21 * g2y.y;
        bA += p30 * g3x.x; bB += p31 * g3x.y; bC += p30 * g3y.x; bD += p31 * g3y.y;
    }
    for (; ii + es < n1; ii += 2) {
        int4 e0 = pbuf[slot][half][ii + es];
        uint2 g0 = g4h[(unsigned)(e0.x + cl)];
        float p00 = __int_as_float(e0.y), p01 = __int_as_float(e0.z);
        float2 g0x = __half22float2(*(__half2*)&g0.x);
        float2 g0y = __half22float2(*(__half2*)&g0.y);
        aA += p00 * g0x.x; aB += p01 * g0x.y; aC += p00 * g0y.x; aD += p01 * g0y.y;
    }
    // rare overflow tail (deg/2 > PCAP): inline scores
    for (int jj = PCAP + es; jj < n; jj += 2) {
        int2 e = edges[lo + jj];
        float2 a = asrc2[(unsigned)e.x >> 5];
        float t0 = a.x + am.x; t0 = (t0 > 0.f) ? t0 : NEG_SLOPE * t0;
        float t1 = a.y + am.y; t1 = (t1 > 0.f) ? t1 : NEG_SLOPE * t1;
        float p0 = __expf(t0 - am.z);
        float p1 = __expf(t1 - am.w);
        uint2 g0 = g4h[(unsigned)(e.x + cl)];
        float2 g0x = __half22float2(*(__half2*)&g0.x);
        float2 g0y = __half22float2(*(__half2*)&g0.y);
        aA += p0 * g0x.x; aB += p1 * g0x.y; aC += p0 * g0y.x; aD += p1 * g0y.y;
    }
    aA += bA; aB += bB; aC += bC; aD += bD;
    aA += __shfl_xor(aA, 32); aB += __shfl_xor(aB, 32);
    aC += __shfl_xor(aC, 32); aD += __shfl_xor(aD, 32);
    if (half && lane < 32) {
        pacc[slot][cl] = make_float4(aA, aB, aC, aD);
        pden[slot][cl] = make_float2(pd0, pd1);
    }
    __syncthreads();
    if (!half && lane < 32) {
        float4 pa = pacc[slot][cl];
        float2 pd = pden[slot][cl];
        float r0 = 1.f / (pd0 + pd.x), r1 = 1.f / (pd1 + pd.y);
        float oe = 0.5f * ((aA + pa.x) * r0 + (aB + pa.y) * r1) + bgat[cl * 2];
        float oo = 0.5f * ((aC + pa.z) * r0 + (aD + pa.w) * r1) + bgat[cl * 2 + 1];
        *(float2*)&out[(unsigned)v * OUTC + cl * 2] = make_float2(oe, oo);
    }
}

extern "C" void kernel_launch(void* const* d_in, const int* in_sizes, int n_in,
                              void* d_out, int out_size, void* d_ws, size_t ws_size,
                              hipStream_t stream) {
    const float* x     = (const float*)d_in[0];
    const int*   ei    = (const int*)d_in[1];
    const float* ea    = (const float*)d_in[2];
    const float* Wsg   = (const float*)d_in[3];
    const float* bsg   = (const float*)d_in[4];
    const float* Wg    = (const float*)d_in[5];
    const float* att_s = (const float*)d_in[6];
    const float* att_d = (const float*)d_in[7];
    const float* bgat  = (const float*)d_in[8];
    const int* src = ei;
    const int* dst = ei + N_EDGES;
    float* out = (float*)d_out;

    char* ws = (char*)d_ws;
    size_t off = 0;
    auto alloc = [&](size_t bytes) -> void* {
        void* p = ws + off;
        off = (off + bytes + 255) & ~(size_t)255;
        return p;
    };
    unsigned*       deg32  = (unsigned*)alloc((size_t)N_NODES * 4);
    float*          dinv   = (float*)alloc((size_t)N_NODES * 4);
    unsigned short* rank   = (unsigned short*)alloc((size_t)N_EDGES * 2);
    int*            offs   = (int*)alloc((size_t)(N_NODES + 1) * 4);
    int*            bsum   = (int*)alloc(256 * 4);
    int2*           edges  = (int2*)alloc((size_t)N_EDGES * 8);
    short*          Wfrag  = (short*)alloc((size_t)IN_CH * HID * 2 * 2);
    __half*         h0     = (__half*)alloc((size_t)N_NODES * HID * 2);
    __half*         h1     = (__half*)alloc((size_t)N_NODES * HID * 2);
    uint2*          g4h    = (uint2*)alloc((size_t)N_NODES * 32 * 8);
    float2*         asrc2  = (float2*)alloc((size_t)N_NODES * 8);
    float4*         admm   = (float4*)alloc((size_t)N_NODES * 16);
    (void)ws_size; (void)in_sizes; (void)n_in; (void)out_size;

    hipMemsetAsync(deg32, 0, (size_t)N_NODES * 4, stream);

    k_wsplit<<<(IN_CH * HID + 255) / 256, 256, 0, stream>>>(Wsg, Wfrag);

    // fused: even blocks = gemm tile (bid>>1), odd blocks = hist chunk (bid>>1)
    k_gemm_hist<<<1564, 256, 0, stream>>>(x, Wfrag, h0, dst, ea, deg32, rank);

    int nb = (N_NODES + 255) / 256;  // 196
    k_scan_reduce<<<nb, 256, 0, stream>>>(deg32, bsum, dinv, N_NODES);
    k_scan_bsum<<<1, 256, 0, stream>>>(bsum, nb);
    k_scan_final<<<nb, 256, 0, stream>>>(deg32, bsum, offs, N_NODES);

    k_scatter<<<(N_EDGES + 255) / 256, 256, 0, stream>>>(src, dst, ea, dinv, offs, rank, edges);

    k_hop<<<N_NODES / 2, 256, 0, stream>>>((const unsigned*)h0, offs, edges, dinv, (unsigned*)h1);
    k_hop<<<N_NODES / 2, 256, 0, stream>>>((const unsigned*)h1, offs, edges, dinv, (unsigned*)h0);
    k_act_gemm2<<<(N_NODES + G2_ROWS - 1) / G2_ROWS, 256, 0, stream>>>(h0, bsg, Wg, att_s, att_d, g4h, asrc2, admm);
    k_gat<<<N_NODES / 2, 256, 0, stream>>>(g4h, asrc2, admm, offs, edges, bgat, out);
}